// Round 13
// baseline (2080.608 us; speedup 1.0000x reference)
//
#include <hip/hip_runtime.h>
#include <hip/hip_bf16.h>

// FilterModule: 7x MHA fusion pipeline, bf16 MFMA + flash attention v12.
// v12 = v11 pipeline with flash rebuilt to satisfy BOTH prior failure modes:
//   256-thr blocks (VGPR cap 256; R11 measured 236, no spill) AND KVB=32
//   (LDS 64KB -> 2 blocks/CU = 2 waves/SIMD TLP). 2 q-frags/wave halves LDS
//   traffic per unit work (32 ds_read : 64 MFMA per tile). NSPLIT keeps grid
//   at 512 blocks = 2/CU (batch=1: NSPLIT=4; batch=2: NSPLIT=2).

typedef __attribute__((ext_vector_type(8))) short short8;
typedef __attribute__((ext_vector_type(4))) float f32x4;
typedef unsigned long long ull;
typedef long long ll;

namespace {
constexpr int NTOK = 4096;
constexpr int EMB  = 1024;
constexpr int QTY  = 512;
}

__device__ __forceinline__ float bf2f(unsigned short u) {
    union { float f; unsigned int i; } x; x.i = ((unsigned int)u) << 16; return x.f;
}
__device__ __forceinline__ unsigned short f2bf(float f) {
    union { float f; unsigned int i; } x; x.f = f;
    unsigned int r = x.i + 0x7fffu + ((x.i >> 16) & 1u);
    return (unsigned short)(r >> 16);
}

#define GLOAD_LDS16(g, l) __builtin_amdgcn_global_load_lds( \
    (const __attribute__((address_space(1))) void*)(g),     \
    (__attribute__((address_space(3))) void*)(l), 16, 0, 0)

// ---------------------------------------------------------------------------
// MFMA GEMM (B^T layout): C[m][n] = alpha*sum_k A[m][k]*B[n][k] (+epilogue).
// 128x128 tile, BK=32, 256 thr. Signed z-strides for batched launches.
template<int SPLITS, int OUTM>
__global__ __launch_bounds__(256)
void gemm_mfma(const unsigned short* __restrict__ Ah, const unsigned short* __restrict__ Al,
               int lda, ll sAz,
               const unsigned short* __restrict__ Bh, const unsigned short* __restrict__ Bl,
               int ldb, ll sBz,
               void* __restrict__ Cp, void* __restrict__ Clp,
               int ldc, ll sCz,
               int K, float alpha, const float* __restrict__ bias, int biasRow,
               const unsigned short* __restrict__ resH, const unsigned short* __restrict__ resL,
               ll sRz, int resMode)
{
    constexpr int NTILES = (SPLITS == 3 ? 4 : (SPLITS == 2 ? 3 : 2));
    constexpr int TSZ = 128 * 32;
    __shared__ unsigned short lds[NTILES * TSZ];  // Ah | Bh | [Bl] | [Al]
    const int tid  = threadIdx.x;
    const int brow = blockIdx.y * 128;
    const int bcol = blockIdx.x * 128;
    const ll   z   = blockIdx.z;
    Ah += z * sAz; Bh += z * sBz;
    if constexpr (SPLITS == 3) Al += z * sAz;
    if constexpr (SPLITS >= 2) Bl += z * sBz;

    const int lane = tid & 63;
    const int wv = tid >> 6, wr = wv >> 1, wc = wv & 1;
    const int l15 = lane & 15, l4 = lane >> 4;

    f32x4 acc[4][4];
    #pragma unroll
    for (int m = 0; m < 4; ++m)
        #pragma unroll
        for (int n = 0; n < 4; ++n) acc[m][n] = (f32x4){0.f, 0.f, 0.f, 0.f};

    for (int k0 = 0; k0 < K; k0 += 32) {
        #pragma unroll
        for (int i = 0; i < 2; ++i) {
            int idx = tid + i * 256;
            int row = idx >> 2;
            int kc  = (idx & 3) ^ ((row >> 1) & 3);
            GLOAD_LDS16(Ah + (ull)(brow + row) * lda + k0 + kc * 8, &lds[idx * 8]);
            GLOAD_LDS16(Bh + (ull)(bcol + row) * ldb + k0 + kc * 8, &lds[TSZ + idx * 8]);
            if constexpr (SPLITS >= 2)
                GLOAD_LDS16(Bl + (ull)(bcol + row) * ldb + k0 + kc * 8, &lds[2 * TSZ + idx * 8]);
            if constexpr (SPLITS == 3)
                GLOAD_LDS16(Al + (ull)(brow + row) * lda + k0 + kc * 8, &lds[3 * TSZ + idx * 8]);
        }
        __syncthreads();

        short8 ah[4], bh[4], bl2[4], al2[4];
        #pragma unroll
        for (int m = 0; m < 4; ++m) {
            int rr = wr * 64 + m * 16 + l15;
            int sl = l4 ^ ((rr >> 1) & 3);
            int off = rr * 32 + sl * 8;
            ah[m] = *(const short8*)&lds[off];
            if constexpr (SPLITS == 3) al2[m] = *(const short8*)&lds[3 * TSZ + off];
        }
        #pragma unroll
        for (int n = 0; n < 4; ++n) {
            int rr = wc * 64 + n * 16 + l15;
            int sl = l4 ^ ((rr >> 1) & 3);
            int off = rr * 32 + sl * 8;
            bh[n] = *(const short8*)&lds[TSZ + off];
            if constexpr (SPLITS >= 2) bl2[n] = *(const short8*)&lds[2 * TSZ + off];
        }
        #pragma unroll
        for (int m = 0; m < 4; ++m)
            #pragma unroll
            for (int n = 0; n < 4; ++n) {
                acc[m][n] = __builtin_amdgcn_mfma_f32_16x16x32_bf16(ah[m], bh[n], acc[m][n], 0, 0, 0);
                if constexpr (SPLITS >= 2)
                    acc[m][n] = __builtin_amdgcn_mfma_f32_16x16x32_bf16(ah[m], bl2[n], acc[m][n], 0, 0, 0);
                if constexpr (SPLITS == 3)
                    acc[m][n] = __builtin_amdgcn_mfma_f32_16x16x32_bf16(al2[m], bh[n], acc[m][n], 0, 0, 0);
            }
        __syncthreads();
    }

    float* Cf = (float*)Cp + z * sCz;
    unsigned short* Ch = (unsigned short*)Cp + z * sCz;
    unsigned short* Cl = (unsigned short*)Clp + z * sCz;
    const unsigned short* rH = resH + z * sRz;
    const unsigned short* rL = resL + z * sRz;
    const int rowB = brow + wr * 64 + l4 * 4;
    const int colB = bcol + wc * 64 + l15;
    #pragma unroll
    for (int n = 0; n < 4; ++n) {
        int col = colB + n * 16;
        #pragma unroll
        for (int m = 0; m < 4; ++m) {
            #pragma unroll
            for (int r = 0; r < 4; ++r) {
                int row = rowB + m * 16 + r;
                ull ci = (ull)row * ldc + col;
                float v = acc[m][n][r] * alpha;
                if (bias) v += biasRow ? bias[row] : bias[col];
                if (resMode == 1)      v += bf2f(rH[ci]) + bf2f(rL[ci]);
                else if (resMode == 2) v *= bf2f(rH[ci]) + bf2f(rL[ci]);
                if constexpr (OUTM == 0)      Cf[ci] = v;
                else if constexpr (OUTM == 1) Ch[ci] = f2bf(v);
                else {
                    unsigned short h = f2bf(v);
                    Ch[ci] = h;
                    Cl[ci] = f2bf(v - bf2f(h));
                }
            }
        }
    }
}

// ---------------------------------------------------------------------------
// Fused Q+K projection. z = b*2 + j (j: 0=Q, 1=K).
__global__ __launch_bounds__(256)
void gemm_qkproj(const unsigned short* a0, const unsigned short* a1,
                 const unsigned short* a2, const unsigned short* a3,
                 const unsigned short* __restrict__ W,
                 unsigned short* __restrict__ QK,
                 const float* __restrict__ bias)
{
    constexpr int TSZ = 128 * 32;
    __shared__ unsigned short lds[2 * TSZ];
    const int tid  = threadIdx.x;
    const int brow = blockIdx.y * 128;
    const int bcol = blockIdx.x * 128;
    const int z = blockIdx.z;
    const int j = z & 1, bb = z >> 1;
    const unsigned short* Ah = (z == 0) ? a0 : (z == 1) ? a1 : (z == 2) ? a2 : a3;
    const unsigned short* Bh = W + (ull)j * EMB * EMB;
    unsigned short* C = QK + (ull)bb * NTOK * 2048 + j * 1024;
    const float* bi = bias + j * 1024;

    const int lane = tid & 63;
    const int wv = tid >> 6, wr = wv >> 1, wc = wv & 1;
    const int l15 = lane & 15, l4 = lane >> 4;

    f32x4 acc[4][4];
    #pragma unroll
    for (int m = 0; m < 4; ++m)
        #pragma unroll
        for (int n = 0; n < 4; ++n) acc[m][n] = (f32x4){0.f, 0.f, 0.f, 0.f};

    for (int k0 = 0; k0 < EMB; k0 += 32) {
        #pragma unroll
        for (int i = 0; i < 2; ++i) {
            int idx = tid + i * 256;
            int row = idx >> 2;
            int kc  = (idx & 3) ^ ((row >> 1) & 3);
            GLOAD_LDS16(Ah + (ull)(brow + row) * EMB + k0 + kc * 8, &lds[idx * 8]);
            GLOAD_LDS16(Bh + (ull)(bcol + row) * EMB + k0 + kc * 8, &lds[TSZ + idx * 8]);
        }
        __syncthreads();

        short8 ah[4], bh[4];
        #pragma unroll
        for (int m = 0; m < 4; ++m) {
            int rr = wr * 64 + m * 16 + l15;
            int sl = l4 ^ ((rr >> 1) & 3);
            ah[m] = *(const short8*)&lds[rr * 32 + sl * 8];
        }
        #pragma unroll
        for (int n = 0; n < 4; ++n) {
            int rr = wc * 64 + n * 16 + l15;
            int sl = l4 ^ ((rr >> 1) & 3);
            bh[n] = *(const short8*)&lds[TSZ + rr * 32 + sl * 8];
        }
        #pragma unroll
        for (int m = 0; m < 4; ++m)
            #pragma unroll
            for (int n = 0; n < 4; ++n)
                acc[m][n] = __builtin_amdgcn_mfma_f32_16x16x32_bf16(ah[m], bh[n], acc[m][n], 0, 0, 0);
        __syncthreads();
    }

    const int rowB = brow + wr * 64 + l4 * 4;
    const int colB = bcol + wc * 64 + l15;
    #pragma unroll
    for (int n = 0; n < 4; ++n) {
        int col = colB + n * 16;
        float bv = bi[col];
        #pragma unroll
        for (int m = 0; m < 4; ++m)
            #pragma unroll
            for (int r = 0; r < 4; ++r) {
                int row = rowB + m * 16 + r;
                C[(ull)row * 2048 + col] = f2bf(acc[m][n][r] + bv);
            }
    }
}

// ---------------------------------------------------------------------------
// Flash attention v12: 4 waves x 32 q (2 q-frags/wave), KVB=32 dbuf (64KB LDS
// -> 2 blocks/CU), shfl P-repack, 256 thr. blockIdx.z = batch*4 + head.
// Writes normalized O (bf16) per split + (m,l).
template<int NSPLIT>
__global__ __launch_bounds__(256, 1)
void flash_attn(const unsigned short* __restrict__ QK,
                const unsigned short* __restrict__ VT,
                unsigned short* __restrict__ Opart, float* __restrict__ ml)
{
    constexpr int KVB = 32;
    constexpr int NTILE = (NTOK / NSPLIT) / KVB;
    __shared__ unsigned short Kt[2][KVB * 256];   // 16 KB each [kv][d], swizzled
    __shared__ unsigned short Vt[2][256 * KVB];   // 16 KB each [d][kv], swizzled

    const int tid = threadIdx.x;
    const int w = tid >> 6, lane = tid & 63;
    const int l15 = lane & 15, l4 = lane >> 4;
    const int qt = blockIdx.x, sp = blockIdx.y;
    const int zb = blockIdx.z, b = zb >> 2, h = zb & 3;
    const int qbase = qt * 128 + w * 32;
    const int kv0 = sp * (NTOK / NSPLIT);
    const unsigned short* QKb = QK + (ull)b * NTOK * 2048;
    const unsigned short* VTb = VT + (ull)b * 1024 * 4096;

    // Q B-fragments (2 q-frags x 8 k-chunks), pre-scaled by 1/16 (exact)
    short8 qreg[2][8];
    #pragma unroll
    for (int qf = 0; qf < 2; ++qf) {
        const unsigned short* qp = QKb + (ull)(qbase + qf * 16 + l15) * 2048 + h * 256;
        #pragma unroll
        for (int c = 0; c < 8; ++c) {
            short8 x = *(const short8*)&qp[c * 32 + l4 * 8];
            #pragma unroll
            for (int j = 0; j < 8; ++j)
                x[j] = (short)f2bf(bf2f((unsigned short)x[j]) * 0.0625f);
            qreg[qf][c] = x;
        }
    }

    f32x4 oacc[2][16];
    #pragma unroll
    for (int qf = 0; qf < 2; ++qf)
        #pragma unroll
        for (int dn = 0; dn < 16; ++dn) oacc[qf][dn] = (f32x4){0.f, 0.f, 0.f, 0.f};
    float m_r[2] = { -1e30f, -1e30f }, l_r[2] = { 0.f, 0.f };

    auto stage = [&](int t, int buf) {
        int base = kv0 + t * KVB;
        #pragma unroll
        for (int i = 0; i < 4; ++i) {       // K tile: 32 rows x 32 chunks
            int s = tid + i * 256;
            int r = s >> 5, c = s & 31;
            int c0 = c ^ (r & 7);
            GLOAD_LDS16(QKb + (ull)(base + r) * 2048 + 1024 + h * 256 + c0 * 8,
                        &Kt[buf][s * 8]);
        }
        #pragma unroll
        for (int i = 0; i < 4; ++i) {       // V^T tile: 256 rows x 4 chunks
            int s = tid + i * 256;
            int r = s >> 2, c = s & 3;
            int c0 = c ^ (r & 3);
            GLOAD_LDS16(VTb + (ull)(h * 256 + r) * 4096 + base + c0 * 8,
                        &Vt[buf][s * 8]);
        }
    };

    stage(0, 0);
    for (int t = 0; t < NTILE; ++t) {
        if (t + 1 < NTILE) {
            stage(t + 1, (t + 1) & 1);
            asm volatile("s_waitcnt vmcnt(8)");
        } else {
            asm volatile("s_waitcnt vmcnt(0)");
        }
        __builtin_amdgcn_s_barrier();

        const unsigned short* Kb = Kt[t & 1];
        const unsigned short* Vb = Vt[t & 1];

        // QK^T (swapped): sacc[qf][fk], lane: q=l15, kv=fk*16+l4*4+r
        f32x4 sacc[2][2];
        #pragma unroll
        for (int qf = 0; qf < 2; ++qf)
            #pragma unroll
            for (int fk = 0; fk < 2; ++fk) sacc[qf][fk] = (f32x4){0.f, 0.f, 0.f, 0.f};

        #pragma unroll
        for (int fk = 0; fk < 2; ++fk) {
            int r = fk * 16 + l15;
            int rx = r & 7;
            #pragma unroll
            for (int c = 0; c < 8; ++c) {
                int ch = (4 * c + l4) ^ rx;
                short8 kf = *(const short8*)&Kb[r * 256 + ch * 8];
                sacc[0][fk] = __builtin_amdgcn_mfma_f32_16x16x32_bf16(kf, qreg[0][c], sacc[0][fk], 0, 0, 0);
                sacc[1][fk] = __builtin_amdgcn_mfma_f32_16x16x32_bf16(kf, qreg[1][c], sacc[1][fk], 0, 0, 0);
            }
        }

        // online softmax per q-frag; exp overwrites sacc in place
        unsigned int W[2][2][2];   // [qf][fk][pp]
        #pragma unroll
        for (int qf = 0; qf < 2; ++qf) {
            float tm = sacc[qf][0][0];
            #pragma unroll
            for (int fk = 0; fk < 2; ++fk)
                #pragma unroll
                for (int rr = 0; rr < 4; ++rr) tm = fmaxf(tm, sacc[qf][fk][rr]);
            tm = fmaxf(tm, __shfl_xor(tm, 16));
            tm = fmaxf(tm, __shfl_xor(tm, 32));

            bool nomax = __all(tm <= m_r[qf]);
            float mnew = nomax ? m_r[qf] : fmaxf(m_r[qf], tm);
            if (!nomax) {
                float corr = __expf(m_r[qf] - mnew);
                float c4[4];
                #pragma unroll
                for (int r = 0; r < 4; ++r) c4[r] = __shfl(corr, l4 * 4 + r);
                #pragma unroll
                for (int dn = 0; dn < 16; ++dn)
                    #pragma unroll
                    for (int r = 0; r < 4; ++r) oacc[qf][dn][r] *= c4[r];
                l_r[qf] *= corr;
                m_r[qf] = mnew;
            }

            float ls = 0.f;
            #pragma unroll
            for (int fk = 0; fk < 2; ++fk)
                #pragma unroll
                for (int rr = 0; rr < 4; ++rr) {
                    float e = __expf(sacc[qf][fk][rr] - m_r[qf]);
                    sacc[qf][fk][rr] = e; ls += e;
                }
            ls += __shfl_xor(ls, 16);
            ls += __shfl_xor(ls, 32);
            l_r[qf] += ls;

            // pack P to bf16 pairs: W[qf][fk][pp] = kv (16fk+4*l4+2pp, +1)
            #pragma unroll
            for (int fk = 0; fk < 2; ++fk)
                #pragma unroll
                for (int pp = 0; pp < 2; ++pp)
                    W[qf][fk][pp] = (unsigned int)f2bf(sacc[qf][fk][2 * pp]) |
                                    ((unsigned int)f2bf(sacc[qf][fk][2 * pp + 1]) << 16);
        }

        // gather to A-frag layout (lane q=l15, kv = l4*8 + j) + PV
        const int sbase = l15 + ((l4 & 1) << 5);
        const bool hi = (l4 >> 1) & 1;
        union { unsigned int u[4]; short8 s8; } pa[2];
        #pragma unroll
        for (int qf = 0; qf < 2; ++qf) {
            unsigned int a0 = (unsigned int)__shfl((int)W[qf][0][0], sbase);
            unsigned int a1 = (unsigned int)__shfl((int)W[qf][0][1], sbase);
            unsigned int a2 = (unsigned int)__shfl((int)W[qf][0][0], sbase + 16);
            unsigned int a3 = (unsigned int)__shfl((int)W[qf][0][1], sbase + 16);
            unsigned int b0 = (unsigned int)__shfl((int)W[qf][1][0], sbase);
            unsigned int b1 = (unsigned int)__shfl((int)W[qf][1][1], sbase);
            unsigned int b2 = (unsigned int)__shfl((int)W[qf][1][0], sbase + 16);
            unsigned int b3 = (unsigned int)__shfl((int)W[qf][1][1], sbase + 16);
            pa[qf].u[0] = hi ? b0 : a0; pa[qf].u[1] = hi ? b1 : a1;
            pa[qf].u[2] = hi ? b2 : a2; pa[qf].u[3] = hi ? b3 : a3;
        }

        // PV: oacc[qf][dn] += P[q, kv32] * V^T[d, kv32]
        #pragma unroll
        for (int dn = 0; dn < 16; ++dn) {
            int row = dn * 16 + l15;
            int ch = l4 ^ (row & 3);
            short8 vf = *(const short8*)&Vb[row * 32 + ch * 8];
            oacc[0][dn] = __builtin_amdgcn_mfma_f32_16x16x32_bf16(pa[0].s8, vf, oacc[0][dn], 0, 0, 0);
            oacc[1][dn] = __builtin_amdgcn_mfma_f32_16x16x32_bf16(pa[1].s8, vf, oacc[1][dn], 0, 0, 0);
        }
        __builtin_amdgcn_s_barrier();
    }

    // epilogue: normalized O (bf16) + (m,l). lane: d=dn*16+l15, q=base+l4*4+r
    unsigned short* Ob = Opart + (((ull)b * NSPLIT + sp) * 4 + h) * NTOK * 256;
    #pragma unroll
    for (int qf = 0; qf < 2; ++qf) {
        float inv = 1.f / l_r[qf];
        float i4[4];
        #pragma unroll
        for (int r = 0; r < 4; ++r) i4[r] = __shfl(inv, l4 * 4 + r);
        #pragma unroll
        for (int dn = 0; dn < 16; ++dn) {
            int d = dn * 16 + l15;
            #pragma unroll
            for (int r = 0; r < 4; ++r) {
                int q = qbase + qf * 16 + l4 * 4 + r;
                Ob[(ull)q * 256 + d] = f2bf(oacc[qf][dn][r] * i4[r]);
            }
        }
        if (l4 == 0) {
            float2* mlp = (float2*)ml + (((ull)b * NSPLIT + sp) * 4 + h) * NTOK
                          + qbase + qf * 16 + l15;
            *mlp = make_float2(m_r[qf], l_r[qf]);
        }
    }
}

// ---------------------------------------------------------------------------
// merge NS KV-split partials (normalized bf16) -> att bf16 (hi only).
// blockIdx.x = batch*4096 + q.
template<int NS>
__global__ __launch_bounds__(256)
void flash_combine(const unsigned short* __restrict__ Opart, const float* __restrict__ ml,
                   unsigned short* __restrict__ attH)
{
    const int bx = blockIdx.x;
    const int b = bx >> 12, q = bx & 4095;
    const int t = threadIdx.x;
    const int h = t >> 6, d4 = (t & 63) * 4;

    float2 ms_[NS]; float mmax = -1e30f;
    #pragma unroll
    for (int s = 0; s < NS; ++s) {
        ms_[s] = ((const float2*)ml)[(((ull)b * NS + s) * 4 + h) * NTOK + q];
        mmax = fmaxf(mmax, ms_[s].x);
    }
    float wt[NS], denom = 0.f;
    #pragma unroll
    for (int s = 0; s < NS; ++s) {
        wt[s] = __expf(ms_[s].x - mmax) * ms_[s].y;
        denom += wt[s];
    }
    float inv = 1.f / denom;
    float acc[4] = { 0.f, 0.f, 0.f, 0.f };
    #pragma unroll
    for (int s = 0; s < NS; ++s) {
        ushort4 o = *(const ushort4*)&Opart[((((ull)b * NS + s) * 4 + h) * NTOK + q) * 256 + d4];
        acc[0] += wt[s] * bf2f(o.x); acc[1] += wt[s] * bf2f(o.y);
        acc[2] += wt[s] * bf2f(o.z); acc[3] += wt[s] * bf2f(o.w);
    }
    ushort4 ho;
    ho.x = f2bf(acc[0] * inv); ho.y = f2bf(acc[1] * inv);
    ho.z = f2bf(acc[2] * inv); ho.w = f2bf(acc[3] * inv);
    *(ushort4*)&attH[(ull)b * NTOK * EMB + (ull)q * EMB + h * 256 + d4] = ho;
}

// ---------------------------------------------------------------------------
template<bool F32IN>
__global__ __launch_bounds__(256)
void l2norm_rows(const float* __restrict__ inF, const unsigned short* __restrict__ inH,
                 const unsigned short* __restrict__ inL,
                 unsigned short* __restrict__ oH, unsigned short* __restrict__ oL)
{
    const ull row = blockIdx.x;
    const int t = threadIdx.x;
    const int lane = t & 63, wid = t >> 6;
    __shared__ float red[4];

    float v[4];
    if constexpr (F32IN) {
        float4 x = *(const float4*)&inF[row * EMB + t * 4];
        v[0] = x.x; v[1] = x.y; v[2] = x.z; v[3] = x.w;
    } else {
        ushort4 hh = *(const ushort4*)&inH[row * EMB + t * 4];
        ushort4 ll2 = *(const ushort4*)&inL[row * EMB + t * 4];
        v[0] = bf2f(hh.x) + bf2f(ll2.x); v[1] = bf2f(hh.y) + bf2f(ll2.y);
        v[2] = bf2f(hh.z) + bf2f(ll2.z); v[3] = bf2f(hh.w) + bf2f(ll2.w);
    }
    float ss = v[0] * v[0] + v[1] * v[1] + v[2] * v[2] + v[3] * v[3];
    #pragma unroll
    for (int o = 32; o > 0; o >>= 1) ss += __shfl_down(ss, o);
    if (lane == 0) red[wid] = ss;
    __syncthreads();
    ss = red[0] + red[1] + red[2] + red[3];

    float inv = 1.f / fmaxf(sqrtf(ss), 1e-8f);
    ushort4 ho, lo;
    float s0 = v[0] * inv, s1 = v[1] * inv, s2 = v[2] * inv, s3 = v[3] * inv;
    ho.x = f2bf(s0); lo.x = f2bf(s0 - bf2f(ho.x));
    ho.y = f2bf(s1); lo.y = f2bf(s1 - bf2f(ho.y));
    ho.z = f2bf(s2); lo.z = f2bf(s2 - bf2f(ho.z));
    ho.w = f2bf(s3); lo.w = f2bf(s3 - bf2f(ho.w));
    *(ushort4*)&oH[row * EMB + t * 4] = ho;
    *(ushort4*)&oL[row * EMB + t * 4] = lo;
}

__global__ __launch_bounds__(256)
void add_pos_pair(const float* __restrict__ in, const float* __restrict__ pos,
                  unsigned short* __restrict__ oH, unsigned short* __restrict__ oL)
{
    ull i = ((ull)blockIdx.x * 256 + threadIdx.x) * 4;
    float4 a = *(const float4*)&in[i];
    float4 p = *(const float4*)&pos[(int)(i & (EMB - 1))];
    float w[4] = { a.x + p.x, a.y + p.y, a.z + p.z, a.w + p.w };
    ushort4 ho, lo;
    ho.x = f2bf(w[0]); lo.x = f2bf(w[0] - bf2f(ho.x));
    ho.y = f2bf(w[1]); lo.y = f2bf(w[1] - bf2f(ho.y));
    ho.z = f2bf(w[2]); lo.z = f2bf(w[2] - bf2f(ho.z));
    ho.w = f2bf(w[3]); lo.w = f2bf(w[3] - bf2f(ho.w));
    *(ushort4*)&oH[i] = ho;
    *(ushort4*)&oL[i] = lo;
}

__global__ __launch_bounds__(256)
void split_pair(const float* __restrict__ in, unsigned short* __restrict__ oH,
                unsigned short* __restrict__ oL)
{
    ull i = ((ull)blockIdx.x * 256 + threadIdx.x) * 4;
    float4 a = *(const float4*)&in[i];
    float w[4] = { a.x, a.y, a.z, a.w };
    ushort4 ho, lo;
    ho.x = f2bf(w[0]); lo.x = f2bf(w[0] - bf2f(ho.x));
    ho.y = f2bf(w[1]); lo.y = f2bf(w[1] - bf2f(ho.y));
    ho.z = f2bf(w[2]); lo.z = f2bf(w[2] - bf2f(ho.z));
    ho.w = f2bf(w[3]); lo.w = f2bf(w[3] - bf2f(ho.w));
    *(ushort4*)&oH[i] = ho;
    *(ushort4*)&oL[i] = lo;
}

// f32 -> bf16 cast (hi only), 4 elems/thread
__global__ __launch_bounds__(256)
void cast_bf16(const float* __restrict__ in, unsigned short* __restrict__ out)
{
    ull i = ((ull)blockIdx.x * 256 + threadIdx.x) * 4;
    float4 a = *(const float4*)&in[i];
    ushort4 ho;
    ho.x = f2bf(a.x); ho.y = f2bf(a.y); ho.z = f2bf(a.z); ho.w = f2bf(a.w);
    *(ushort4*)&out[i] = ho;
}

// ---------------------------------------------------------------------------
namespace {

template<int S, int O>
inline void G(dim3 grid,
              const unsigned short* Ah, const unsigned short* Al, int lda, ll sAz,
              const unsigned short* Bh, const unsigned short* Bl, int ldb, ll sBz,
              void* Ch, void* Cl, int ldc, ll sCz,
              int K, float alpha, const float* bias, int biasRow,
              const unsigned short* rh, const unsigned short* rl, ll sRz, int rm,
              hipStream_t st)
{
    gemm_mfma<S, O><<<grid, dim3(256), 0, st>>>(Ah, Al, lda, sAz, Bh, Bl, ldb, sBz,
                                                Ch, Cl, ldc, sCz, K, alpha, bias, biasRow,
                                                rh, rl, sRz, rm);
}

struct Bufs {
    unsigned short *Ph[6], *Pl[6];
    unsigned short *ATTh, *QK, *VT, *Wih, *Woh, *Wol, *Opart;
    float *ml;
};

// batch mhas sharing (in_w,out_w): z in [0,batch). q input = qh + z*sQ,
// k/v input = kh + z*sK, dest = dsth/dstl + z*2TE, res = resh/resl + z*sR.
void run_mha(int batch,
             const unsigned short* qh, ll sQ,
             const unsigned short* kh, ll sK,
             const float* in_w, const float* in_b,
             const float* out_w, const float* out_b,
             unsigned short* dsth, unsigned short* dstl,
             const unsigned short* resh, const unsigned short* resl, ll sR, int resMode,
             const Bufs& B, bool convW, hipStream_t s)
{
    const ull EE = (ull)EMB * EMB;
    const ll  TE = (ll)NTOK * EMB;
    const ll  VTBS = (ll)1024 * 4096;
    if (convW) {
        cast_bf16<<<3 * EE / 1024, 256, 0, s>>>(in_w, B.Wih);
        split_pair<<<EE / 1024, 256, 0, s>>>(out_w, B.Woh, B.Wol);
    }
    // fused Q+K projection: z = b*2 + {0:Q, 1:K}
    gemm_qkproj<<<dim3(8, 32, 2 * batch), 256, 0, s>>>(
        qh, kh, qh + sQ, kh + sK, B.Wih, B.QK, in_b);
    // V^T proj: C[b][d][token] = Wv[d,:]·feat[token,:] + b_v[d]  (bias-row)
    G<1, 1>(dim3(32, 8, batch), B.Wih + 2 * EE, nullptr, EMB, 0, kh, nullptr, EMB, sK,
            B.VT, nullptr, 4096, VTBS, EMB, 1.f, in_b + 2 * EMB, 1, nullptr, nullptr, 0, 0, s);

    if (batch == 1) {
        flash_attn<4><<<dim3(32, 4, 4), 256, 0, s>>>(B.QK, B.VT, B.Opart, B.ml);
        flash_combine<4><<<NTOK, 256, 0, s>>>(B.Opart, B.ml, B.ATTh);
    } else {
        flash_attn<2><<<dim3(32, 2, 4 * batch), 256, 0, s>>>(B.QK, B.VT, B.Opart, B.ml);
        flash_combine<2><<<batch * NTOK, 256, 0, s>>>(B.Opart, B.ml, B.ATTh);
    }

    // out-proj: A = att (hi only) x weight pair -> dest pair (+res epilogue)
    G<2, 2>(dim3(8, 32, batch), B.ATTh, nullptr, EMB, TE, B.Woh, B.Wol, EMB, 0,
            dsth, dstl, EMB, 2 * TE, EMB, 1.f, out_b, 0, resh, resl, sR, resMode, s);
}

} // namespace

extern "C" void kernel_launch(void* const* d_in, const int* in_sizes, int n_in,
                              void* d_out, int out_size, void* d_ws, size_t ws_size,
                              hipStream_t stream) {
    const float* local_feat  = (const float*)d_in[0];
    const float* global_feat = (const float*)d_in[1];
    const float* text_feat   = (const float*)d_in[2];
    const float* pos_l       = (const float*)d_in[3];
    const float* pos_g       = (const float*)d_in[4];
    const float* fc_w        = (const float*)d_in[5];
    const float* fc_b        = (const float*)d_in[6];
    const float* lg_in_w     = (const float*)d_in[7];
    const float* lg_in_b     = (const float*)d_in[8];
    const float* lg_out_w    = (const float*)d_in[9];
    const float* lg_out_b    = (const float*)d_in[10];
    const float* vt_in_w     = (const float*)d_in[11];
    const float* vt_in_b     = (const float*)d_in[12];
    const float* vt_out_w    = (const float*)d_in[13];
    const float* vt_out_b    = (const float*)d_in[14];
    const float* ml_in_w     = (const float*)d_in[15];
    const float* ml_in_b     = (const float*)d_in[16];
    const float* ml_out_w    = (const float*)d_in[17];
    const float* ml_out_b    = (const float*)d_in[18];
    float* out = (float*)d_out;

    const ull TE = (ull)NTOK * EMB;
    const ull EE = (ull)EMB * EMB;
    unsigned short* w = (unsigned short*)d_ws;
    Bufs B;
    for (int i = 0; i < 6; ++i) { B.Ph[i] = w + (2 * i) * TE; B.Pl[i] = w + (2 * i + 1) * TE; }
    B.ATTh  = w + 12 * TE;              // 2 TE (batch 2)
    B.QK    = w + 14 * TE;              // 4 TE (batch 2)
    B.VT    = w + 18 * TE;              // 2 TE
    B.Opart = w + 20 * TE;              // 4 TE (max: batch2 x 2 splits, b1 x 4)
    B.ml    = (float*)(w + 24 * TE);    // 1 MB
    B.Wih   = w + 25 * TE;              // 3 EE
    B.Woh   = B.Wih + 3 * EE;           // EE
    B.Wol   = B.Woh + EE;               // EE

    add_pos_pair<<<TE / 1024, 256, 0, stream>>>(local_feat, pos_l, B.Ph[0], B.Pl[0]);
    add_pos_pair<<<TE / 1024, 256, 0, stream>>>(global_feat, pos_g, B.Ph[1], B.Pl[1]);

    // tf = text @ fc_w^T + fc_b -> P2 pair (text pair staged in QK scratch,
    // fc weight pair in Woh/Wol — both overwritten by the first mha round)
    split_pair<<<TE / 1024, 256, 0, stream>>>(text_feat, B.QK, B.QK + TE);
    split_pair<<<EE / 1024, 256, 0, stream>>>(fc_w, B.Woh, B.Wol);
    G<3, 2>(dim3(EMB / 128, NTOK / 128), B.QK, B.QK + TE, EMB, 0, B.Woh, B.Wol, EMB, 0,
            B.Ph[2], B.Pl[2], EMB, 0, EMB, 1.f, fc_b, 0, nullptr, nullptr, 0, 0, stream);

    const ll T2 = (ll)2 * TE, T4 = (ll)4 * TE;
    // round 1: local_global = mha(lf, gf; lg) + lf           -> P3
    run_mha(1, B.Ph[0], 0, B.Ph[1], 0, lg_in_w, lg_in_b, lg_out_w, lg_out_b,
            B.Ph[3], B.Pl[3], B.Ph[0], B.Pl[0], 0, 1, B, true, stream);
    // round 2 (batch): text_local = mha(tf, lf; vt)+lf -> P4
    //                  text_global = mha(tf, gf; vt)+tf -> P5
    run_mha(2, B.Ph[2], 0, B.Ph[0], T2, vt_in_w, vt_in_b, vt_out_w, vt_out_b,
            B.Ph[4], B.Pl[4], B.Ph[0], B.Pl[0], T4, 1, B, true, stream);
    // round 3 (batch): gt_gl = mha(P3, P5; ml) -> P0
    //                  gl_lt = mha(P4, P3; ml) -> P1
    run_mha(2, B.Ph[3], T2, B.Ph[5], -T4, ml_in_w, ml_in_b, ml_out_w, ml_out_b,
            B.Ph[0], B.Pl[0], nullptr, nullptr, 0, 0, B, true, stream);
    // round 4: full = mha(gl_lt=P1, gt_gl=P0; ml)            -> P3
    run_mha(1, B.Ph[1], 0, B.Ph[0], 0, ml_in_w, ml_in_b, ml_out_w, ml_out_b,
            B.Ph[3], B.Pl[3], nullptr, nullptr, 0, 0, B, false, stream);
    // round 5: fusion = mha(tf=P2, full=P3; ml) * tf         -> P4
    run_mha(1, B.Ph[2], 0, B.Ph[3], 0, ml_in_w, ml_in_b, ml_out_w, ml_out_b,
            B.Ph[4], B.Pl[4], B.Ph[2], B.Pl[2], 0, 2, B, false, stream);

    l2norm_rows<false><<<NTOK, 256, 0, stream>>>(nullptr, B.Ph[4], B.Pl[4], B.Ph[4], B.Pl[4]);
    l2norm_rows<true ><<<NTOK, 256, 0, stream>>>(local_feat, nullptr, nullptr, B.Ph[5], B.Pl[5]);

    G<3, 0>(dim3(QTY / 128, QTY / 128, 8),
            B.Ph[4], B.Pl[4], EMB, (ll)QTY * EMB,
            B.Ph[5], B.Pl[5], EMB, (ll)QTY * EMB,
            out, nullptr, QTY, (ll)QTY * QTY,
            EMB, 1.f, nullptr, 0, nullptr, nullptr, 0, 0, stream);
}

// Round 14
// 1684.859 us; speedup vs baseline: 1.2349x; 1.2349x over previous
//
#include <hip/hip_runtime.h>
#include <hip/hip_bf16.h>

// FilterModule: 7x MHA fusion pipeline, bf16 MFMA + flash attention v13.
// v13 = v11/R12 (measured best, 1687us) + two in-structure flash wins:
//   - z-major 1D grid (z = bid&7): block->XCD assignment aligns with the
//     8 (b,sp,h) groups so each XCD's L2 owns one K/V working set
//   - defer-max THR=5.545 (T13): skip O-rescale unless tile max grows >THR
// Flash geometry LOCKED at v7 (8 waves x 16q, KVB=64 dbuf, VGPR 96): the
// register-blocked variants failed 4x (R4/R5 spill, R11/R13 occupancy).

typedef __attribute__((ext_vector_type(8))) short short8;
typedef __attribute__((ext_vector_type(4))) float f32x4;
typedef unsigned long long ull;
typedef long long ll;

namespace {
constexpr int NTOK = 4096;
constexpr int EMB  = 1024;
constexpr int QTY  = 512;
}

__device__ __forceinline__ float bf2f(unsigned short u) {
    union { float f; unsigned int i; } x; x.i = ((unsigned int)u) << 16; return x.f;
}
__device__ __forceinline__ unsigned short f2bf(float f) {
    union { float f; unsigned int i; } x; x.f = f;
    unsigned int r = x.i + 0x7fffu + ((x.i >> 16) & 1u);
    return (unsigned short)(r >> 16);
}

#define GLOAD_LDS16(g, l) __builtin_amdgcn_global_load_lds( \
    (const __attribute__((address_space(1))) void*)(g),     \
    (__attribute__((address_space(3))) void*)(l), 16, 0, 0)

// ---------------------------------------------------------------------------
// MFMA GEMM (B^T layout): C[m][n] = alpha*sum_k A[m][k]*B[n][k] (+epilogue).
// 128x128 tile, BK=32, 256 thr. Signed z-strides for batched launches.
template<int SPLITS, int OUTM>
__global__ __launch_bounds__(256)
void gemm_mfma(const unsigned short* __restrict__ Ah, const unsigned short* __restrict__ Al,
               int lda, ll sAz,
               const unsigned short* __restrict__ Bh, const unsigned short* __restrict__ Bl,
               int ldb, ll sBz,
               void* __restrict__ Cp, void* __restrict__ Clp,
               int ldc, ll sCz,
               int K, float alpha, const float* __restrict__ bias, int biasRow,
               const unsigned short* __restrict__ resH, const unsigned short* __restrict__ resL,
               ll sRz, int resMode)
{
    constexpr int NTILES = (SPLITS == 3 ? 4 : (SPLITS == 2 ? 3 : 2));
    constexpr int TSZ = 128 * 32;
    __shared__ unsigned short lds[NTILES * TSZ];  // Ah | Bh | [Bl] | [Al]
    const int tid  = threadIdx.x;
    const int brow = blockIdx.y * 128;
    const int bcol = blockIdx.x * 128;
    const ll   z   = blockIdx.z;
    Ah += z * sAz; Bh += z * sBz;
    if constexpr (SPLITS == 3) Al += z * sAz;
    if constexpr (SPLITS >= 2) Bl += z * sBz;

    const int lane = tid & 63;
    const int wv = tid >> 6, wr = wv >> 1, wc = wv & 1;
    const int l15 = lane & 15, l4 = lane >> 4;

    f32x4 acc[4][4];
    #pragma unroll
    for (int m = 0; m < 4; ++m)
        #pragma unroll
        for (int n = 0; n < 4; ++n) acc[m][n] = (f32x4){0.f, 0.f, 0.f, 0.f};

    for (int k0 = 0; k0 < K; k0 += 32) {
        #pragma unroll
        for (int i = 0; i < 2; ++i) {
            int idx = tid + i * 256;
            int row = idx >> 2;
            int kc  = (idx & 3) ^ ((row >> 1) & 3);
            GLOAD_LDS16(Ah + (ull)(brow + row) * lda + k0 + kc * 8, &lds[idx * 8]);
            GLOAD_LDS16(Bh + (ull)(bcol + row) * ldb + k0 + kc * 8, &lds[TSZ + idx * 8]);
            if constexpr (SPLITS >= 2)
                GLOAD_LDS16(Bl + (ull)(bcol + row) * ldb + k0 + kc * 8, &lds[2 * TSZ + idx * 8]);
            if constexpr (SPLITS == 3)
                GLOAD_LDS16(Al + (ull)(brow + row) * lda + k0 + kc * 8, &lds[3 * TSZ + idx * 8]);
        }
        __syncthreads();

        short8 ah[4], bh[4], bl2[4], al2[4];
        #pragma unroll
        for (int m = 0; m < 4; ++m) {
            int rr = wr * 64 + m * 16 + l15;
            int sl = l4 ^ ((rr >> 1) & 3);
            int off = rr * 32 + sl * 8;
            ah[m] = *(const short8*)&lds[off];
            if constexpr (SPLITS == 3) al2[m] = *(const short8*)&lds[3 * TSZ + off];
        }
        #pragma unroll
        for (int n = 0; n < 4; ++n) {
            int rr = wc * 64 + n * 16 + l15;
            int sl = l4 ^ ((rr >> 1) & 3);
            int off = rr * 32 + sl * 8;
            bh[n] = *(const short8*)&lds[TSZ + off];
            if constexpr (SPLITS >= 2) bl2[n] = *(const short8*)&lds[2 * TSZ + off];
        }
        #pragma unroll
        for (int m = 0; m < 4; ++m)
            #pragma unroll
            for (int n = 0; n < 4; ++n) {
                acc[m][n] = __builtin_amdgcn_mfma_f32_16x16x32_bf16(ah[m], bh[n], acc[m][n], 0, 0, 0);
                if constexpr (SPLITS >= 2)
                    acc[m][n] = __builtin_amdgcn_mfma_f32_16x16x32_bf16(ah[m], bl2[n], acc[m][n], 0, 0, 0);
                if constexpr (SPLITS == 3)
                    acc[m][n] = __builtin_amdgcn_mfma_f32_16x16x32_bf16(al2[m], bh[n], acc[m][n], 0, 0, 0);
            }
        __syncthreads();
    }

    float* Cf = (float*)Cp + z * sCz;
    unsigned short* Ch = (unsigned short*)Cp + z * sCz;
    unsigned short* Cl = (unsigned short*)Clp + z * sCz;
    const unsigned short* rH = resH + z * sRz;
    const unsigned short* rL = resL + z * sRz;
    const int rowB = brow + wr * 64 + l4 * 4;
    const int colB = bcol + wc * 64 + l15;
    #pragma unroll
    for (int n = 0; n < 4; ++n) {
        int col = colB + n * 16;
        #pragma unroll
        for (int m = 0; m < 4; ++m) {
            #pragma unroll
            for (int r = 0; r < 4; ++r) {
                int row = rowB + m * 16 + r;
                ull ci = (ull)row * ldc + col;
                float v = acc[m][n][r] * alpha;
                if (bias) v += biasRow ? bias[row] : bias[col];
                if (resMode == 1)      v += bf2f(rH[ci]) + bf2f(rL[ci]);
                else if (resMode == 2) v *= bf2f(rH[ci]) + bf2f(rL[ci]);
                if constexpr (OUTM == 0)      Cf[ci] = v;
                else if constexpr (OUTM == 1) Ch[ci] = f2bf(v);
                else {
                    unsigned short h = f2bf(v);
                    Ch[ci] = h;
                    Cl[ci] = f2bf(v - bf2f(h));
                }
            }
        }
    }
}

// ---------------------------------------------------------------------------
// Fused Q+K projection. z = b*2 + j (j: 0=Q, 1=K).
__global__ __launch_bounds__(256)
void gemm_qkproj(const unsigned short* a0, const unsigned short* a1,
                 const unsigned short* a2, const unsigned short* a3,
                 const unsigned short* __restrict__ W,
                 unsigned short* __restrict__ QK,
                 const float* __restrict__ bias)
{
    constexpr int TSZ = 128 * 32;
    __shared__ unsigned short lds[2 * TSZ];
    const int tid  = threadIdx.x;
    const int brow = blockIdx.y * 128;
    const int bcol = blockIdx.x * 128;
    const int z = blockIdx.z;
    const int j = z & 1, bb = z >> 1;
    const unsigned short* Ah = (z == 0) ? a0 : (z == 1) ? a1 : (z == 2) ? a2 : a3;
    const unsigned short* Bh = W + (ull)j * EMB * EMB;
    unsigned short* C = QK + (ull)bb * NTOK * 2048 + j * 1024;
    const float* bi = bias + j * 1024;

    const int lane = tid & 63;
    const int wv = tid >> 6, wr = wv >> 1, wc = wv & 1;
    const int l15 = lane & 15, l4 = lane >> 4;

    f32x4 acc[4][4];
    #pragma unroll
    for (int m = 0; m < 4; ++m)
        #pragma unroll
        for (int n = 0; n < 4; ++n) acc[m][n] = (f32x4){0.f, 0.f, 0.f, 0.f};

    for (int k0 = 0; k0 < EMB; k0 += 32) {
        #pragma unroll
        for (int i = 0; i < 2; ++i) {
            int idx = tid + i * 256;
            int row = idx >> 2;
            int kc  = (idx & 3) ^ ((row >> 1) & 3);
            GLOAD_LDS16(Ah + (ull)(brow + row) * EMB + k0 + kc * 8, &lds[idx * 8]);
            GLOAD_LDS16(Bh + (ull)(bcol + row) * EMB + k0 + kc * 8, &lds[TSZ + idx * 8]);
        }
        __syncthreads();

        short8 ah[4], bh[4];
        #pragma unroll
        for (int m = 0; m < 4; ++m) {
            int rr = wr * 64 + m * 16 + l15;
            int sl = l4 ^ ((rr >> 1) & 3);
            ah[m] = *(const short8*)&lds[rr * 32 + sl * 8];
        }
        #pragma unroll
        for (int n = 0; n < 4; ++n) {
            int rr = wc * 64 + n * 16 + l15;
            int sl = l4 ^ ((rr >> 1) & 3);
            bh[n] = *(const short8*)&lds[TSZ + rr * 32 + sl * 8];
        }
        #pragma unroll
        for (int m = 0; m < 4; ++m)
            #pragma unroll
            for (int n = 0; n < 4; ++n)
                acc[m][n] = __builtin_amdgcn_mfma_f32_16x16x32_bf16(ah[m], bh[n], acc[m][n], 0, 0, 0);
        __syncthreads();
    }

    const int rowB = brow + wr * 64 + l4 * 4;
    const int colB = bcol + wc * 64 + l15;
    #pragma unroll
    for (int n = 0; n < 4; ++n) {
        int col = colB + n * 16;
        float bv = bi[col];
        #pragma unroll
        for (int m = 0; m < 4; ++m)
            #pragma unroll
            for (int r = 0; r < 4; ++r) {
                int row = rowB + m * 16 + r;
                C[(ull)row * 2048 + col] = f2bf(acc[m][n][r] + bv);
            }
    }
}

// ---------------------------------------------------------------------------
// Flash attention (v7 structure, LOCKED). 1D grid of 256 blocks:
// z = bid&7 (aligns with XCD = id%8 so each XCD's L2 owns one K/V set),
// qt = bid>>3. NSPLIT=2 (batch=1): z = sp*4+h. NSPLIT=1 (batch=2): z = b*4+h.
// QK [batch][4096][2048]; VT [batch][1024][4096].
template<int NSPLIT>
__global__ __launch_bounds__(512)
void flash_attn(const unsigned short* __restrict__ QK,
                const unsigned short* __restrict__ VT,
                unsigned short* __restrict__ Opart, float* __restrict__ ml,
                unsigned short* __restrict__ attH)
{
    constexpr int KVB = 64;
    constexpr int NTILE = (NTOK / NSPLIT) / KVB;
    __shared__ unsigned short Kt[2][KVB * 256];   // [kv][d], 16B-chunk-swizzled
    __shared__ unsigned short Vt[2][256 * KVB];   // [d][kv], swizzled

    const int tid = threadIdx.x;
    const int w = tid >> 6, lane = tid & 63;
    const int l15 = lane & 15, l4 = lane >> 4;
    const int bid = blockIdx.x;
    const int zz = bid & 7, qt = bid >> 3;
    const int h = zz & 3;
    int b, sp;
    if constexpr (NSPLIT == 2) { b = 0; sp = zz >> 2; }
    else                       { b = zz >> 2; sp = 0; }
    const int qrow = qt * 128 + w * 16 + l15;
    const int kv0 = sp * (NTOK / NSPLIT);
    const unsigned short* QKb = QK + (ull)b * NTOK * 2048;
    const unsigned short* VTb = VT + (ull)b * 1024 * 4096;

    // Q fragments in registers, pre-scaled by 1/sqrt(d)=1/16 (exact in bf16)
    short8 qreg[8];
    {
        const unsigned short* qp = QKb + (ull)qrow * 2048 + h * 256;
        #pragma unroll
        for (int c = 0; c < 8; ++c) {
            short8 x = *(const short8*)&qp[c * 32 + l4 * 8];
            #pragma unroll
            for (int j = 0; j < 8; ++j)
                x[j] = (short)f2bf(bf2f((unsigned short)x[j]) * 0.0625f);
            qreg[c] = x;
        }
    }

    f32x4 oacc[16];
    #pragma unroll
    for (int dn = 0; dn < 16; ++dn) oacc[dn] = (f32x4){0.f, 0.f, 0.f, 0.f};
    float m_r = -1e30f, l_r = 0.f;

    auto stage = [&](int t, int buf) {
        int base = kv0 + t * KVB;
        #pragma unroll
        for (int i = 0; i < 4; ++i) {       // K tile: 64 rows x 32 chunks
            int s = tid + i * 512;
            int r = s >> 5, c = s & 31;
            int c0 = c ^ (r & 7);
            GLOAD_LDS16(QKb + (ull)(base + r) * 2048 + 1024 + h * 256 + c0 * 8,
                        &Kt[buf][s * 8]);
        }
        #pragma unroll
        for (int i = 0; i < 4; ++i) {       // V^T tile: 256 rows x 8 chunks
            int s = tid + i * 512;
            int r = s >> 3, c = s & 7;
            int c0 = c ^ (r & 7);
            GLOAD_LDS16(VTb + (ull)(h * 256 + r) * 4096 + base + c0 * 8,
                        &Vt[buf][s * 8]);
        }
    };

    stage(0, 0);
    for (int t = 0; t < NTILE; ++t) {
        if (t + 1 < NTILE) {
            stage(t + 1, (t + 1) & 1);
            asm volatile("s_waitcnt vmcnt(8)");
        } else {
            asm volatile("s_waitcnt vmcnt(0)");
        }
        __builtin_amdgcn_s_barrier();

        const unsigned short* Kb = Kt[t & 1];
        const unsigned short* Vb = Vt[t & 1];

        // QK^T (swapped): sacc[fk] = S^T tile, lane: q=l15, kv=fk*16+l4*4+r
        f32x4 sacc[4];
        #pragma unroll
        for (int fk = 0; fk < 4; ++fk) sacc[fk] = (f32x4){0.f, 0.f, 0.f, 0.f};
        #pragma unroll
        for (int fk = 0; fk < 4; ++fk) {
            int r = fk * 16 + l15;
            int rx = r & 7;
            #pragma unroll
            for (int c = 0; c < 8; ++c) {
                int ch = (4 * c + l4) ^ rx;
                short8 kf = *(const short8*)&Kb[r * 256 + ch * 8];
                sacc[fk] = __builtin_amdgcn_mfma_f32_16x16x32_bf16(kf, qreg[c], sacc[fk], 0, 0, 0);
            }
        }

        // online softmax (per q-row = per l15; reduce over l4 groups)
        float tm = sacc[0][0];
        #pragma unroll
        for (int fk = 0; fk < 4; ++fk)
            #pragma unroll
            for (int rr = 0; rr < 4; ++rr) tm = fmaxf(tm, sacc[fk][rr]);
        tm = fmaxf(tm, __shfl_xor(tm, 16));
        tm = fmaxf(tm, __shfl_xor(tm, 32));

        // defer-max (T13): rescale only when tile max exceeds running max + THR
        bool nomax = __all(tm <= m_r + 5.545f);
        if (!nomax) {
            float mnew = fmaxf(m_r, tm);
            float corr = __expf(m_r - mnew);
            float c4[4];
            #pragma unroll
            for (int r = 0; r < 4; ++r) c4[r] = __shfl(corr, l4 * 4 + r);
            #pragma unroll
            for (int dn = 0; dn < 16; ++dn)
                #pragma unroll
                for (int r = 0; r < 4; ++r) oacc[dn][r] *= c4[r];
            l_r *= corr;
            m_r = mnew;
        }

        float p[16]; float ls = 0.f;
        #pragma unroll
        for (int fk = 0; fk < 4; ++fk)
            #pragma unroll
            for (int rr = 0; rr < 4; ++rr) {
                float e = __expf(sacc[fk][rr] - m_r);
                p[fk * 4 + rr] = e; ls += e;
            }
        ls += __shfl_xor(ls, 16);
        ls += __shfl_xor(ls, 32);
        l_r += ls;

        // pack P to bf16 pairs: W[f][pp] = kv (16f+4*l4+2pp, +1) for q=l15
        unsigned int W[4][2];
        #pragma unroll
        for (int f = 0; f < 4; ++f)
            #pragma unroll
            for (int pp = 0; pp < 2; ++pp)
                W[f][pp] = (unsigned int)f2bf(p[f * 4 + 2 * pp]) |
                           ((unsigned int)f2bf(p[f * 4 + 2 * pp + 1]) << 16);

        // gather to A-frag layout: lane q=l15, kv = c*32 + l4*8 + j
        const int sbase = l15 + ((l4 & 1) << 5);
        const bool hi = (l4 >> 1) & 1;
        #pragma unroll
        for (int kvc = 0; kvc < 2; ++kvc) {
            unsigned int a0 = (unsigned int)__shfl((int)W[2 * kvc][0], sbase);
            unsigned int a1 = (unsigned int)__shfl((int)W[2 * kvc][1], sbase);
            unsigned int a2 = (unsigned int)__shfl((int)W[2 * kvc][0], sbase + 16);
            unsigned int a3 = (unsigned int)__shfl((int)W[2 * kvc][1], sbase + 16);
            unsigned int b0 = (unsigned int)__shfl((int)W[2 * kvc + 1][0], sbase);
            unsigned int b1 = (unsigned int)__shfl((int)W[2 * kvc + 1][1], sbase);
            unsigned int b2 = (unsigned int)__shfl((int)W[2 * kvc + 1][0], sbase + 16);
            unsigned int b3 = (unsigned int)__shfl((int)W[2 * kvc + 1][1], sbase + 16);
            union { unsigned int u[4]; short8 s8; } pa;
            pa.u[0] = hi ? b0 : a0; pa.u[1] = hi ? b1 : a1;
            pa.u[2] = hi ? b2 : a2; pa.u[3] = hi ? b3 : a3;

            // PV: oacc[dn] += P[q, kv32] * V^T[d, kv32]
            #pragma unroll
            for (int dn = 0; dn < 16; ++dn) {
                int row = dn * 16 + l15;
                int ch = (kvc * 4 + l4) ^ (row & 7);
                short8 vf = *(const short8*)&Vb[row * 64 + ch * 8];
                oacc[dn] = __builtin_amdgcn_mfma_f32_16x16x32_bf16(pa.s8, vf, oacc[dn], 0, 0, 0);
            }
        }
        __builtin_amdgcn_s_barrier();
    }

    // epilogue: normalized O (bf16). lane: d=dn*16+l15, q=base+l4*4+r
    float inv = 1.f / l_r;
    float i4[4];
    #pragma unroll
    for (int r = 0; r < 4; ++r) i4[r] = __shfl(inv, l4 * 4 + r);

    if constexpr (NSPLIT == 2) {
        unsigned short* Ob = Opart + (((ull)b * 2 + sp) * 4 + h) * NTOK * 256;
        #pragma unroll
        for (int dn = 0; dn < 16; ++dn) {
            int d = dn * 16 + l15;
            #pragma unroll
            for (int r = 0; r < 4; ++r) {
                int q = qt * 128 + w * 16 + l4 * 4 + r;
                Ob[(ull)q * 256 + d] = f2bf(oacc[dn][r] * i4[r]);
            }
        }
        if (l4 == 0) {
            float2* mlp = (float2*)ml + (((ull)b * 2 + sp) * 4 + h) * NTOK + qrow;
            *mlp = make_float2(m_r, l_r);
        }
    } else {
        unsigned short* Ob = attH + (ull)b * NTOK * EMB;
        #pragma unroll
        for (int dn = 0; dn < 16; ++dn) {
            int d = dn * 16 + l15;
            #pragma unroll
            for (int r = 0; r < 4; ++r) {
                int q = qt * 128 + w * 16 + l4 * 4 + r;
                Ob[(ull)q * EMB + h * 256 + d] = f2bf(oacc[dn][r] * i4[r]);
            }
        }
    }
}

// ---------------------------------------------------------------------------
// merge 2 KV-split partials (normalized bf16) -> att bf16 (hi only).
// blockIdx.x = batch*4096 + q.
__global__ __launch_bounds__(256)
void flash_combine(const unsigned short* __restrict__ Opart, const float* __restrict__ ml,
                   unsigned short* __restrict__ attH)
{
    const int bx = blockIdx.x;
    const int b = bx >> 12, q = bx & 4095;
    const int t = threadIdx.x;
    const int h = t >> 6, d4 = (t & 63) * 4;

    float2 m0 = ((const float2*)ml)[(((ull)b * 2 + 0) * 4 + h) * NTOK + q];
    float2 m1 = ((const float2*)ml)[(((ull)b * 2 + 1) * 4 + h) * NTOK + q];
    float ms = fmaxf(m0.x, m1.x);
    float w0 = __expf(m0.x - ms) * m0.y;
    float w1 = __expf(m1.x - ms) * m1.y;
    float inv = 1.f / (w0 + w1);
    w0 *= inv; w1 *= inv;

    ushort4 o0 = *(const ushort4*)&Opart[((((ull)b * 2 + 0) * 4 + h) * NTOK + q) * 256 + d4];
    ushort4 o1 = *(const ushort4*)&Opart[((((ull)b * 2 + 1) * 4 + h) * NTOK + q) * 256 + d4];
    ushort4 ho;
    ho.x = f2bf(w0 * bf2f(o0.x) + w1 * bf2f(o1.x));
    ho.y = f2bf(w0 * bf2f(o0.y) + w1 * bf2f(o1.y));
    ho.z = f2bf(w0 * bf2f(o0.z) + w1 * bf2f(o1.z));
    ho.w = f2bf(w0 * bf2f(o0.w) + w1 * bf2f(o1.w));
    *(ushort4*)&attH[(ull)b * NTOK * EMB + (ull)q * EMB + h * 256 + d4] = ho;
}

// ---------------------------------------------------------------------------
template<bool F32IN>
__global__ __launch_bounds__(256)
void l2norm_rows(const float* __restrict__ inF, const unsigned short* __restrict__ inH,
                 const unsigned short* __restrict__ inL,
                 unsigned short* __restrict__ oH, unsigned short* __restrict__ oL)
{
    const ull row = blockIdx.x;
    const int t = threadIdx.x;
    const int lane = t & 63, wid = t >> 6;
    __shared__ float red[4];

    float v[4];
    if constexpr (F32IN) {
        float4 x = *(const float4*)&inF[row * EMB + t * 4];
        v[0] = x.x; v[1] = x.y; v[2] = x.z; v[3] = x.w;
    } else {
        ushort4 hh = *(const ushort4*)&inH[row * EMB + t * 4];
        ushort4 ll2 = *(const ushort4*)&inL[row * EMB + t * 4];
        v[0] = bf2f(hh.x) + bf2f(ll2.x); v[1] = bf2f(hh.y) + bf2f(ll2.y);
        v[2] = bf2f(hh.z) + bf2f(ll2.z); v[3] = bf2f(hh.w) + bf2f(ll2.w);
    }
    float ss = v[0] * v[0] + v[1] * v[1] + v[2] * v[2] + v[3] * v[3];
    #pragma unroll
    for (int o = 32; o > 0; o >>= 1) ss += __shfl_down(ss, o);
    if (lane == 0) red[wid] = ss;
    __syncthreads();
    ss = red[0] + red[1] + red[2] + red[3];

    float inv = 1.f / fmaxf(sqrtf(ss), 1e-8f);
    ushort4 ho, lo;
    float s0 = v[0] * inv, s1 = v[1] * inv, s2 = v[2] * inv, s3 = v[3] * inv;
    ho.x = f2bf(s0); lo.x = f2bf(s0 - bf2f(ho.x));
    ho.y = f2bf(s1); lo.y = f2bf(s1 - bf2f(ho.y));
    ho.z = f2bf(s2); lo.z = f2bf(s2 - bf2f(ho.z));
    ho.w = f2bf(s3); lo.w = f2bf(s3 - bf2f(ho.w));
    *(ushort4*)&oH[row * EMB + t * 4] = ho;
    *(ushort4*)&oL[row * EMB + t * 4] = lo;
}

__global__ __launch_bounds__(256)
void add_pos_pair(const float* __restrict__ in, const float* __restrict__ pos,
                  unsigned short* __restrict__ oH, unsigned short* __restrict__ oL)
{
    ull i = ((ull)blockIdx.x * 256 + threadIdx.x) * 4;
    float4 a = *(const float4*)&in[i];
    float4 p = *(const float4*)&pos[(int)(i & (EMB - 1))];
    float w[4] = { a.x + p.x, a.y + p.y, a.z + p.z, a.w + p.w };
    ushort4 ho, lo;
    ho.x = f2bf(w[0]); lo.x = f2bf(w[0] - bf2f(ho.x));
    ho.y = f2bf(w[1]); lo.y = f2bf(w[1] - bf2f(ho.y));
    ho.z = f2bf(w[2]); lo.z = f2bf(w[2] - bf2f(ho.z));
    ho.w = f2bf(w[3]); lo.w = f2bf(w[3] - bf2f(ho.w));
    *(ushort4*)&oH[i] = ho;
    *(ushort4*)&oL[i] = lo;
}

__global__ __launch_bounds__(256)
void split_pair(const float* __restrict__ in, unsigned short* __restrict__ oH,
                unsigned short* __restrict__ oL)
{
    ull i = ((ull)blockIdx.x * 256 + threadIdx.x) * 4;
    float4 a = *(const float4*)&in[i];
    float w[4] = { a.x, a.y, a.z, a.w };
    ushort4 ho, lo;
    ho.x = f2bf(w[0]); lo.x = f2bf(w[0] - bf2f(ho.x));
    ho.y = f2bf(w[1]); lo.y = f2bf(w[1] - bf2f(ho.y));
    ho.z = f2bf(w[2]); lo.z = f2bf(w[2] - bf2f(ho.z));
    ho.w = f2bf(w[3]); lo.w = f2bf(w[3] - bf2f(ho.w));
    *(ushort4*)&oH[i] = ho;
    *(ushort4*)&oL[i] = lo;
}

// f32 -> bf16 cast (hi only), 4 elems/thread
__global__ __launch_bounds__(256)
void cast_bf16(const float* __restrict__ in, unsigned short* __restrict__ out)
{
    ull i = ((ull)blockIdx.x * 256 + threadIdx.x) * 4;
    float4 a = *(const float4*)&in[i];
    ushort4 ho;
    ho.x = f2bf(a.x); ho.y = f2bf(a.y); ho.z = f2bf(a.z); ho.w = f2bf(a.w);
    *(ushort4*)&out[i] = ho;
}

// ---------------------------------------------------------------------------
namespace {

template<int S, int O>
inline void G(dim3 grid,
              const unsigned short* Ah, const unsigned short* Al, int lda, ll sAz,
              const unsigned short* Bh, const unsigned short* Bl, int ldb, ll sBz,
              void* Ch, void* Cl, int ldc, ll sCz,
              int K, float alpha, const float* bias, int biasRow,
              const unsigned short* rh, const unsigned short* rl, ll sRz, int rm,
              hipStream_t st)
{
    gemm_mfma<S, O><<<grid, dim3(256), 0, st>>>(Ah, Al, lda, sAz, Bh, Bl, ldb, sBz,
                                                Ch, Cl, ldc, sCz, K, alpha, bias, biasRow,
                                                rh, rl, sRz, rm);
}

struct Bufs {
    unsigned short *Ph[6], *Pl[6];
    unsigned short *ATTh, *QK, *VT, *Wih, *Woh, *Wol, *Opart;
    float *ml;
};

// batch mhas sharing (in_w,out_w): z in [0,batch). q input = qh + z*sQ,
// k/v input = kh + z*sK, dest = dsth/dstl + z*2TE, res = resh/resl + z*sR.
void run_mha(int batch,
             const unsigned short* qh, ll sQ,
             const unsigned short* kh, ll sK,
             const float* in_w, const float* in_b,
             const float* out_w, const float* out_b,
             unsigned short* dsth, unsigned short* dstl,
             const unsigned short* resh, const unsigned short* resl, ll sR, int resMode,
             const Bufs& B, bool convW, hipStream_t s)
{
    const ull EE = (ull)EMB * EMB;
    const ll  TE = (ll)NTOK * EMB;
    const ll  VTBS = (ll)1024 * 4096;
    if (convW) {
        cast_bf16<<<3 * EE / 1024, 256, 0, s>>>(in_w, B.Wih);
        split_pair<<<EE / 1024, 256, 0, s>>>(out_w, B.Woh, B.Wol);
    }
    // fused Q+K projection: z = b*2 + {0:Q, 1:K}
    gemm_qkproj<<<dim3(8, 32, 2 * batch), 256, 0, s>>>(
        qh, kh, qh + sQ, kh + sK, B.Wih, B.QK, in_b);
    // V^T proj: C[b][d][token] = Wv[d,:]·feat[token,:] + b_v[d]  (bias-row)
    G<1, 1>(dim3(32, 8, batch), B.Wih + 2 * EE, nullptr, EMB, 0, kh, nullptr, EMB, sK,
            B.VT, nullptr, 4096, VTBS, EMB, 1.f, in_b + 2 * EMB, 1, nullptr, nullptr, 0, 0, s);

    if (batch == 1) {
        flash_attn<2><<<256, 512, 0, s>>>(B.QK, B.VT, B.Opart, B.ml, B.ATTh);
        flash_combine<<<NTOK, 256, 0, s>>>(B.Opart, B.ml, B.ATTh);
    } else {
        flash_attn<1><<<256, 512, 0, s>>>(B.QK, B.VT, B.Opart, B.ml, B.ATTh);
    }

    // out-proj: A = att (hi only) x weight pair -> dest pair (+res epilogue)
    G<2, 2>(dim3(8, 32, batch), B.ATTh, nullptr, EMB, TE, B.Woh, B.Wol, EMB, 0,
            dsth, dstl, EMB, 2 * TE, EMB, 1.f, out_b, 0, resh, resl, sR, resMode, s);
}

} // namespace

extern "C" void kernel_launch(void* const* d_in, const int* in_sizes, int n_in,
                              void* d_out, int out_size, void* d_ws, size_t ws_size,
                              hipStream_t stream) {
    const float* local_feat  = (const float*)d_in[0];
    const float* global_feat = (const float*)d_in[1];
    const float* text_feat   = (const float*)d_in[2];
    const float* pos_l       = (const float*)d_in[3];
    const float* pos_g       = (const float*)d_in[4];
    const float* fc_w        = (const float*)d_in[5];
    const float* fc_b        = (const float*)d_in[6];
    const float* lg_in_w     = (const float*)d_in[7];
    const float* lg_in_b     = (const float*)d_in[8];
    const float* lg_out_w    = (const float*)d_in[9];
    const float* lg_out_b    = (const float*)d_in[10];
    const float* vt_in_w     = (const float*)d_in[11];
    const float* vt_in_b     = (const float*)d_in[12];
    const float* vt_out_w    = (const float*)d_in[13];
    const float* vt_out_b    = (const float*)d_in[14];
    const float* ml_in_w     = (const float*)d_in[15];
    const float* ml_in_b     = (const float*)d_in[16];
    const float* ml_out_w    = (const float*)d_in[17];
    const float* ml_out_b    = (const float*)d_in[18];
    float* out = (float*)d_out;

    const ull TE = (ull)NTOK * EMB;
    const ull EE = (ull)EMB * EMB;
    unsigned short* w = (unsigned short*)d_ws;
    Bufs B;
    for (int i = 0; i < 6; ++i) { B.Ph[i] = w + (2 * i) * TE; B.Pl[i] = w + (2 * i + 1) * TE; }
    B.ATTh  = w + 12 * TE;              // 2 TE (batch 2)
    B.QK    = w + 14 * TE;              // 4 TE (batch 2)
    B.VT    = w + 18 * TE;              // 2 TE
    B.Opart = w + 20 * TE;              // 2 TE (batch-1 rounds only)
    B.ml    = (float*)(w + 24 * TE);    // 1 MB
    B.Wih   = w + 25 * TE;              // 3 EE
    B.Woh   = B.Wih + 3 * EE;           // EE
    B.Wol   = B.Woh + EE;               // EE

    add_pos_pair<<<TE / 1024, 256, 0, stream>>>(local_feat, pos_l, B.Ph[0], B.Pl[0]);
    add_pos_pair<<<TE / 1024, 256, 0, stream>>>(global_feat, pos_g, B.Ph[1], B.Pl[1]);

    // tf = text @ fc_w^T + fc_b -> P2 pair (text pair staged in QK scratch,
    // fc weight pair in Woh/Wol — both overwritten by the first mha round)
    split_pair<<<TE / 1024, 256, 0, stream>>>(text_feat, B.QK, B.QK + TE);
    split_pair<<<EE / 1024, 256, 0, stream>>>(fc_w, B.Woh, B.Wol);
    G<3, 2>(dim3(EMB / 128, NTOK / 128), B.QK, B.QK + TE, EMB, 0, B.Woh, B.Wol, EMB, 0,
            B.Ph[2], B.Pl[2], EMB, 0, EMB, 1.f, fc_b, 0, nullptr, nullptr, 0, 0, stream);

    const ll T2 = (ll)2 * TE, T4 = (ll)4 * TE;
    // round 1: local_global = mha(lf, gf; lg) + lf           -> P3
    run_mha(1, B.Ph[0], 0, B.Ph[1], 0, lg_in_w, lg_in_b, lg_out_w, lg_out_b,
            B.Ph[3], B.Pl[3], B.Ph[0], B.Pl[0], 0, 1, B, true, stream);
    // round 2 (batch): text_local = mha(tf, lf; vt)+lf -> P4
    //                  text_global = mha(tf, gf; vt)+tf -> P5
    run_mha(2, B.Ph[2], 0, B.Ph[0], T2, vt_in_w, vt_in_b, vt_out_w, vt_out_b,
            B.Ph[4], B.Pl[4], B.Ph[0], B.Pl[0], T4, 1, B, true, stream);
    // round 3 (batch): gt_gl = mha(P3, P5; ml) -> P0
    //                  gl_lt = mha(P4, P3; ml) -> P1
    run_mha(2, B.Ph[3], T2, B.Ph[5], -T4, ml_in_w, ml_in_b, ml_out_w, ml_out_b,
            B.Ph[0], B.Pl[0], nullptr, nullptr, 0, 0, B, true, stream);
    // round 4: full = mha(gl_lt=P1, gt_gl=P0; ml)            -> P3
    run_mha(1, B.Ph[1], 0, B.Ph[0], 0, ml_in_w, ml_in_b, ml_out_w, ml_out_b,
            B.Ph[3], B.Pl[3], nullptr, nullptr, 0, 0, B, false, stream);
    // round 5: fusion = mha(tf=P2, full=P3; ml) * tf         -> P4
    run_mha(1, B.Ph[2], 0, B.Ph[3], 0, ml_in_w, ml_in_b, ml_out_w, ml_out_b,
            B.Ph[4], B.Pl[4], B.Ph[2], B.Pl[2], 0, 2, B, false, stream);

    l2norm_rows<false><<<NTOK, 256, 0, stream>>>(nullptr, B.Ph[4], B.Pl[4], B.Ph[4], B.Pl[4]);
    l2norm_rows<true ><<<NTOK, 256, 0, stream>>>(local_feat, nullptr, nullptr, B.Ph[5], B.Pl[5]);

    G<3, 0>(dim3(QTY / 128, QTY / 128, 8),
            B.Ph[4], B.Pl[4], EMB, (ll)QTY * EMB,
            B.Ph[5], B.Pl[5], EMB, (ll)QTY * EMB,
            out, nullptr, QTY, (ll)QTY * QTY,
            EMB, 1.f, nullptr, 0, nullptr, nullptr, 0, 0, stream);
}

// Round 15
// 1667.991 us; speedup vs baseline: 1.2474x; 1.0101x over previous
//
#include <hip/hip_runtime.h>
#include <hip/hip_bf16.h>

// FilterModule: 7x MHA fusion pipeline, bf16 MFMA + flash attention v14.
// v14 = v13 + rounds-1&2 merge (they are dependence-independent): one 3-mha
// super-round with per-z weight/pointer select (gemm_proj6 / gemm_vt3 /
// flash<1,12> / gemm_out3), no combine for the merged round. Rounds 3-5 keep
// the proven batched path. Flash geometry LOCKED at v7.

typedef __attribute__((ext_vector_type(8))) short short8;
typedef __attribute__((ext_vector_type(4))) float f32x4;
typedef unsigned long long ull;
typedef long long ll;

namespace {
constexpr int NTOK = 4096;
constexpr int EMB  = 1024;
constexpr int QTY  = 512;
}

__device__ __forceinline__ float bf2f(unsigned short u) {
    union { float f; unsigned int i; } x; x.i = ((unsigned int)u) << 16; return x.f;
}
__device__ __forceinline__ unsigned short f2bf(float f) {
    union { float f; unsigned int i; } x; x.f = f;
    unsigned int r = x.i + 0x7fffu + ((x.i >> 16) & 1u);
    return (unsigned short)(r >> 16);
}

#define GLOAD_LDS16(g, l) __builtin_amdgcn_global_load_lds( \
    (const __attribute__((address_space(1))) void*)(g),     \
    (__attribute__((address_space(3))) void*)(l), 16, 0, 0)

// ---------------------------------------------------------------------------
// Generic MFMA GEMM (B^T layout), 128x128 tile, BK=32, 256 thr.
template<int SPLITS, int OUTM>
__global__ __launch_bounds__(256)
void gemm_mfma(const unsigned short* __restrict__ Ah, const unsigned short* __restrict__ Al,
               int lda, ll sAz,
               const unsigned short* __restrict__ Bh, const unsigned short* __restrict__ Bl,
               int ldb, ll sBz,
               void* __restrict__ Cp, void* __restrict__ Clp,
               int ldc, ll sCz,
               int K, float alpha, const float* __restrict__ bias, int biasRow,
               const unsigned short* __restrict__ resH, const unsigned short* __restrict__ resL,
               ll sRz, int resMode)
{
    constexpr int NTILES = (SPLITS == 3 ? 4 : (SPLITS == 2 ? 3 : 2));
    constexpr int TSZ = 128 * 32;
    __shared__ unsigned short lds[NTILES * TSZ];
    const int tid  = threadIdx.x;
    const int brow = blockIdx.y * 128;
    const int bcol = blockIdx.x * 128;
    const ll   z   = blockIdx.z;
    Ah += z * sAz; Bh += z * sBz;
    if constexpr (SPLITS == 3) Al += z * sAz;
    if constexpr (SPLITS >= 2) Bl += z * sBz;

    const int lane = tid & 63;
    const int wv = tid >> 6, wr = wv >> 1, wc = wv & 1;
    const int l15 = lane & 15, l4 = lane >> 4;

    f32x4 acc[4][4];
    #pragma unroll
    for (int m = 0; m < 4; ++m)
        #pragma unroll
        for (int n = 0; n < 4; ++n) acc[m][n] = (f32x4){0.f, 0.f, 0.f, 0.f};

    for (int k0 = 0; k0 < K; k0 += 32) {
        #pragma unroll
        for (int i = 0; i < 2; ++i) {
            int idx = tid + i * 256;
            int row = idx >> 2;
            int kc  = (idx & 3) ^ ((row >> 1) & 3);
            GLOAD_LDS16(Ah + (ull)(brow + row) * lda + k0 + kc * 8, &lds[idx * 8]);
            GLOAD_LDS16(Bh + (ull)(bcol + row) * ldb + k0 + kc * 8, &lds[TSZ + idx * 8]);
            if constexpr (SPLITS >= 2)
                GLOAD_LDS16(Bl + (ull)(bcol + row) * ldb + k0 + kc * 8, &lds[2 * TSZ + idx * 8]);
            if constexpr (SPLITS == 3)
                GLOAD_LDS16(Al + (ull)(brow + row) * lda + k0 + kc * 8, &lds[3 * TSZ + idx * 8]);
        }
        __syncthreads();

        short8 ah[4], bh[4], bl2[4], al2[4];
        #pragma unroll
        for (int m = 0; m < 4; ++m) {
            int rr = wr * 64 + m * 16 + l15;
            int sl = l4 ^ ((rr >> 1) & 3);
            int off = rr * 32 + sl * 8;
            ah[m] = *(const short8*)&lds[off];
            if constexpr (SPLITS == 3) al2[m] = *(const short8*)&lds[3 * TSZ + off];
        }
        #pragma unroll
        for (int n = 0; n < 4; ++n) {
            int rr = wc * 64 + n * 16 + l15;
            int sl = l4 ^ ((rr >> 1) & 3);
            int off = rr * 32 + sl * 8;
            bh[n] = *(const short8*)&lds[TSZ + off];
            if constexpr (SPLITS >= 2) bl2[n] = *(const short8*)&lds[2 * TSZ + off];
        }
        #pragma unroll
        for (int m = 0; m < 4; ++m)
            #pragma unroll
            for (int n = 0; n < 4; ++n) {
                acc[m][n] = __builtin_amdgcn_mfma_f32_16x16x32_bf16(ah[m], bh[n], acc[m][n], 0, 0, 0);
                if constexpr (SPLITS >= 2)
                    acc[m][n] = __builtin_amdgcn_mfma_f32_16x16x32_bf16(ah[m], bl2[n], acc[m][n], 0, 0, 0);
                if constexpr (SPLITS == 3)
                    acc[m][n] = __builtin_amdgcn_mfma_f32_16x16x32_bf16(al2[m], bh[n], acc[m][n], 0, 0, 0);
            }
        __syncthreads();
    }

    float* Cf = (float*)Cp + z * sCz;
    unsigned short* Ch = (unsigned short*)Cp + z * sCz;
    unsigned short* Cl = (unsigned short*)Clp + z * sCz;
    const unsigned short* rH = resH + z * sRz;
    const unsigned short* rL = resL + z * sRz;
    const int rowB = brow + wr * 64 + l4 * 4;
    const int colB = bcol + wc * 64 + l15;
    #pragma unroll
    for (int n = 0; n < 4; ++n) {
        int col = colB + n * 16;
        #pragma unroll
        for (int m = 0; m < 4; ++m) {
            #pragma unroll
            for (int r = 0; r < 4; ++r) {
                int row = rowB + m * 16 + r;
                ull ci = (ull)row * ldc + col;
                float v = acc[m][n][r] * alpha;
                if (bias) v += biasRow ? bias[row] : bias[col];
                if (resMode == 1)      v += bf2f(rH[ci]) + bf2f(rL[ci]);
                else if (resMode == 2) v *= bf2f(rH[ci]) + bf2f(rL[ci]);
                if constexpr (OUTM == 0)      Cf[ci] = v;
                else if constexpr (OUTM == 1) Ch[ci] = f2bf(v);
                else {
                    unsigned short h = f2bf(v);
                    Ch[ci] = h;
                    Cl[ci] = f2bf(v - bf2f(h));
                }
            }
        }
    }
}

// ---------------------------------------------------------------------------
// Q/K projection for up to 2 batches (rounds 3-5). z = b*2 + j (j: 0=Q, 1=K).
__global__ __launch_bounds__(256)
void gemm_qkproj(const unsigned short* a0, const unsigned short* a1,
                 const unsigned short* a2, const unsigned short* a3,
                 const unsigned short* __restrict__ W,
                 unsigned short* __restrict__ QK,
                 const float* __restrict__ bias)
{
    constexpr int TSZ = 128 * 32;
    __shared__ unsigned short lds[2 * TSZ];
    const int tid  = threadIdx.x;
    const int brow = blockIdx.y * 128;
    const int bcol = blockIdx.x * 128;
    const int z = blockIdx.z;
    const int j = z & 1, bb = z >> 1;
    const unsigned short* Ah = (z == 0) ? a0 : (z == 1) ? a1 : (z == 2) ? a2 : a3;
    const unsigned short* Bh = W + (ull)j * EMB * EMB;
    unsigned short* C = QK + (ull)bb * NTOK * 2048 + j * 1024;
    const float* bi = bias + j * 1024;

    const int lane = tid & 63;
    const int wv = tid >> 6, wr = wv >> 1, wc = wv & 1;
    const int l15 = lane & 15, l4 = lane >> 4;

    f32x4 acc[4][4];
    #pragma unroll
    for (int m = 0; m < 4; ++m)
        #pragma unroll
        for (int n = 0; n < 4; ++n) acc[m][n] = (f32x4){0.f, 0.f, 0.f, 0.f};

    for (int k0 = 0; k0 < EMB; k0 += 32) {
        #pragma unroll
        for (int i = 0; i < 2; ++i) {
            int idx = tid + i * 256;
            int row = idx >> 2;
            int kc  = (idx & 3) ^ ((row >> 1) & 3);
            GLOAD_LDS16(Ah + (ull)(brow + row) * EMB + k0 + kc * 8, &lds[idx * 8]);
            GLOAD_LDS16(Bh + (ull)(bcol + row) * EMB + k0 + kc * 8, &lds[TSZ + idx * 8]);
        }
        __syncthreads();
        short8 ah[4], bh[4];
        #pragma unroll
        for (int m = 0; m < 4; ++m) {
            int rr = wr * 64 + m * 16 + l15;
            int sl = l4 ^ ((rr >> 1) & 3);
            ah[m] = *(const short8*)&lds[rr * 32 + sl * 8];
        }
        #pragma unroll
        for (int n = 0; n < 4; ++n) {
            int rr = wc * 64 + n * 16 + l15;
            int sl = l4 ^ ((rr >> 1) & 3);
            bh[n] = *(const short8*)&lds[TSZ + rr * 32 + sl * 8];
        }
        #pragma unroll
        for (int m = 0; m < 4; ++m)
            #pragma unroll
            for (int n = 0; n < 4; ++n)
                acc[m][n] = __builtin_amdgcn_mfma_f32_16x16x32_bf16(ah[m], bh[n], acc[m][n], 0, 0, 0);
        __syncthreads();
    }

    const int rowB = brow + wr * 64 + l4 * 4;
    const int colB = bcol + wc * 64 + l15;
    #pragma unroll
    for (int n = 0; n < 4; ++n) {
        int col = colB + n * 16;
        float bv = bi[col];
        #pragma unroll
        for (int m = 0; m < 4; ++m)
            #pragma unroll
            for (int r = 0; r < 4; ++r) {
                int row = rowB + m * 16 + r;
                C[(ull)row * 2048 + col] = f2bf(acc[m][n][r] + bv);
            }
    }
}

// ---------------------------------------------------------------------------
// Merged-round Q/K projection: 3 mhas, z = m*2 + j. Set: m==0 -> (w0,b0) [lg],
// else (w1,b1) [vt]. grid (8, 32, 6).
__global__ __launch_bounds__(256)
void gemm_proj6(const unsigned short* a0, const unsigned short* a1,
                const unsigned short* a2, const unsigned short* a3,
                const unsigned short* a4, const unsigned short* a5,
                const unsigned short* __restrict__ w0, const unsigned short* __restrict__ w1,
                const float* __restrict__ b0, const float* __restrict__ b1,
                unsigned short* __restrict__ QK)
{
    constexpr int TSZ = 128 * 32;
    __shared__ unsigned short lds[2 * TSZ];
    const int tid  = threadIdx.x;
    const int brow = blockIdx.y * 128;
    const int bcol = blockIdx.x * 128;
    const int z = blockIdx.z;
    const int j = z & 1, m6 = z >> 1;
    const unsigned short* Ah = (z == 0) ? a0 : (z == 1) ? a1 : (z == 2) ? a2
                              : (z == 3) ? a3 : (z == 4) ? a4 : a5;
    const unsigned short* Bh = ((m6 == 0) ? w0 : w1) + (ull)j * EMB * EMB;
    unsigned short* C = QK + (ull)m6 * NTOK * 2048 + j * 1024;
    const float* bi = ((m6 == 0) ? b0 : b1) + j * 1024;

    const int lane = tid & 63;
    const int wv = tid >> 6, wr = wv >> 1, wc = wv & 1;
    const int l15 = lane & 15, l4 = lane >> 4;

    f32x4 acc[4][4];
    #pragma unroll
    for (int m = 0; m < 4; ++m)
        #pragma unroll
        for (int n = 0; n < 4; ++n) acc[m][n] = (f32x4){0.f, 0.f, 0.f, 0.f};

    for (int k0 = 0; k0 < EMB; k0 += 32) {
        #pragma unroll
        for (int i = 0; i < 2; ++i) {
            int idx = tid + i * 256;
            int row = idx >> 2;
            int kc  = (idx & 3) ^ ((row >> 1) & 3);
            GLOAD_LDS16(Ah + (ull)(brow + row) * EMB + k0 + kc * 8, &lds[idx * 8]);
            GLOAD_LDS16(Bh + (ull)(bcol + row) * EMB + k0 + kc * 8, &lds[TSZ + idx * 8]);
        }
        __syncthreads();
        short8 ah[4], bh[4];
        #pragma unroll
        for (int m = 0; m < 4; ++m) {
            int rr = wr * 64 + m * 16 + l15;
            int sl = l4 ^ ((rr >> 1) & 3);
            ah[m] = *(const short8*)&lds[rr * 32 + sl * 8];
        }
        #pragma unroll
        for (int n = 0; n < 4; ++n) {
            int rr = wc * 64 + n * 16 + l15;
            int sl = l4 ^ ((rr >> 1) & 3);
            bh[n] = *(const short8*)&lds[TSZ + rr * 32 + sl * 8];
        }
        #pragma unroll
        for (int m = 0; m < 4; ++m)
            #pragma unroll
            for (int n = 0; n < 4; ++n)
                acc[m][n] = __builtin_amdgcn_mfma_f32_16x16x32_bf16(ah[m], bh[n], acc[m][n], 0, 0, 0);
        __syncthreads();
    }

    const int rowB = brow + wr * 64 + l4 * 4;
    const int colB = bcol + wc * 64 + l15;
    #pragma unroll
    for (int n = 0; n < 4; ++n) {
        int col = colB + n * 16;
        float bv = bi[col];
        #pragma unroll
        for (int m = 0; m < 4; ++m)
            #pragma unroll
            for (int r = 0; r < 4; ++r) {
                int row = rowB + m * 16 + r;
                C[(ull)row * 2048 + col] = f2bf(acc[m][n][r] + bv);
            }
    }
}

// ---------------------------------------------------------------------------
// Merged-round V^T projection: 3 mhas, z = m. C[m][d][token] = Wv[d,:]·feat.
// grid (32, 8, 3). bias indexed by row (d).
__global__ __launch_bounds__(256)
void gemm_vt3(const unsigned short* f0, const unsigned short* f1,
              const unsigned short* f2,
              const unsigned short* __restrict__ w0, const unsigned short* __restrict__ w1,
              const float* __restrict__ b0, const float* __restrict__ b1,
              unsigned short* __restrict__ VT)
{
    constexpr int TSZ = 128 * 32;
    __shared__ unsigned short lds[2 * TSZ];
    const int tid  = threadIdx.x;
    const int brow = blockIdx.y * 128;          // d
    const int bcol = blockIdx.x * 128;          // token
    const int z = blockIdx.z;
    const unsigned short* Ah = ((z == 0) ? w0 : w1) + 2ull * EMB * EMB;
    const unsigned short* Bh = (z == 0) ? f0 : (z == 1) ? f1 : f2;
    const float* bi = ((z == 0) ? b0 : b1) + 2048;
    unsigned short* C = VT + (ull)z * 1024 * 4096;

    const int lane = tid & 63;
    const int wv = tid >> 6, wr = wv >> 1, wc = wv & 1;
    const int l15 = lane & 15, l4 = lane >> 4;

    f32x4 acc[4][4];
    #pragma unroll
    for (int m = 0; m < 4; ++m)
        #pragma unroll
        for (int n = 0; n < 4; ++n) acc[m][n] = (f32x4){0.f, 0.f, 0.f, 0.f};

    for (int k0 = 0; k0 < EMB; k0 += 32) {
        #pragma unroll
        for (int i = 0; i < 2; ++i) {
            int idx = tid + i * 256;
            int row = idx >> 2;
            int kc  = (idx & 3) ^ ((row >> 1) & 3);
            GLOAD_LDS16(Ah + (ull)(brow + row) * EMB + k0 + kc * 8, &lds[idx * 8]);
            GLOAD_LDS16(Bh + (ull)(bcol + row) * EMB + k0 + kc * 8, &lds[TSZ + idx * 8]);
        }
        __syncthreads();
        short8 ah[4], bh[4];
        #pragma unroll
        for (int m = 0; m < 4; ++m) {
            int rr = wr * 64 + m * 16 + l15;
            int sl = l4 ^ ((rr >> 1) & 3);
            ah[m] = *(const short8*)&lds[rr * 32 + sl * 8];
        }
        #pragma unroll
        for (int n = 0; n < 4; ++n) {
            int rr = wc * 64 + n * 16 + l15;
            int sl = l4 ^ ((rr >> 1) & 3);
            bh[n] = *(const short8*)&lds[TSZ + rr * 32 + sl * 8];
        }
        #pragma unroll
        for (int m = 0; m < 4; ++m)
            #pragma unroll
            for (int n = 0; n < 4; ++n)
                acc[m][n] = __builtin_amdgcn_mfma_f32_16x16x32_bf16(ah[m], bh[n], acc[m][n], 0, 0, 0);
        __syncthreads();
    }

    const int rowB = brow + wr * 64 + l4 * 4;
    const int colB = bcol + wc * 64 + l15;
    #pragma unroll
    for (int n = 0; n < 4; ++n) {
        int col = colB + n * 16;
        #pragma unroll
        for (int m = 0; m < 4; ++m)
            #pragma unroll
            for (int r = 0; r < 4; ++r) {
                int row = rowB + m * 16 + r;
                C[(ull)row * 4096 + col] = f2bf(acc[m][n][r] + bi[row]);
            }
    }
}

// ---------------------------------------------------------------------------
// Merged-round out-proj: 3 mhas. A = ATTh + z*TE (hi only) x weight pair.
// z==0 -> set0 (lg), else set1 (vt). res: z0=r0, z1=r1, z2=r2 (add).
// dest pair: dsth/dstl + z*2TE. grid (8, 32, 3).
__global__ __launch_bounds__(256)
void gemm_out3(const unsigned short* __restrict__ ATTh,
               const unsigned short* __restrict__ w0h, const unsigned short* __restrict__ w0l,
               const unsigned short* __restrict__ w1h, const unsigned short* __restrict__ w1l,
               const float* __restrict__ b0, const float* __restrict__ b1,
               unsigned short* __restrict__ dsth, unsigned short* __restrict__ dstl,
               const unsigned short* r0h, const unsigned short* r0l,
               const unsigned short* r1h, const unsigned short* r1l,
               const unsigned short* r2h, const unsigned short* r2l)
{
    constexpr int TSZ = 128 * 32;
    __shared__ unsigned short lds[3 * TSZ];     // A | Bh | Bl
    const int tid  = threadIdx.x;
    const int brow = blockIdx.y * 128;
    const int bcol = blockIdx.x * 128;
    const int z = blockIdx.z;
    const ll TE = (ll)NTOK * EMB;
    const unsigned short* Ah = ATTh + z * TE;
    const unsigned short* Bh = (z == 0) ? w0h : w1h;
    const unsigned short* Bl = (z == 0) ? w0l : w1l;
    const float* bi = (z == 0) ? b0 : b1;
    unsigned short* Ch = dsth + z * 2 * TE;
    unsigned short* Cl = dstl + z * 2 * TE;
    const unsigned short* rH = (z == 0) ? r0h : (z == 1) ? r1h : r2h;
    const unsigned short* rL = (z == 0) ? r0l : (z == 1) ? r1l : r2l;

    const int lane = tid & 63;
    const int wv = tid >> 6, wr = wv >> 1, wc = wv & 1;
    const int l15 = lane & 15, l4 = lane >> 4;

    f32x4 acc[4][4];
    #pragma unroll
    for (int m = 0; m < 4; ++m)
        #pragma unroll
        for (int n = 0; n < 4; ++n) acc[m][n] = (f32x4){0.f, 0.f, 0.f, 0.f};

    for (int k0 = 0; k0 < EMB; k0 += 32) {
        #pragma unroll
        for (int i = 0; i < 2; ++i) {
            int idx = tid + i * 256;
            int row = idx >> 2;
            int kc  = (idx & 3) ^ ((row >> 1) & 3);
            GLOAD_LDS16(Ah + (ull)(brow + row) * EMB + k0 + kc * 8, &lds[idx * 8]);
            GLOAD_LDS16(Bh + (ull)(bcol + row) * EMB + k0 + kc * 8, &lds[TSZ + idx * 8]);
            GLOAD_LDS16(Bl + (ull)(bcol + row) * EMB + k0 + kc * 8, &lds[2 * TSZ + idx * 8]);
        }
        __syncthreads();
        short8 ah[4], bh[4], bl2[4];
        #pragma unroll
        for (int m = 0; m < 4; ++m) {
            int rr = wr * 64 + m * 16 + l15;
            int sl = l4 ^ ((rr >> 1) & 3);
            ah[m] = *(const short8*)&lds[rr * 32 + sl * 8];
        }
        #pragma unroll
        for (int n = 0; n < 4; ++n) {
            int rr = wc * 64 + n * 16 + l15;
            int sl = l4 ^ ((rr >> 1) & 3);
            bh[n]  = *(const short8*)&lds[TSZ + rr * 32 + sl * 8];
            bl2[n] = *(const short8*)&lds[2 * TSZ + rr * 32 + sl * 8];
        }
        #pragma unroll
        for (int m = 0; m < 4; ++m)
            #pragma unroll
            for (int n = 0; n < 4; ++n) {
                acc[m][n] = __builtin_amdgcn_mfma_f32_16x16x32_bf16(ah[m], bh[n], acc[m][n], 0, 0, 0);
                acc[m][n] = __builtin_amdgcn_mfma_f32_16x16x32_bf16(ah[m], bl2[n], acc[m][n], 0, 0, 0);
            }
        __syncthreads();
    }

    const int rowB = brow + wr * 64 + l4 * 4;
    const int colB = bcol + wc * 64 + l15;
    #pragma unroll
    for (int n = 0; n < 4; ++n) {
        int col = colB + n * 16;
        float bv = bi[col];
        #pragma unroll
        for (int m = 0; m < 4; ++m)
            #pragma unroll
            for (int r = 0; r < 4; ++r) {
                int row = rowB + m * 16 + r;
                ull ci = (ull)row * EMB + col;
                float v = acc[m][n][r] + bv + bf2f(rH[ci]) + bf2f(rL[ci]);
                unsigned short h = f2bf(v);
                Ch[ci] = h;
                Cl[ci] = f2bf(v - bf2f(h));
            }
    }
}

// ---------------------------------------------------------------------------
// Flash attention (v7 structure, LOCKED). 1D grid of 32*NZ blocks:
// zz = bid % NZ, qt = bid / NZ. NSPLIT=2: zz=sp*4+h (batch=1).
// NSPLIT=1: zz=b*4+h (b < NZ/4). QK [b][4096][2048]; VT [b][1024][4096].
template<int NSPLIT, int NZ>
__global__ __launch_bounds__(512)
void flash_attn(const unsigned short* __restrict__ QK,
                const unsigned short* __restrict__ VT,
                unsigned short* __restrict__ Opart, float* __restrict__ ml,
                unsigned short* __restrict__ attH)
{
    constexpr int KVB = 64;
    constexpr int NTILE = (NTOK / NSPLIT) / KVB;
    __shared__ unsigned short Kt[2][KVB * 256];
    __shared__ unsigned short Vt[2][256 * KVB];

    const int tid = threadIdx.x;
    const int w = tid >> 6, lane = tid & 63;
    const int l15 = lane & 15, l4 = lane >> 4;
    const int bid = blockIdx.x;
    const int zz = bid % NZ, qt = bid / NZ;
    const int h = zz & 3;
    int b, sp;
    if constexpr (NSPLIT == 2) { b = 0; sp = zz >> 2; }
    else                       { b = zz >> 2; sp = 0; }
    const int qrow = qt * 128 + w * 16 + l15;
    const int kv0 = sp * (NTOK / NSPLIT);
    const unsigned short* QKb = QK + (ull)b * NTOK * 2048;
    const unsigned short* VTb = VT + (ull)b * 1024 * 4096;

    short8 qreg[8];
    {
        const unsigned short* qp = QKb + (ull)qrow * 2048 + h * 256;
        #pragma unroll
        for (int c = 0; c < 8; ++c) {
            short8 x = *(const short8*)&qp[c * 32 + l4 * 8];
            #pragma unroll
            for (int j = 0; j < 8; ++j)
                x[j] = (short)f2bf(bf2f((unsigned short)x[j]) * 0.0625f);
            qreg[c] = x;
        }
    }

    f32x4 oacc[16];
    #pragma unroll
    for (int dn = 0; dn < 16; ++dn) oacc[dn] = (f32x4){0.f, 0.f, 0.f, 0.f};
    float m_r = -1e30f, l_r = 0.f;

    auto stage = [&](int t, int buf) {
        int base = kv0 + t * KVB;
        #pragma unroll
        for (int i = 0; i < 4; ++i) {
            int s = tid + i * 512;
            int r = s >> 5, c = s & 31;
            int c0 = c ^ (r & 7);
            GLOAD_LDS16(QKb + (ull)(base + r) * 2048 + 1024 + h * 256 + c0 * 8,
                        &Kt[buf][s * 8]);
        }
        #pragma unroll
        for (int i = 0; i < 4; ++i) {
            int s = tid + i * 512;
            int r = s >> 3, c = s & 7;
            int c0 = c ^ (r & 7);
            GLOAD_LDS16(VTb + (ull)(h * 256 + r) * 4096 + base + c0 * 8,
                        &Vt[buf][s * 8]);
        }
    };

    stage(0, 0);
    for (int t = 0; t < NTILE; ++t) {
        if (t + 1 < NTILE) {
            stage(t + 1, (t + 1) & 1);
            asm volatile("s_waitcnt vmcnt(8)");
        } else {
            asm volatile("s_waitcnt vmcnt(0)");
        }
        __builtin_amdgcn_s_barrier();

        const unsigned short* Kb = Kt[t & 1];
        const unsigned short* Vb = Vt[t & 1];

        f32x4 sacc[4];
        #pragma unroll
        for (int fk = 0; fk < 4; ++fk) sacc[fk] = (f32x4){0.f, 0.f, 0.f, 0.f};
        #pragma unroll
        for (int fk = 0; fk < 4; ++fk) {
            int r = fk * 16 + l15;
            int rx = r & 7;
            #pragma unroll
            for (int c = 0; c < 8; ++c) {
                int ch = (4 * c + l4) ^ rx;
                short8 kf = *(const short8*)&Kb[r * 256 + ch * 8];
                sacc[fk] = __builtin_amdgcn_mfma_f32_16x16x32_bf16(kf, qreg[c], sacc[fk], 0, 0, 0);
            }
        }

        float tm = sacc[0][0];
        #pragma unroll
        for (int fk = 0; fk < 4; ++fk)
            #pragma unroll
            for (int rr = 0; rr < 4; ++rr) tm = fmaxf(tm, sacc[fk][rr]);
        tm = fmaxf(tm, __shfl_xor(tm, 16));
        tm = fmaxf(tm, __shfl_xor(tm, 32));

        bool nomax = __all(tm <= m_r + 5.545f);
        if (!nomax) {
            float mnew = fmaxf(m_r, tm);
            float corr = __expf(m_r - mnew);
            float c4[4];
            #pragma unroll
            for (int r = 0; r < 4; ++r) c4[r] = __shfl(corr, l4 * 4 + r);
            #pragma unroll
            for (int dn = 0; dn < 16; ++dn)
                #pragma unroll
                for (int r = 0; r < 4; ++r) oacc[dn][r] *= c4[r];
            l_r *= corr;
            m_r = mnew;
        }

        float p[16]; float ls = 0.f;
        #pragma unroll
        for (int fk = 0; fk < 4; ++fk)
            #pragma unroll
            for (int rr = 0; rr < 4; ++rr) {
                float e = __expf(sacc[fk][rr] - m_r);
                p[fk * 4 + rr] = e; ls += e;
            }
        ls += __shfl_xor(ls, 16);
        ls += __shfl_xor(ls, 32);
        l_r += ls;

        unsigned int W[4][2];
        #pragma unroll
        for (int f = 0; f < 4; ++f)
            #pragma unroll
            for (int pp = 0; pp < 2; ++pp)
                W[f][pp] = (unsigned int)f2bf(p[f * 4 + 2 * pp]) |
                           ((unsigned int)f2bf(p[f * 4 + 2 * pp + 1]) << 16);

        const int sbase = l15 + ((l4 & 1) << 5);
        const bool hi = (l4 >> 1) & 1;
        #pragma unroll
        for (int kvc = 0; kvc < 2; ++kvc) {
            unsigned int a0 = (unsigned int)__shfl((int)W[2 * kvc][0], sbase);
            unsigned int a1 = (unsigned int)__shfl((int)W[2 * kvc][1], sbase);
            unsigned int a2 = (unsigned int)__shfl((int)W[2 * kvc][0], sbase + 16);
            unsigned int a3 = (unsigned int)__shfl((int)W[2 * kvc][1], sbase + 16);
            unsigned int b0 = (unsigned int)__shfl((int)W[2 * kvc + 1][0], sbase);
            unsigned int b1 = (unsigned int)__shfl((int)W[2 * kvc + 1][1], sbase);
            unsigned int b2 = (unsigned int)__shfl((int)W[2 * kvc + 1][0], sbase + 16);
            unsigned int b3 = (unsigned int)__shfl((int)W[2 * kvc + 1][1], sbase + 16);
            union { unsigned int u[4]; short8 s8; } pa;
            pa.u[0] = hi ? b0 : a0; pa.u[1] = hi ? b1 : a1;
            pa.u[2] = hi ? b2 : a2; pa.u[3] = hi ? b3 : a3;

            #pragma unroll
            for (int dn = 0; dn < 16; ++dn) {
                int row = dn * 16 + l15;
                int ch = (kvc * 4 + l4) ^ (row & 7);
                short8 vf = *(const short8*)&Vb[row * 64 + ch * 8];
                oacc[dn] = __builtin_amdgcn_mfma_f32_16x16x32_bf16(pa.s8, vf, oacc[dn], 0, 0, 0);
            }
        }
        __builtin_amdgcn_s_barrier();
    }

    float inv = 1.f / l_r;
    float i4[4];
    #pragma unroll
    for (int r = 0; r < 4; ++r) i4[r] = __shfl(inv, l4 * 4 + r);

    if constexpr (NSPLIT == 2) {
        unsigned short* Ob = Opart + (((ull)b * 2 + sp) * 4 + h) * NTOK * 256;
        #pragma unroll
        for (int dn = 0; dn < 16; ++dn) {
            int d = dn * 16 + l15;
            #pragma unroll
            for (int r = 0; r < 4; ++r) {
                int q = qt * 128 + w * 16 + l4 * 4 + r;
                Ob[(ull)q * 256 + d] = f2bf(oacc[dn][r] * i4[r]);
            }
        }
        if (l4 == 0) {
            float2* mlp = (float2*)ml + (((ull)b * 2 + sp) * 4 + h) * NTOK + qrow;
            *mlp = make_float2(m_r, l_r);
        }
    } else {
        unsigned short* Ob = attH + (ull)b * NTOK * EMB;
        #pragma unroll
        for (int dn = 0; dn < 16; ++dn) {
            int d = dn * 16 + l15;
            #pragma unroll
            for (int r = 0; r < 4; ++r) {
                int q = qt * 128 + w * 16 + l4 * 4 + r;
                Ob[(ull)q * EMB + h * 256 + d] = f2bf(oacc[dn][r] * i4[r]);
            }
        }
    }
}

// ---------------------------------------------------------------------------
// merge 2 KV-split partials (normalized bf16) -> att bf16 (hi only).
__global__ __launch_bounds__(256)
void flash_combine(const unsigned short* __restrict__ Opart, const float* __restrict__ ml,
                   unsigned short* __restrict__ attH)
{
    const int bx = blockIdx.x;
    const int b = bx >> 12, q = bx & 4095;
    const int t = threadIdx.x;
    const int h = t >> 6, d4 = (t & 63) * 4;

    float2 m0 = ((const float2*)ml)[(((ull)b * 2 + 0) * 4 + h) * NTOK + q];
    float2 m1 = ((const float2*)ml)[(((ull)b * 2 + 1) * 4 + h) * NTOK + q];
    float ms = fmaxf(m0.x, m1.x);
    float w0 = __expf(m0.x - ms) * m0.y;
    float w1 = __expf(m1.x - ms) * m1.y;
    float inv = 1.f / (w0 + w1);
    w0 *= inv; w1 *= inv;

    ushort4 o0 = *(const ushort4*)&Opart[((((ull)b * 2 + 0) * 4 + h) * NTOK + q) * 256 + d4];
    ushort4 o1 = *(const ushort4*)&Opart[((((ull)b * 2 + 1) * 4 + h) * NTOK + q) * 256 + d4];
    ushort4 ho;
    ho.x = f2bf(w0 * bf2f(o0.x) + w1 * bf2f(o1.x));
    ho.y = f2bf(w0 * bf2f(o0.y) + w1 * bf2f(o1.y));
    ho.z = f2bf(w0 * bf2f(o0.z) + w1 * bf2f(o1.z));
    ho.w = f2bf(w0 * bf2f(o0.w) + w1 * bf2f(o1.w));
    *(ushort4*)&attH[(ull)b * NTOK * EMB + (ull)q * EMB + h * 256 + d4] = ho;
}

// ---------------------------------------------------------------------------
template<bool F32IN>
__global__ __launch_bounds__(256)
void l2norm_rows(const float* __restrict__ inF, const unsigned short* __restrict__ inH,
                 const unsigned short* __restrict__ inL,
                 unsigned short* __restrict__ oH, unsigned short* __restrict__ oL)
{
    const ull row = blockIdx.x;
    const int t = threadIdx.x;
    const int lane = t & 63, wid = t >> 6;
    __shared__ float red[4];

    float v[4];
    if constexpr (F32IN) {
        float4 x = *(const float4*)&inF[row * EMB + t * 4];
        v[0] = x.x; v[1] = x.y; v[2] = x.z; v[3] = x.w;
    } else {
        ushort4 hh = *(const ushort4*)&inH[row * EMB + t * 4];
        ushort4 ll2 = *(const ushort4*)&inL[row * EMB + t * 4];
        v[0] = bf2f(hh.x) + bf2f(ll2.x); v[1] = bf2f(hh.y) + bf2f(ll2.y);
        v[2] = bf2f(hh.z) + bf2f(ll2.z); v[3] = bf2f(hh.w) + bf2f(ll2.w);
    }
    float ss = v[0] * v[0] + v[1] * v[1] + v[2] * v[2] + v[3] * v[3];
    #pragma unroll
    for (int o = 32; o > 0; o >>= 1) ss += __shfl_down(ss, o);
    if (lane == 0) red[wid] = ss;
    __syncthreads();
    ss = red[0] + red[1] + red[2] + red[3];

    float inv = 1.f / fmaxf(sqrtf(ss), 1e-8f);
    ushort4 ho, lo;
    float s0 = v[0] * inv, s1 = v[1] * inv, s2 = v[2] * inv, s3 = v[3] * inv;
    ho.x = f2bf(s0); lo.x = f2bf(s0 - bf2f(ho.x));
    ho.y = f2bf(s1); lo.y = f2bf(s1 - bf2f(ho.y));
    ho.z = f2bf(s2); lo.z = f2bf(s2 - bf2f(ho.z));
    ho.w = f2bf(s3); lo.w = f2bf(s3 - bf2f(ho.w));
    *(ushort4*)&oH[row * EMB + t * 4] = ho;
    *(ushort4*)&oL[row * EMB + t * 4] = lo;
}

__global__ __launch_bounds__(256)
void add_pos_pair(const float* __restrict__ in, const float* __restrict__ pos,
                  unsigned short* __restrict__ oH, unsigned short* __restrict__ oL)
{
    ull i = ((ull)blockIdx.x * 256 + threadIdx.x) * 4;
    float4 a = *(const float4*)&in[i];
    float4 p = *(const float4*)&pos[(int)(i & (EMB - 1))];
    float w[4] = { a.x + p.x, a.y + p.y, a.z + p.z, a.w + p.w };
    ushort4 ho, lo;
    ho.x = f2bf(w[0]); lo.x = f2bf(w[0] - bf2f(ho.x));
    ho.y = f2bf(w[1]); lo.y = f2bf(w[1] - bf2f(ho.y));
    ho.z = f2bf(w[2]); lo.z = f2bf(w[2] - bf2f(ho.z));
    ho.w = f2bf(w[3]); lo.w = f2bf(w[3] - bf2f(ho.w));
    *(ushort4*)&oH[i] = ho;
    *(ushort4*)&oL[i] = lo;
}

__global__ __launch_bounds__(256)
void split_pair(const float* __restrict__ in, unsigned short* __restrict__ oH,
                unsigned short* __restrict__ oL)
{
    ull i = ((ull)blockIdx.x * 256 + threadIdx.x) * 4;
    float4 a = *(const float4*)&in[i];
    float w[4] = { a.x, a.y, a.z, a.w };
    ushort4 ho, lo;
    ho.x = f2bf(w[0]); lo.x = f2bf(w[0] - bf2f(ho.x));
    ho.y = f2bf(w[1]); lo.y = f2bf(w[1] - bf2f(ho.y));
    ho.z = f2bf(w[2]); lo.z = f2bf(w[2] - bf2f(ho.z));
    ho.w = f2bf(w[3]); lo.w = f2bf(w[3] - bf2f(ho.w));
    *(ushort4*)&oH[i] = ho;
    *(ushort4*)&oL[i] = lo;
}

__global__ __launch_bounds__(256)
void cast_bf16(const float* __restrict__ in, unsigned short* __restrict__ out)
{
    ull i = ((ull)blockIdx.x * 256 + threadIdx.x) * 4;
    float4 a = *(const float4*)&in[i];
    ushort4 ho;
    ho.x = f2bf(a.x); ho.y = f2bf(a.y); ho.z = f2bf(a.z); ho.w = f2bf(a.w);
    *(ushort4*)&out[i] = ho;
}

// ---------------------------------------------------------------------------
namespace {

template<int S, int O>
inline void G(dim3 grid,
              const unsigned short* Ah, const unsigned short* Al, int lda, ll sAz,
              const unsigned short* Bh, const unsigned short* Bl, int ldb, ll sBz,
              void* Ch, void* Cl, int ldc, ll sCz,
              int K, float alpha, const float* bias, int biasRow,
              const unsigned short* rh, const unsigned short* rl, ll sRz, int rm,
              hipStream_t st)
{
    gemm_mfma<S, O><<<grid, dim3(256), 0, st>>>(Ah, Al, lda, sAz, Bh, Bl, ldb, sBz,
                                                Ch, Cl, ldc, sCz, K, alpha, bias, biasRow,
                                                rh, rl, sRz, rm);
}

struct Bufs {
    unsigned short *Ph[6], *Pl[6];
    unsigned short *ATTh, *QK, *VT, *Opart;
    unsigned short *Wih0, *Wih1, *Wo0h, *Wo0l, *Wo1h, *Wo1l;
    float *ml;
};

// rounds 3-5: batch mhas sharing set-0 weights (existing proven path)
void run_mha(int batch,
             const unsigned short* qh, ll sQ,
             const unsigned short* kh, ll sK,
             const float* in_w, const float* in_b,
             const float* out_w, const float* out_b,
             unsigned short* dsth, unsigned short* dstl,
             const unsigned short* resh, const unsigned short* resl, ll sR, int resMode,
             const Bufs& B, bool convW, hipStream_t s)
{
    const ull EE = (ull)EMB * EMB;
    const ll  TE = (ll)NTOK * EMB;
    const ll  VTBS = (ll)1024 * 4096;
    if (convW) {
        cast_bf16<<<3 * EE / 1024, 256, 0, s>>>(in_w, B.Wih0);
        split_pair<<<EE / 1024, 256, 0, s>>>(out_w, B.Wo0h, B.Wo0l);
    }
    gemm_qkproj<<<dim3(8, 32, 2 * batch), 256, 0, s>>>(
        qh, kh, qh + sQ, kh + sK, B.Wih0, B.QK, in_b);
    G<1, 1>(dim3(32, 8, batch), B.Wih0 + 2 * EE, nullptr, EMB, 0, kh, nullptr, EMB, sK,
            B.VT, nullptr, 4096, VTBS, EMB, 1.f, in_b + 2 * EMB, 1, nullptr, nullptr, 0, 0, s);

    if (batch == 1) {
        flash_attn<2, 8><<<256, 512, 0, s>>>(B.QK, B.VT, B.Opart, B.ml, B.ATTh);
        flash_combine<<<NTOK, 256, 0, s>>>(B.Opart, B.ml, B.ATTh);
    } else {
        flash_attn<1, 8><<<256, 512, 0, s>>>(B.QK, B.VT, B.Opart, B.ml, B.ATTh);
    }

    G<2, 2>(dim3(8, 32, batch), B.ATTh, nullptr, EMB, TE, B.Wo0h, B.Wo0l, EMB, 0,
            dsth, dstl, EMB, 2 * TE, EMB, 1.f, out_b, 0, resh, resl, sR, resMode, s);
}

} // namespace

extern "C" void kernel_launch(void* const* d_in, const int* in_sizes, int n_in,
                              void* d_out, int out_size, void* d_ws, size_t ws_size,
                              hipStream_t stream) {
    const float* local_feat  = (const float*)d_in[0];
    const float* global_feat = (const float*)d_in[1];
    const float* text_feat   = (const float*)d_in[2];
    const float* pos_l       = (const float*)d_in[3];
    const float* pos_g       = (const float*)d_in[4];
    const float* fc_w        = (const float*)d_in[5];
    const float* fc_b        = (const float*)d_in[6];
    const float* lg_in_w     = (const float*)d_in[7];
    const float* lg_in_b     = (const float*)d_in[8];
    const float* lg_out_w    = (const float*)d_in[9];
    const float* lg_out_b    = (const float*)d_in[10];
    const float* vt_in_w     = (const float*)d_in[11];
    const float* vt_in_b     = (const float*)d_in[12];
    const float* vt_out_w    = (const float*)d_in[13];
    const float* vt_out_b    = (const float*)d_in[14];
    const float* ml_in_w     = (const float*)d_in[15];
    const float* ml_in_b     = (const float*)d_in[16];
    const float* ml_out_w    = (const float*)d_in[17];
    const float* ml_out_b    = (const float*)d_in[18];
    float* out = (float*)d_out;

    const ull TE = (ull)NTOK * EMB;
    const ull EE = (ull)EMB * EMB;
    unsigned short* w = (unsigned short*)d_ws;
    Bufs B;
    for (int i = 0; i < 6; ++i) { B.Ph[i] = w + (2 * i) * TE; B.Pl[i] = w + (2 * i + 1) * TE; }
    B.ATTh  = w + 12 * TE;              // 3 TE
    B.QK    = w + 15 * TE;              // 6 TE (merged); rounds 3-5 use <=4 TE
    B.Opart = B.QK + 2 * TE;            // aliases QK batch-2 region (batch-1 rounds only)
    B.VT    = w + 21 * TE;              // 3 TE
    B.ml    = (float*)(w + 24 * TE);    // 256 KB = 131072 ushorts
    B.Wih0  = w + 24 * TE + 131072;     // 3 EE
    B.Wih1  = B.Wih0 + 3 * EE;          // 3 EE
    B.Wo0h  = B.Wih1 + 3 * EE;
    B.Wo0l  = B.Wo0h + EE;
    B.Wo1h  = B.Wo0l + EE;
    B.Wo1l  = B.Wo1h + EE;              // end ~= 26.6 TE (~213 MB)

    add_pos_pair<<<TE / 1024, 256, 0, stream>>>(local_feat, pos_l, B.Ph[0], B.Pl[0]);
    add_pos_pair<<<TE / 1024, 256, 0, stream>>>(global_feat, pos_g, B.Ph[1], B.Pl[1]);

    // tf = text @ fc_w^T + fc_b -> P2 pair (text pair staged in QK scratch,
    // fc pair staged in Wo0 — overwritten after the tf GEMM completes)
    split_pair<<<TE / 1024, 256, 0, stream>>>(text_feat, B.QK, B.QK + TE);
    split_pair<<<EE / 1024, 256, 0, stream>>>(fc_w, B.Wo0h, B.Wo0l);
    G<3, 2>(dim3(EMB / 128, NTOK / 128), B.QK, B.QK + TE, EMB, 0, B.Wo0h, B.Wo0l, EMB, 0,
            B.Ph[2], B.Pl[2], EMB, 0, EMB, 1.f, fc_b, 0, nullptr, nullptr, 0, 0, stream);

    // ---- merged round 1+2: three independent mhas ----
    // m0: local_global = mha(lf, gf; lg) + lf   -> P3
    // m1: text_local   = mha(tf, lf; vt) + lf   -> P4
    // m2: text_global  = mha(tf, gf; vt) + tf   -> P5
    cast_bf16<<<3 * EE / 1024, 256, 0, stream>>>(lg_in_w, B.Wih0);
    cast_bf16<<<3 * EE / 1024, 256, 0, stream>>>(vt_in_w, B.Wih1);
    split_pair<<<EE / 1024, 256, 0, stream>>>(lg_out_w, B.Wo0h, B.Wo0l);
    split_pair<<<EE / 1024, 256, 0, stream>>>(vt_out_w, B.Wo1h, B.Wo1l);
    gemm_proj6<<<dim3(8, 32, 6), 256, 0, stream>>>(
        B.Ph[0], B.Ph[1], B.Ph[2], B.Ph[0], B.Ph[2], B.Ph[1],
        B.Wih0, B.Wih1, lg_in_b, vt_in_b, B.QK);
    gemm_vt3<<<dim3(32, 8, 3), 256, 0, stream>>>(
        B.Ph[1], B.Ph[0], B.Ph[1], B.Wih0, B.Wih1, lg_in_b, vt_in_b, B.VT);
    flash_attn<1, 12><<<384, 512, 0, stream>>>(B.QK, B.VT, nullptr, nullptr, B.ATTh);
    gemm_out3<<<dim3(8, 32, 3), 256, 0, stream>>>(
        B.ATTh, B.Wo0h, B.Wo0l, B.Wo1h, B.Wo1l, lg_out_b, vt_out_b,
        B.Ph[3], B.Pl[3],
        B.Ph[0], B.Pl[0], B.Ph[0], B.Pl[0], B.Ph[2], B.Pl[2]);

    const ll T2 = (ll)2 * TE, T4 = (ll)4 * TE;
    // round 3 (batch): gt_gl = mha(P3, P5; ml) -> P0 ; gl_lt = mha(P4, P3; ml) -> P1
    run_mha(2, B.Ph[3], T2, B.Ph[5], -T4, ml_in_w, ml_in_b, ml_out_w, ml_out_b,
            B.Ph[0], B.Pl[0], nullptr, nullptr, 0, 0, B, true, stream);
    // round 4: full = mha(gl_lt=P1, gt_gl=P0; ml)            -> P3
    run_mha(1, B.Ph[1], 0, B.Ph[0], 0, ml_in_w, ml_in_b, ml_out_w, ml_out_b,
            B.Ph[3], B.Pl[3], nullptr, nullptr, 0, 0, B, false, stream);
    // round 5: fusion = mha(tf=P2, full=P3; ml) * tf         -> P4
    run_mha(1, B.Ph[2], 0, B.Ph[3], 0, ml_in_w, ml_in_b, ml_out_w, ml_out_b,
            B.Ph[4], B.Pl[4], B.Ph[2], B.Pl[2], 0, 2, B, false, stream);

    l2norm_rows<false><<<NTOK, 256, 0, stream>>>(nullptr, B.Ph[4], B.Pl[4], B.Ph[4], B.Pl[4]);
    l2norm_rows<true ><<<NTOK, 256, 0, stream>>>(local_feat, nullptr, nullptr, B.Ph[5], B.Pl[5]);

    G<3, 0>(dim3(QTY / 128, QTY / 128, 8),
            B.Ph[4], B.Pl[4], EMB, (ll)QTY * EMB,
            B.Ph[5], B.Pl[5], EMB, (ll)QTY * EMB,
            out, nullptr, QTY, (ll)QTY * QTY,
            EMB, 1.f, nullptr, 0, nullptr, nullptr, 0, 0, stream);
}

// Round 16
// 1602.074 us; speedup vs baseline: 1.2987x; 1.0411x over previous
//
#include <hip/hip_runtime.h>
#include <hip/hip_bf16.h>

// FilterModule: 7x MHA fusion pipeline, bf16 MFMA + flash attention v15.
// v15 = v14 with the merged-round flash re-shaped to avoid grid-tail waste:
//   384-block NZ=12 dispatch (1.5 waves @ 1 block/CU, 417us measured) ->
//   two full-chip 256-block dispatches: flash<2,8> (mha0, +combine) and
//   flash<1,8> (mhas 1-2, direct ATTh). NZ=8 restores z-major XCD/L2 align.
//   Opart for the merged round aliases the dead P3/P4 region (no extra ws).

typedef __attribute__((ext_vector_type(8))) short short8;
typedef __attribute__((ext_vector_type(4))) float f32x4;
typedef unsigned long long ull;
typedef long long ll;

namespace {
constexpr int NTOK = 4096;
constexpr int EMB  = 1024;
constexpr int QTY  = 512;
}

__device__ __forceinline__ float bf2f(unsigned short u) {
    union { float f; unsigned int i; } x; x.i = ((unsigned int)u) << 16; return x.f;
}
__device__ __forceinline__ unsigned short f2bf(float f) {
    union { float f; unsigned int i; } x; x.f = f;
    unsigned int r = x.i + 0x7fffu + ((x.i >> 16) & 1u);
    return (unsigned short)(r >> 16);
}

#define GLOAD_LDS16(g, l) __builtin_amdgcn_global_load_lds( \
    (const __attribute__((address_space(1))) void*)(g),     \
    (__attribute__((address_space(3))) void*)(l), 16, 0, 0)

// ---------------------------------------------------------------------------
// Generic MFMA GEMM (B^T layout), 128x128 tile, BK=32, 256 thr.
template<int SPLITS, int OUTM>
__global__ __launch_bounds__(256)
void gemm_mfma(const unsigned short* __restrict__ Ah, const unsigned short* __restrict__ Al,
               int lda, ll sAz,
               const unsigned short* __restrict__ Bh, const unsigned short* __restrict__ Bl,
               int ldb, ll sBz,
               void* __restrict__ Cp, void* __restrict__ Clp,
               int ldc, ll sCz,
               int K, float alpha, const float* __restrict__ bias, int biasRow,
               const unsigned short* __restrict__ resH, const unsigned short* __restrict__ resL,
               ll sRz, int resMode)
{
    constexpr int NTILES = (SPLITS == 3 ? 4 : (SPLITS == 2 ? 3 : 2));
    constexpr int TSZ = 128 * 32;
    __shared__ unsigned short lds[NTILES * TSZ];
    const int tid  = threadIdx.x;
    const int brow = blockIdx.y * 128;
    const int bcol = blockIdx.x * 128;
    const ll   z   = blockIdx.z;
    Ah += z * sAz; Bh += z * sBz;
    if constexpr (SPLITS == 3) Al += z * sAz;
    if constexpr (SPLITS >= 2) Bl += z * sBz;

    const int lane = tid & 63;
    const int wv = tid >> 6, wr = wv >> 1, wc = wv & 1;
    const int l15 = lane & 15, l4 = lane >> 4;

    f32x4 acc[4][4];
    #pragma unroll
    for (int m = 0; m < 4; ++m)
        #pragma unroll
        for (int n = 0; n < 4; ++n) acc[m][n] = (f32x4){0.f, 0.f, 0.f, 0.f};

    for (int k0 = 0; k0 < K; k0 += 32) {
        #pragma unroll
        for (int i = 0; i < 2; ++i) {
            int idx = tid + i * 256;
            int row = idx >> 2;
            int kc  = (idx & 3) ^ ((row >> 1) & 3);
            GLOAD_LDS16(Ah + (ull)(brow + row) * lda + k0 + kc * 8, &lds[idx * 8]);
            GLOAD_LDS16(Bh + (ull)(bcol + row) * ldb + k0 + kc * 8, &lds[TSZ + idx * 8]);
            if constexpr (SPLITS >= 2)
                GLOAD_LDS16(Bl + (ull)(bcol + row) * ldb + k0 + kc * 8, &lds[2 * TSZ + idx * 8]);
            if constexpr (SPLITS == 3)
                GLOAD_LDS16(Al + (ull)(brow + row) * lda + k0 + kc * 8, &lds[3 * TSZ + idx * 8]);
        }
        __syncthreads();

        short8 ah[4], bh[4], bl2[4], al2[4];
        #pragma unroll
        for (int m = 0; m < 4; ++m) {
            int rr = wr * 64 + m * 16 + l15;
            int sl = l4 ^ ((rr >> 1) & 3);
            int off = rr * 32 + sl * 8;
            ah[m] = *(const short8*)&lds[off];
            if constexpr (SPLITS == 3) al2[m] = *(const short8*)&lds[3 * TSZ + off];
        }
        #pragma unroll
        for (int n = 0; n < 4; ++n) {
            int rr = wc * 64 + n * 16 + l15;
            int sl = l4 ^ ((rr >> 1) & 3);
            int off = rr * 32 + sl * 8;
            bh[n] = *(const short8*)&lds[TSZ + off];
            if constexpr (SPLITS >= 2) bl2[n] = *(const short8*)&lds[2 * TSZ + off];
        }
        #pragma unroll
        for (int m = 0; m < 4; ++m)
            #pragma unroll
            for (int n = 0; n < 4; ++n) {
                acc[m][n] = __builtin_amdgcn_mfma_f32_16x16x32_bf16(ah[m], bh[n], acc[m][n], 0, 0, 0);
                if constexpr (SPLITS >= 2)
                    acc[m][n] = __builtin_amdgcn_mfma_f32_16x16x32_bf16(ah[m], bl2[n], acc[m][n], 0, 0, 0);
                if constexpr (SPLITS == 3)
                    acc[m][n] = __builtin_amdgcn_mfma_f32_16x16x32_bf16(al2[m], bh[n], acc[m][n], 0, 0, 0);
            }
        __syncthreads();
    }

    float* Cf = (float*)Cp + z * sCz;
    unsigned short* Ch = (unsigned short*)Cp + z * sCz;
    unsigned short* Cl = (unsigned short*)Clp + z * sCz;
    const unsigned short* rH = resH + z * sRz;
    const unsigned short* rL = resL + z * sRz;
    const int rowB = brow + wr * 64 + l4 * 4;
    const int colB = bcol + wc * 64 + l15;
    #pragma unroll
    for (int n = 0; n < 4; ++n) {
        int col = colB + n * 16;
        #pragma unroll
        for (int m = 0; m < 4; ++m) {
            #pragma unroll
            for (int r = 0; r < 4; ++r) {
                int row = rowB + m * 16 + r;
                ull ci = (ull)row * ldc + col;
                float v = acc[m][n][r] * alpha;
                if (bias) v += biasRow ? bias[row] : bias[col];
                if (resMode == 1)      v += bf2f(rH[ci]) + bf2f(rL[ci]);
                else if (resMode == 2) v *= bf2f(rH[ci]) + bf2f(rL[ci]);
                if constexpr (OUTM == 0)      Cf[ci] = v;
                else if constexpr (OUTM == 1) Ch[ci] = f2bf(v);
                else {
                    unsigned short h = f2bf(v);
                    Ch[ci] = h;
                    Cl[ci] = f2bf(v - bf2f(h));
                }
            }
        }
    }
}

// ---------------------------------------------------------------------------
// Q/K projection for up to 2 batches (rounds 3-5). z = b*2 + j (j: 0=Q, 1=K).
__global__ __launch_bounds__(256)
void gemm_qkproj(const unsigned short* a0, const unsigned short* a1,
                 const unsigned short* a2, const unsigned short* a3,
                 const unsigned short* __restrict__ W,
                 unsigned short* __restrict__ QK,
                 const float* __restrict__ bias)
{
    constexpr int TSZ = 128 * 32;
    __shared__ unsigned short lds[2 * TSZ];
    const int tid  = threadIdx.x;
    const int brow = blockIdx.y * 128;
    const int bcol = blockIdx.x * 128;
    const int z = blockIdx.z;
    const int j = z & 1, bb = z >> 1;
    const unsigned short* Ah = (z == 0) ? a0 : (z == 1) ? a1 : (z == 2) ? a2 : a3;
    const unsigned short* Bh = W + (ull)j * EMB * EMB;
    unsigned short* C = QK + (ull)bb * NTOK * 2048 + j * 1024;
    const float* bi = bias + j * 1024;

    const int lane = tid & 63;
    const int wv = tid >> 6, wr = wv >> 1, wc = wv & 1;
    const int l15 = lane & 15, l4 = lane >> 4;

    f32x4 acc[4][4];
    #pragma unroll
    for (int m = 0; m < 4; ++m)
        #pragma unroll
        for (int n = 0; n < 4; ++n) acc[m][n] = (f32x4){0.f, 0.f, 0.f, 0.f};

    for (int k0 = 0; k0 < EMB; k0 += 32) {
        #pragma unroll
        for (int i = 0; i < 2; ++i) {
            int idx = tid + i * 256;
            int row = idx >> 2;
            int kc  = (idx & 3) ^ ((row >> 1) & 3);
            GLOAD_LDS16(Ah + (ull)(brow + row) * EMB + k0 + kc * 8, &lds[idx * 8]);
            GLOAD_LDS16(Bh + (ull)(bcol + row) * EMB + k0 + kc * 8, &lds[TSZ + idx * 8]);
        }
        __syncthreads();
        short8 ah[4], bh[4];
        #pragma unroll
        for (int m = 0; m < 4; ++m) {
            int rr = wr * 64 + m * 16 + l15;
            int sl = l4 ^ ((rr >> 1) & 3);
            ah[m] = *(const short8*)&lds[rr * 32 + sl * 8];
        }
        #pragma unroll
        for (int n = 0; n < 4; ++n) {
            int rr = wc * 64 + n * 16 + l15;
            int sl = l4 ^ ((rr >> 1) & 3);
            bh[n] = *(const short8*)&lds[TSZ + rr * 32 + sl * 8];
        }
        #pragma unroll
        for (int m = 0; m < 4; ++m)
            #pragma unroll
            for (int n = 0; n < 4; ++n)
                acc[m][n] = __builtin_amdgcn_mfma_f32_16x16x32_bf16(ah[m], bh[n], acc[m][n], 0, 0, 0);
        __syncthreads();
    }

    const int rowB = brow + wr * 64 + l4 * 4;
    const int colB = bcol + wc * 64 + l15;
    #pragma unroll
    for (int n = 0; n < 4; ++n) {
        int col = colB + n * 16;
        float bv = bi[col];
        #pragma unroll
        for (int m = 0; m < 4; ++m)
            #pragma unroll
            for (int r = 0; r < 4; ++r) {
                int row = rowB + m * 16 + r;
                C[(ull)row * 2048 + col] = f2bf(acc[m][n][r] + bv);
            }
    }
}

// ---------------------------------------------------------------------------
// Merged-round Q/K projection: 3 mhas, z = m*2 + j. m==0 -> (w0,b0) [lg],
// else (w1,b1) [vt]. grid (8, 32, 6).
__global__ __launch_bounds__(256)
void gemm_proj6(const unsigned short* a0, const unsigned short* a1,
                const unsigned short* a2, const unsigned short* a3,
                const unsigned short* a4, const unsigned short* a5,
                const unsigned short* __restrict__ w0, const unsigned short* __restrict__ w1,
                const float* __restrict__ b0, const float* __restrict__ b1,
                unsigned short* __restrict__ QK)
{
    constexpr int TSZ = 128 * 32;
    __shared__ unsigned short lds[2 * TSZ];
    const int tid  = threadIdx.x;
    const int brow = blockIdx.y * 128;
    const int bcol = blockIdx.x * 128;
    const int z = blockIdx.z;
    const int j = z & 1, m6 = z >> 1;
    const unsigned short* Ah = (z == 0) ? a0 : (z == 1) ? a1 : (z == 2) ? a2
                              : (z == 3) ? a3 : (z == 4) ? a4 : a5;
    const unsigned short* Bh = ((m6 == 0) ? w0 : w1) + (ull)j * EMB * EMB;
    unsigned short* C = QK + (ull)m6 * NTOK * 2048 + j * 1024;
    const float* bi = ((m6 == 0) ? b0 : b1) + j * 1024;

    const int lane = tid & 63;
    const int wv = tid >> 6, wr = wv >> 1, wc = wv & 1;
    const int l15 = lane & 15, l4 = lane >> 4;

    f32x4 acc[4][4];
    #pragma unroll
    for (int m = 0; m < 4; ++m)
        #pragma unroll
        for (int n = 0; n < 4; ++n) acc[m][n] = (f32x4){0.f, 0.f, 0.f, 0.f};

    for (int k0 = 0; k0 < EMB; k0 += 32) {
        #pragma unroll
        for (int i = 0; i < 2; ++i) {
            int idx = tid + i * 256;
            int row = idx >> 2;
            int kc  = (idx & 3) ^ ((row >> 1) & 3);
            GLOAD_LDS16(Ah + (ull)(brow + row) * EMB + k0 + kc * 8, &lds[idx * 8]);
            GLOAD_LDS16(Bh + (ull)(bcol + row) * EMB + k0 + kc * 8, &lds[TSZ + idx * 8]);
        }
        __syncthreads();
        short8 ah[4], bh[4];
        #pragma unroll
        for (int m = 0; m < 4; ++m) {
            int rr = wr * 64 + m * 16 + l15;
            int sl = l4 ^ ((rr >> 1) & 3);
            ah[m] = *(const short8*)&lds[rr * 32 + sl * 8];
        }
        #pragma unroll
        for (int n = 0; n < 4; ++n) {
            int rr = wc * 64 + n * 16 + l15;
            int sl = l4 ^ ((rr >> 1) & 3);
            bh[n] = *(const short8*)&lds[TSZ + rr * 32 + sl * 8];
        }
        #pragma unroll
        for (int m = 0; m < 4; ++m)
            #pragma unroll
            for (int n = 0; n < 4; ++n)
                acc[m][n] = __builtin_amdgcn_mfma_f32_16x16x32_bf16(ah[m], bh[n], acc[m][n], 0, 0, 0);
        __syncthreads();
    }

    const int rowB = brow + wr * 64 + l4 * 4;
    const int colB = bcol + wc * 64 + l15;
    #pragma unroll
    for (int n = 0; n < 4; ++n) {
        int col = colB + n * 16;
        float bv = bi[col];
        #pragma unroll
        for (int m = 0; m < 4; ++m)
            #pragma unroll
            for (int r = 0; r < 4; ++r) {
                int row = rowB + m * 16 + r;
                C[(ull)row * 2048 + col] = f2bf(acc[m][n][r] + bv);
            }
    }
}

// ---------------------------------------------------------------------------
// Merged-round V^T projection: 3 mhas, z = m. C[m][d][token] = Wv[d,:]·feat.
// grid (32, 8, 3). bias indexed by row (d).
__global__ __launch_bounds__(256)
void gemm_vt3(const unsigned short* f0, const unsigned short* f1,
              const unsigned short* f2,
              const unsigned short* __restrict__ w0, const unsigned short* __restrict__ w1,
              const float* __restrict__ b0, const float* __restrict__ b1,
              unsigned short* __restrict__ VT)
{
    constexpr int TSZ = 128 * 32;
    __shared__ unsigned short lds[2 * TSZ];
    const int tid  = threadIdx.x;
    const int brow = blockIdx.y * 128;          // d
    const int bcol = blockIdx.x * 128;          // token
    const int z = blockIdx.z;
    const unsigned short* Ah = ((z == 0) ? w0 : w1) + 2ull * EMB * EMB;
    const unsigned short* Bh = (z == 0) ? f0 : (z == 1) ? f1 : f2;
    const float* bi = ((z == 0) ? b0 : b1) + 2048;
    unsigned short* C = VT + (ull)z * 1024 * 4096;

    const int lane = tid & 63;
    const int wv = tid >> 6, wr = wv >> 1, wc = wv & 1;
    const int l15 = lane & 15, l4 = lane >> 4;

    f32x4 acc[4][4];
    #pragma unroll
    for (int m = 0; m < 4; ++m)
        #pragma unroll
        for (int n = 0; n < 4; ++n) acc[m][n] = (f32x4){0.f, 0.f, 0.f, 0.f};

    for (int k0 = 0; k0 < EMB; k0 += 32) {
        #pragma unroll
        for (int i = 0; i < 2; ++i) {
            int idx = tid + i * 256;
            int row = idx >> 2;
            int kc  = (idx & 3) ^ ((row >> 1) & 3);
            GLOAD_LDS16(Ah + (ull)(brow + row) * EMB + k0 + kc * 8, &lds[idx * 8]);
            GLOAD_LDS16(Bh + (ull)(bcol + row) * EMB + k0 + kc * 8, &lds[TSZ + idx * 8]);
        }
        __syncthreads();
        short8 ah[4], bh[4];
        #pragma unroll
        for (int m = 0; m < 4; ++m) {
            int rr = wr * 64 + m * 16 + l15;
            int sl = l4 ^ ((rr >> 1) & 3);
            ah[m] = *(const short8*)&lds[rr * 32 + sl * 8];
        }
        #pragma unroll
        for (int n = 0; n < 4; ++n) {
            int rr = wc * 64 + n * 16 + l15;
            int sl = l4 ^ ((rr >> 1) & 3);
            bh[n] = *(const short8*)&lds[TSZ + rr * 32 + sl * 8];
        }
        #pragma unroll
        for (int m = 0; m < 4; ++m)
            #pragma unroll
            for (int n = 0; n < 4; ++n)
                acc[m][n] = __builtin_amdgcn_mfma_f32_16x16x32_bf16(ah[m], bh[n], acc[m][n], 0, 0, 0);
        __syncthreads();
    }

    const int rowB = brow + wr * 64 + l4 * 4;
    const int colB = bcol + wc * 64 + l15;
    #pragma unroll
    for (int n = 0; n < 4; ++n) {
        int col = colB + n * 16;
        #pragma unroll
        for (int m = 0; m < 4; ++m)
            #pragma unroll
            for (int r = 0; r < 4; ++r) {
                int row = rowB + m * 16 + r;
                C[(ull)row * 4096 + col] = f2bf(acc[m][n][r] + bi[row]);
            }
    }
}

// ---------------------------------------------------------------------------
// Merged-round out-proj: 3 mhas. A = ATTh + z*TE (hi only) x weight pair.
// z==0 -> set0 (lg), else set1 (vt). res add: z0=r0, z1=r1, z2=r2.
__global__ __launch_bounds__(256)
void gemm_out3(const unsigned short* __restrict__ ATTh,
               const unsigned short* __restrict__ w0h, const unsigned short* __restrict__ w0l,
               const unsigned short* __restrict__ w1h, const unsigned short* __restrict__ w1l,
               const float* __restrict__ b0, const float* __restrict__ b1,
               unsigned short* __restrict__ dsth, unsigned short* __restrict__ dstl,
               const unsigned short* r0h, const unsigned short* r0l,
               const unsigned short* r1h, const unsigned short* r1l,
               const unsigned short* r2h, const unsigned short* r2l)
{
    constexpr int TSZ = 128 * 32;
    __shared__ unsigned short lds[3 * TSZ];     // A | Bh | Bl
    const int tid  = threadIdx.x;
    const int brow = blockIdx.y * 128;
    const int bcol = blockIdx.x * 128;
    const int z = blockIdx.z;
    const ll TE = (ll)NTOK * EMB;
    const unsigned short* Ah = ATTh + z * TE;
    const unsigned short* Bh = (z == 0) ? w0h : w1h;
    const unsigned short* Bl = (z == 0) ? w0l : w1l;
    const float* bi = (z == 0) ? b0 : b1;
    unsigned short* Ch = dsth + z * 2 * TE;
    unsigned short* Cl = dstl + z * 2 * TE;
    const unsigned short* rH = (z == 0) ? r0h : (z == 1) ? r1h : r2h;
    const unsigned short* rL = (z == 0) ? r0l : (z == 1) ? r1l : r2l;

    const int lane = tid & 63;
    const int wv = tid >> 6, wr = wv >> 1, wc = wv & 1;
    const int l15 = lane & 15, l4 = lane >> 4;

    f32x4 acc[4][4];
    #pragma unroll
    for (int m = 0; m < 4; ++m)
        #pragma unroll
        for (int n = 0; n < 4; ++n) acc[m][n] = (f32x4){0.f, 0.f, 0.f, 0.f};

    for (int k0 = 0; k0 < EMB; k0 += 32) {
        #pragma unroll
        for (int i = 0; i < 2; ++i) {
            int idx = tid + i * 256;
            int row = idx >> 2;
            int kc  = (idx & 3) ^ ((row >> 1) & 3);
            GLOAD_LDS16(Ah + (ull)(brow + row) * EMB + k0 + kc * 8, &lds[idx * 8]);
            GLOAD_LDS16(Bh + (ull)(bcol + row) * EMB + k0 + kc * 8, &lds[TSZ + idx * 8]);
            GLOAD_LDS16(Bl + (ull)(bcol + row) * EMB + k0 + kc * 8, &lds[2 * TSZ + idx * 8]);
        }
        __syncthreads();
        short8 ah[4], bh[4], bl2[4];
        #pragma unroll
        for (int m = 0; m < 4; ++m) {
            int rr = wr * 64 + m * 16 + l15;
            int sl = l4 ^ ((rr >> 1) & 3);
            ah[m] = *(const short8*)&lds[rr * 32 + sl * 8];
        }
        #pragma unroll
        for (int n = 0; n < 4; ++n) {
            int rr = wc * 64 + n * 16 + l15;
            int sl = l4 ^ ((rr >> 1) & 3);
            bh[n]  = *(const short8*)&lds[TSZ + rr * 32 + sl * 8];
            bl2[n] = *(const short8*)&lds[2 * TSZ + rr * 32 + sl * 8];
        }
        #pragma unroll
        for (int m = 0; m < 4; ++m)
            #pragma unroll
            for (int n = 0; n < 4; ++n) {
                acc[m][n] = __builtin_amdgcn_mfma_f32_16x16x32_bf16(ah[m], bh[n], acc[m][n], 0, 0, 0);
                acc[m][n] = __builtin_amdgcn_mfma_f32_16x16x32_bf16(ah[m], bl2[n], acc[m][n], 0, 0, 0);
            }
        __syncthreads();
    }

    const int rowB = brow + wr * 64 + l4 * 4;
    const int colB = bcol + wc * 64 + l15;
    #pragma unroll
    for (int n = 0; n < 4; ++n) {
        int col = colB + n * 16;
        float bv = bi[col];
        #pragma unroll
        for (int m = 0; m < 4; ++m)
            #pragma unroll
            for (int r = 0; r < 4; ++r) {
                int row = rowB + m * 16 + r;
                ull ci = (ull)row * EMB + col;
                float v = acc[m][n][r] + bv + bf2f(rH[ci]) + bf2f(rL[ci]);
                unsigned short h = f2bf(v);
                Ch[ci] = h;
                Cl[ci] = f2bf(v - bf2f(h));
            }
    }
}

// ---------------------------------------------------------------------------
// Flash attention (v7 structure, LOCKED). 1D grid of 32*NZ blocks:
// zz = bid % NZ, qt = bid / NZ. NSPLIT=2: zz=sp*4+h (batch=1).
// NSPLIT=1: zz=b*4+h. QK [b][4096][2048]; VT [b][1024][4096].
template<int NSPLIT, int NZ>
__global__ __launch_bounds__(512)
void flash_attn(const unsigned short* __restrict__ QK,
                const unsigned short* __restrict__ VT,
                unsigned short* __restrict__ Opart, float* __restrict__ ml,
                unsigned short* __restrict__ attH)
{
    constexpr int KVB = 64;
    constexpr int NTILE = (NTOK / NSPLIT) / KVB;
    __shared__ unsigned short Kt[2][KVB * 256];
    __shared__ unsigned short Vt[2][256 * KVB];

    const int tid = threadIdx.x;
    const int w = tid >> 6, lane = tid & 63;
    const int l15 = lane & 15, l4 = lane >> 4;
    const int bid = blockIdx.x;
    const int zz = bid % NZ, qt = bid / NZ;
    const int h = zz & 3;
    int b, sp;
    if constexpr (NSPLIT == 2) { b = 0; sp = zz >> 2; }
    else                       { b = zz >> 2; sp = 0; }
    const int qrow = qt * 128 + w * 16 + l15;
    const int kv0 = sp * (NTOK / NSPLIT);
    const unsigned short* QKb = QK + (ull)b * NTOK * 2048;
    const unsigned short* VTb = VT + (ull)b * 1024 * 4096;

    short8 qreg[8];
    {
        const unsigned short* qp = QKb + (ull)qrow * 2048 + h * 256;
        #pragma unroll
        for (int c = 0; c < 8; ++c) {
            short8 x = *(const short8*)&qp[c * 32 + l4 * 8];
            #pragma unroll
            for (int j = 0; j < 8; ++j)
                x[j] = (short)f2bf(bf2f((unsigned short)x[j]) * 0.0625f);
            qreg[c] = x;
        }
    }

    f32x4 oacc[16];
    #pragma unroll
    for (int dn = 0; dn < 16; ++dn) oacc[dn] = (f32x4){0.f, 0.f, 0.f, 0.f};
    float m_r = -1e30f, l_r = 0.f;

    auto stage = [&](int t, int buf) {
        int base = kv0 + t * KVB;
        #pragma unroll
        for (int i = 0; i < 4; ++i) {
            int s = tid + i * 512;
            int r = s >> 5, c = s & 31;
            int c0 = c ^ (r & 7);
            GLOAD_LDS16(QKb + (ull)(base + r) * 2048 + 1024 + h * 256 + c0 * 8,
                        &Kt[buf][s * 8]);
        }
        #pragma unroll
        for (int i = 0; i < 4; ++i) {
            int s = tid + i * 512;
            int r = s >> 3, c = s & 7;
            int c0 = c ^ (r & 7);
            GLOAD_LDS16(VTb + (ull)(h * 256 + r) * 4096 + base + c0 * 8,
                        &Vt[buf][s * 8]);
        }
    };

    stage(0, 0);
    for (int t = 0; t < NTILE; ++t) {
        if (t + 1 < NTILE) {
            stage(t + 1, (t + 1) & 1);
            asm volatile("s_waitcnt vmcnt(8)");
        } else {
            asm volatile("s_waitcnt vmcnt(0)");
        }
        __builtin_amdgcn_s_barrier();

        const unsigned short* Kb = Kt[t & 1];
        const unsigned short* Vb = Vt[t & 1];

        f32x4 sacc[4];
        #pragma unroll
        for (int fk = 0; fk < 4; ++fk) sacc[fk] = (f32x4){0.f, 0.f, 0.f, 0.f};
        #pragma unroll
        for (int fk = 0; fk < 4; ++fk) {
            int r = fk * 16 + l15;
            int rx = r & 7;
            #pragma unroll
            for (int c = 0; c < 8; ++c) {
                int ch = (4 * c + l4) ^ rx;
                short8 kf = *(const short8*)&Kb[r * 256 + ch * 8];
                sacc[fk] = __builtin_amdgcn_mfma_f32_16x16x32_bf16(kf, qreg[c], sacc[fk], 0, 0, 0);
            }
        }

        float tm = sacc[0][0];
        #pragma unroll
        for (int fk = 0; fk < 4; ++fk)
            #pragma unroll
            for (int rr = 0; rr < 4; ++rr) tm = fmaxf(tm, sacc[fk][rr]);
        tm = fmaxf(tm, __shfl_xor(tm, 16));
        tm = fmaxf(tm, __shfl_xor(tm, 32));

        bool nomax = __all(tm <= m_r + 5.545f);
        if (!nomax) {
            float mnew = fmaxf(m_r, tm);
            float corr = __expf(m_r - mnew);
            float c4[4];
            #pragma unroll
            for (int r = 0; r < 4; ++r) c4[r] = __shfl(corr, l4 * 4 + r);
            #pragma unroll
            for (int dn = 0; dn < 16; ++dn)
                #pragma unroll
                for (int r = 0; r < 4; ++r) oacc[dn][r] *= c4[r];
            l_r *= corr;
            m_r = mnew;
        }

        float p[16]; float ls = 0.f;
        #pragma unroll
        for (int fk = 0; fk < 4; ++fk)
            #pragma unroll
            for (int rr = 0; rr < 4; ++rr) {
                float e = __expf(sacc[fk][rr] - m_r);
                p[fk * 4 + rr] = e; ls += e;
            }
        ls += __shfl_xor(ls, 16);
        ls += __shfl_xor(ls, 32);
        l_r += ls;

        unsigned int W[4][2];
        #pragma unroll
        for (int f = 0; f < 4; ++f)
            #pragma unroll
            for (int pp = 0; pp < 2; ++pp)
                W[f][pp] = (unsigned int)f2bf(p[f * 4 + 2 * pp]) |
                           ((unsigned int)f2bf(p[f * 4 + 2 * pp + 1]) << 16);

        const int sbase = l15 + ((l4 & 1) << 5);
        const bool hi = (l4 >> 1) & 1;
        #pragma unroll
        for (int kvc = 0; kvc < 2; ++kvc) {
            unsigned int a0 = (unsigned int)__shfl((int)W[2 * kvc][0], sbase);
            unsigned int a1 = (unsigned int)__shfl((int)W[2 * kvc][1], sbase);
            unsigned int a2 = (unsigned int)__shfl((int)W[2 * kvc][0], sbase + 16);
            unsigned int a3 = (unsigned int)__shfl((int)W[2 * kvc][1], sbase + 16);
            unsigned int b0 = (unsigned int)__shfl((int)W[2 * kvc + 1][0], sbase);
            unsigned int b1 = (unsigned int)__shfl((int)W[2 * kvc + 1][1], sbase);
            unsigned int b2 = (unsigned int)__shfl((int)W[2 * kvc + 1][0], sbase + 16);
            unsigned int b3 = (unsigned int)__shfl((int)W[2 * kvc + 1][1], sbase + 16);
            union { unsigned int u[4]; short8 s8; } pa;
            pa.u[0] = hi ? b0 : a0; pa.u[1] = hi ? b1 : a1;
            pa.u[2] = hi ? b2 : a2; pa.u[3] = hi ? b3 : a3;

            #pragma unroll
            for (int dn = 0; dn < 16; ++dn) {
                int row = dn * 16 + l15;
                int ch = (kvc * 4 + l4) ^ (row & 7);
                short8 vf = *(const short8*)&Vb[row * 64 + ch * 8];
                oacc[dn] = __builtin_amdgcn_mfma_f32_16x16x32_bf16(pa.s8, vf, oacc[dn], 0, 0, 0);
            }
        }
        __builtin_amdgcn_s_barrier();
    }

    float inv = 1.f / l_r;
    float i4[4];
    #pragma unroll
    for (int r = 0; r < 4; ++r) i4[r] = __shfl(inv, l4 * 4 + r);

    if constexpr (NSPLIT == 2) {
        unsigned short* Ob = Opart + (((ull)b * 2 + sp) * 4 + h) * NTOK * 256;
        #pragma unroll
        for (int dn = 0; dn < 16; ++dn) {
            int d = dn * 16 + l15;
            #pragma unroll
            for (int r = 0; r < 4; ++r) {
                int q = qt * 128 + w * 16 + l4 * 4 + r;
                Ob[(ull)q * 256 + d] = f2bf(oacc[dn][r] * i4[r]);
            }
        }
        if (l4 == 0) {
            float2* mlp = (float2*)ml + (((ull)b * 2 + sp) * 4 + h) * NTOK + qrow;
            *mlp = make_float2(m_r, l_r);
        }
    } else {
        unsigned short* Ob = attH + (ull)b * NTOK * EMB;
        #pragma unroll
        for (int dn = 0; dn < 16; ++dn) {
            int d = dn * 16 + l15;
            #pragma unroll
            for (int r = 0; r < 4; ++r) {
                int q = qt * 128 + w * 16 + l4 * 4 + r;
                Ob[(ull)q * EMB + h * 256 + d] = f2bf(oacc[dn][r] * i4[r]);
            }
        }
    }
}

// ---------------------------------------------------------------------------
// merge 2 KV-split partials (normalized bf16) -> att bf16 (hi only).
__global__ __launch_bounds__(256)
void flash_combine(const unsigned short* __restrict__ Opart, const float* __restrict__ ml,
                   unsigned short* __restrict__ attH)
{
    const int bx = blockIdx.x;
    const int b = bx >> 12, q = bx & 4095;
    const int t = threadIdx.x;
    const int h = t >> 6, d4 = (t & 63) * 4;

    float2 m0 = ((const float2*)ml)[(((ull)b * 2 + 0) * 4 + h) * NTOK + q];
    float2 m1 = ((const float2*)ml)[(((ull)b * 2 + 1) * 4 + h) * NTOK + q];
    float ms = fmaxf(m0.x, m1.x);
    float w0 = __expf(m0.x - ms) * m0.y;
    float w1 = __expf(m1.x - ms) * m1.y;
    float inv = 1.f / (w0 + w1);
    w0 *= inv; w1 *= inv;

    ushort4 o0 = *(const ushort4*)&Opart[((((ull)b * 2 + 0) * 4 + h) * NTOK + q) * 256 + d4];
    ushort4 o1 = *(const ushort4*)&Opart[((((ull)b * 2 + 1) * 4 + h) * NTOK + q) * 256 + d4];
    ushort4 ho;
    ho.x = f2bf(w0 * bf2f(o0.x) + w1 * bf2f(o1.x));
    ho.y = f2bf(w0 * bf2f(o0.y) + w1 * bf2f(o1.y));
    ho.z = f2bf(w0 * bf2f(o0.z) + w1 * bf2f(o1.z));
    ho.w = f2bf(w0 * bf2f(o0.w) + w1 * bf2f(o1.w));
    *(ushort4*)&attH[(ull)b * NTOK * EMB + (ull)q * EMB + h * 256 + d4] = ho;
}

// ---------------------------------------------------------------------------
template<bool F32IN>
__global__ __launch_bounds__(256)
void l2norm_rows(const float* __restrict__ inF, const unsigned short* __restrict__ inH,
                 const unsigned short* __restrict__ inL,
                 unsigned short* __restrict__ oH, unsigned short* __restrict__ oL)
{
    const ull row = blockIdx.x;
    const int t = threadIdx.x;
    const int lane = t & 63, wid = t >> 6;
    __shared__ float red[4];

    float v[4];
    if constexpr (F32IN) {
        float4 x = *(const float4*)&inF[row * EMB + t * 4];
        v[0] = x.x; v[1] = x.y; v[2] = x.z; v[3] = x.w;
    } else {
        ushort4 hh = *(const ushort4*)&inH[row * EMB + t * 4];
        ushort4 ll2 = *(const ushort4*)&inL[row * EMB + t * 4];
        v[0] = bf2f(hh.x) + bf2f(ll2.x); v[1] = bf2f(hh.y) + bf2f(ll2.y);
        v[2] = bf2f(hh.z) + bf2f(ll2.z); v[3] = bf2f(hh.w) + bf2f(ll2.w);
    }
    float ss = v[0] * v[0] + v[1] * v[1] + v[2] * v[2] + v[3] * v[3];
    #pragma unroll
    for (int o = 32; o > 0; o >>= 1) ss += __shfl_down(ss, o);
    if (lane == 0) red[wid] = ss;
    __syncthreads();
    ss = red[0] + red[1] + red[2] + red[3];

    float inv = 1.f / fmaxf(sqrtf(ss), 1e-8f);
    ushort4 ho, lo;
    float s0 = v[0] * inv, s1 = v[1] * inv, s2 = v[2] * inv, s3 = v[3] * inv;
    ho.x = f2bf(s0); lo.x = f2bf(s0 - bf2f(ho.x));
    ho.y = f2bf(s1); lo.y = f2bf(s1 - bf2f(ho.y));
    ho.z = f2bf(s2); lo.z = f2bf(s2 - bf2f(ho.z));
    ho.w = f2bf(s3); lo.w = f2bf(s3 - bf2f(ho.w));
    *(ushort4*)&oH[row * EMB + t * 4] = ho;
    *(ushort4*)&oL[row * EMB + t * 4] = lo;
}

__global__ __launch_bounds__(256)
void add_pos_pair(const float* __restrict__ in, const float* __restrict__ pos,
                  unsigned short* __restrict__ oH, unsigned short* __restrict__ oL)
{
    ull i = ((ull)blockIdx.x * 256 + threadIdx.x) * 4;
    float4 a = *(const float4*)&in[i];
    float4 p = *(const float4*)&pos[(int)(i & (EMB - 1))];
    float w[4] = { a.x + p.x, a.y + p.y, a.z + p.z, a.w + p.w };
    ushort4 ho, lo;
    ho.x = f2bf(w[0]); lo.x = f2bf(w[0] - bf2f(ho.x));
    ho.y = f2bf(w[1]); lo.y = f2bf(w[1] - bf2f(ho.y));
    ho.z = f2bf(w[2]); lo.z = f2bf(w[2] - bf2f(ho.z));
    ho.w = f2bf(w[3]); lo.w = f2bf(w[3] - bf2f(ho.w));
    *(ushort4*)&oH[i] = ho;
    *(ushort4*)&oL[i] = lo;
}

__global__ __launch_bounds__(256)
void split_pair(const float* __restrict__ in, unsigned short* __restrict__ oH,
                unsigned short* __restrict__ oL)
{
    ull i = ((ull)blockIdx.x * 256 + threadIdx.x) * 4;
    float4 a = *(const float4*)&in[i];
    float w[4] = { a.x, a.y, a.z, a.w };
    ushort4 ho, lo;
    ho.x = f2bf(w[0]); lo.x = f2bf(w[0] - bf2f(ho.x));
    ho.y = f2bf(w[1]); lo.y = f2bf(w[1] - bf2f(ho.y));
    ho.z = f2bf(w[2]); lo.z = f2bf(w[2] - bf2f(ho.z));
    ho.w = f2bf(w[3]); lo.w = f2bf(w[3] - bf2f(ho.w));
    *(ushort4*)&oH[i] = ho;
    *(ushort4*)&oL[i] = lo;
}

__global__ __launch_bounds__(256)
void cast_bf16(const float* __restrict__ in, unsigned short* __restrict__ out)
{
    ull i = ((ull)blockIdx.x * 256 + threadIdx.x) * 4;
    float4 a = *(const float4*)&in[i];
    ushort4 ho;
    ho.x = f2bf(a.x); ho.y = f2bf(a.y); ho.z = f2bf(a.z); ho.w = f2bf(a.w);
    *(ushort4*)&out[i] = ho;
}

// ---------------------------------------------------------------------------
namespace {

template<int S, int O>
inline void G(dim3 grid,
              const unsigned short* Ah, const unsigned short* Al, int lda, ll sAz,
              const unsigned short* Bh, const unsigned short* Bl, int ldb, ll sBz,
              void* Ch, void* Cl, int ldc, ll sCz,
              int K, float alpha, const float* bias, int biasRow,
              const unsigned short* rh, const unsigned short* rl, ll sRz, int rm,
              hipStream_t st)
{
    gemm_mfma<S, O><<<grid, dim3(256), 0, st>>>(Ah, Al, lda, sAz, Bh, Bl, ldb, sBz,
                                                Ch, Cl, ldc, sCz, K, alpha, bias, biasRow,
                                                rh, rl, sRz, rm);
}

struct Bufs {
    unsigned short *Ph[6], *Pl[6];
    unsigned short *ATTh, *QK, *VT, *Opart;
    unsigned short *Wih0, *Wih1, *Wo0h, *Wo0l, *Wo1h, *Wo1l;
    float *ml;
};

// rounds 3-5: batch mhas sharing set-0 weights (existing proven path)
void run_mha(int batch,
             const unsigned short* qh, ll sQ,
             const unsigned short* kh, ll sK,
             const float* in_w, const float* in_b,
             const float* out_w, const float* out_b,
             unsigned short* dsth, unsigned short* dstl,
             const unsigned short* resh, const unsigned short* resl, ll sR, int resMode,
             const Bufs& B, bool convW, hipStream_t s)
{
    const ull EE = (ull)EMB * EMB;
    const ll  TE = (ll)NTOK * EMB;
    const ll  VTBS = (ll)1024 * 4096;
    if (convW) {
        cast_bf16<<<3 * EE / 1024, 256, 0, s>>>(in_w, B.Wih0);
        split_pair<<<EE / 1024, 256, 0, s>>>(out_w, B.Wo0h, B.Wo0l);
    }
    gemm_qkproj<<<dim3(8, 32, 2 * batch), 256, 0, s>>>(
        qh, kh, qh + sQ, kh + sK, B.Wih0, B.QK, in_b);
    G<1, 1>(dim3(32, 8, batch), B.Wih0 + 2 * EE, nullptr, EMB, 0, kh, nullptr, EMB, sK,
            B.VT, nullptr, 4096, VTBS, EMB, 1.f, in_b + 2 * EMB, 1, nullptr, nullptr, 0, 0, s);

    if (batch == 1) {
        flash_attn<2, 8><<<256, 512, 0, s>>>(B.QK, B.VT, B.Opart, B.ml, nullptr);
        flash_combine<<<NTOK, 256, 0, s>>>(B.Opart, B.ml, B.ATTh);
    } else {
        flash_attn<1, 8><<<256, 512, 0, s>>>(B.QK, B.VT, nullptr, nullptr, B.ATTh);
    }

    G<2, 2>(dim3(8, 32, batch), B.ATTh, nullptr, EMB, TE, B.Wo0h, B.Wo0l, EMB, 0,
            dsth, dstl, EMB, 2 * TE, EMB, 1.f, out_b, 0, resh, resl, sR, resMode, s);
}

} // namespace

extern "C" void kernel_launch(void* const* d_in, const int* in_sizes, int n_in,
                              void* d_out, int out_size, void* d_ws, size_t ws_size,
                              hipStream_t stream) {
    const float* local_feat  = (const float*)d_in[0];
    const float* global_feat = (const float*)d_in[1];
    const float* text_feat   = (const float*)d_in[2];
    const float* pos_l       = (const float*)d_in[3];
    const float* pos_g       = (const float*)d_in[4];
    const float* fc_w        = (const float*)d_in[5];
    const float* fc_b        = (const float*)d_in[6];
    const float* lg_in_w     = (const float*)d_in[7];
    const float* lg_in_b     = (const float*)d_in[8];
    const float* lg_out_w    = (const float*)d_in[9];
    const float* lg_out_b    = (const float*)d_in[10];
    const float* vt_in_w     = (const float*)d_in[11];
    const float* vt_in_b     = (const float*)d_in[12];
    const float* vt_out_w    = (const float*)d_in[13];
    const float* vt_out_b    = (const float*)d_in[14];
    const float* ml_in_w     = (const float*)d_in[15];
    const float* ml_in_b     = (const float*)d_in[16];
    const float* ml_out_w    = (const float*)d_in[17];
    const float* ml_out_b    = (const float*)d_in[18];
    float* out = (float*)d_out;

    const ull TE = (ull)NTOK * EMB;
    const ull EE = (ull)EMB * EMB;
    unsigned short* w = (unsigned short*)d_ws;
    Bufs B;
    for (int i = 0; i < 6; ++i) { B.Ph[i] = w + (2 * i) * TE; B.Pl[i] = w + (2 * i + 1) * TE; }
    B.ATTh  = w + 12 * TE;              // 3 TE
    B.QK    = w + 15 * TE;              // 6 TE (merged); rounds 3-5 use <=4 TE
    B.Opart = B.QK + 2 * TE;            // rounds 4-5 only (QK batch-1 region free)
    B.VT    = w + 21 * TE;              // 3 TE
    B.ml    = (float*)(w + 24 * TE);    // 256 KB = 131072 ushorts
    B.Wih0  = w + 24 * TE + 131072;     // 3 EE
    B.Wih1  = B.Wih0 + 3 * EE;          // 3 EE
    B.Wo0h  = B.Wih1 + 3 * EE;
    B.Wo0l  = B.Wo0h + EE;
    B.Wo1h  = B.Wo0l + EE;
    B.Wo1l  = B.Wo1h + EE;

    add_pos_pair<<<TE / 1024, 256, 0, stream>>>(local_feat, pos_l, B.Ph[0], B.Pl[0]);
    add_pos_pair<<<TE / 1024, 256, 0, stream>>>(global_feat, pos_g, B.Ph[1], B.Pl[1]);

    // tf = text @ fc_w^T + fc_b -> P2 pair
    split_pair<<<TE / 1024, 256, 0, stream>>>(text_feat, B.QK, B.QK + TE);
    split_pair<<<EE / 1024, 256, 0, stream>>>(fc_w, B.Wo0h, B.Wo0l);
    G<3, 2>(dim3(EMB / 128, NTOK / 128), B.QK, B.QK + TE, EMB, 0, B.Wo0h, B.Wo0l, EMB, 0,
            B.Ph[2], B.Pl[2], EMB, 0, EMB, 1.f, fc_b, 0, nullptr, nullptr, 0, 0, stream);

    // ---- merged round 1+2: three independent mhas ----
    // m0: local_global = mha(lf, gf; lg) + lf   -> P3
    // m1: text_local   = mha(tf, lf; vt) + lf   -> P4
    // m2: text_global  = mha(tf, gf; vt) + tf   -> P5
    cast_bf16<<<3 * EE / 1024, 256, 0, stream>>>(lg_in_w, B.Wih0);
    cast_bf16<<<3 * EE / 1024, 256, 0, stream>>>(vt_in_w, B.Wih1);
    split_pair<<<EE / 1024, 256, 0, stream>>>(lg_out_w, B.Wo0h, B.Wo0l);
    split_pair<<<EE / 1024, 256, 0, stream>>>(vt_out_w, B.Wo1h, B.Wo1l);
    gemm_proj6<<<dim3(8, 32, 6), 256, 0, stream>>>(
        B.Ph[0], B.Ph[1], B.Ph[2], B.Ph[0], B.Ph[2], B.Ph[1],
        B.Wih0, B.Wih1, lg_in_b, vt_in_b, B.QK);
    gemm_vt3<<<dim3(32, 8, 3), 256, 0, stream>>>(
        B.Ph[1], B.Ph[0], B.Ph[1], B.Wih0, B.Wih1, lg_in_b, vt_in_b, B.VT);
    // mha0: NSPLIT=2 full-chip; Opart aliases dead P3/P4 dest region (2 TE)
    flash_attn<2, 8><<<256, 512, 0, stream>>>(B.QK, B.VT, B.Ph[3], B.ml, nullptr);
    // mhas 1,2: NSPLIT=1 full-chip, b in {0,1} over QK batches 1,2 -> ATTh+TE
    flash_attn<1, 8><<<256, 512, 0, stream>>>(B.QK + 2 * TE, B.VT + TE,
                                              nullptr, nullptr, B.ATTh + TE);
    flash_combine<<<NTOK, 256, 0, stream>>>(B.Ph[3], B.ml, B.ATTh);
    gemm_out3<<<dim3(8, 32, 3), 256, 0, stream>>>(
        B.ATTh, B.Wo0h, B.Wo0l, B.Wo1h, B.Wo1l, lg_out_b, vt_out_b,
        B.Ph[3], B.Pl[3],
        B.Ph[0], B.Pl[0], B.Ph[0], B.Pl[0], B.Ph[2], B.Pl[2]);

    const ll T2 = (ll)2 * TE, T4 = (ll)4 * TE;
    // round 3 (batch): gt_gl = mha(P3, P5; ml) -> P0 ; gl_lt = mha(P4, P3; ml) -> P1
    run_mha(2, B.Ph[3], T2, B.Ph[5], -T4, ml_in_w, ml_in_b, ml_out_w, ml_out_b,
            B.Ph[0], B.Pl[0], nullptr, nullptr, 0, 0, B, true, stream);
    // round 4: full = mha(gl_lt=P1, gt_gl=P0; ml)            -> P3
    run_mha(1, B.Ph[1], 0, B.Ph[0], 0, ml_in_w, ml_in_b, ml_out_w, ml_out_b,
            B.Ph[3], B.Pl[3], nullptr, nullptr, 0, 0, B, false, stream);
    // round 5: fusion = mha(tf=P2, full=P3; ml) * tf         -> P4
    run_mha(1, B.Ph[2], 0, B.Ph[3], 0, ml_in_w, ml_in_b, ml_out_w, ml_out_b,
            B.Ph[4], B.Pl[4], B.Ph[2], B.Pl[2], 0, 2, B, false, stream);

    l2norm_rows<false><<<NTOK, 256, 0, stream>>>(nullptr, B.Ph[4], B.Pl[4], B.Ph[4], B.Pl[4]);
    l2norm_rows<true ><<<NTOK, 256, 0, stream>>>(local_feat, nullptr, nullptr, B.Ph[5], B.Pl[5]);

    G<3, 0>(dim3(QTY / 128, QTY / 128, 8),
            B.Ph[4], B.Pl[4], EMB, (ll)QTY * EMB,
            B.Ph[5], B.Pl[5], EMB, (ll)QTY * EMB,
            out, nullptr, QTY, (ll)QTY * QTY,
            EMB, 1.f, nullptr, 0, nullptr, nullptr, 0, 0, stream);
}

// Round 17
// 1513.459 us; speedup vs baseline: 1.3747x; 1.0586x over previous
//
#include <hip/hip_runtime.h>
#include <hip/hip_bf16.h>

// FilterModule: 7x MHA fusion pipeline, bf16 MFMA + flash attention v16.
// v16 = v15 + BK=64 K-loop for all SPLITS<=2 GEMMs (halves barrier-drain
// stalls; LDS 32-48KB keeps 3-5 blocks/CU). SPLITS=3 (fc, logits) keeps the
// proven BK=32 path. Swizzle = flash-Kt-proven c^(row&7) involution.
// Flash geometry LOCKED at v7; launch shapes locked at v15.

typedef __attribute__((ext_vector_type(8))) short short8;
typedef __attribute__((ext_vector_type(4))) float f32x4;
typedef unsigned long long ull;
typedef long long ll;

namespace {
constexpr int NTOK = 4096;
constexpr int EMB  = 1024;
constexpr int QTY  = 512;
}

__device__ __forceinline__ float bf2f(unsigned short u) {
    union { float f; unsigned int i; } x; x.i = ((unsigned int)u) << 16; return x.f;
}
__device__ __forceinline__ unsigned short f2bf(float f) {
    union { float f; unsigned int i; } x; x.f = f;
    unsigned int r = x.i + 0x7fffu + ((x.i >> 16) & 1u);
    return (unsigned short)(r >> 16);
}

#define GLOAD_LDS16(g, l) __builtin_amdgcn_global_load_lds( \
    (const __attribute__((address_space(1))) void*)(g),     \
    (__attribute__((address_space(3))) void*)(l), 16, 0, 0)

// ---------------------------------------------------------------------------
// Generic MFMA GEMM (B^T layout), 128x128 tile, templated BK (32 or 64).
template<int SPLITS, int OUTM, int BK>
__global__ __launch_bounds__(256)
void gemm_mfma(const unsigned short* __restrict__ Ah, const unsigned short* __restrict__ Al,
               int lda, ll sAz,
               const unsigned short* __restrict__ Bh, const unsigned short* __restrict__ Bl,
               int ldb, ll sBz,
               void* __restrict__ Cp, void* __restrict__ Clp,
               int ldc, ll sCz,
               int K, float alpha, const float* __restrict__ bias, int biasRow,
               const unsigned short* __restrict__ resH, const unsigned short* __restrict__ resL,
               ll sRz, int resMode)
{
    constexpr int NTILES = (SPLITS == 3 ? 4 : (SPLITS == 2 ? 3 : 2));
    constexpr int CPR = BK / 8;               // 16B chunks per row
    constexpr int TSZ = 128 * BK;
    constexpr int NLD = 128 * CPR / 256;      // stage iters per tile
    __shared__ unsigned short lds[NTILES * TSZ];
    const int tid  = threadIdx.x;
    const int brow = blockIdx.y * 128;
    const int bcol = blockIdx.x * 128;
    const ll   z   = blockIdx.z;
    Ah += z * sAz; Bh += z * sBz;
    if constexpr (SPLITS == 3) Al += z * sAz;
    if constexpr (SPLITS >= 2) Bl += z * sBz;

    const int lane = tid & 63;
    const int wv = tid >> 6, wr = wv >> 1, wc = wv & 1;
    const int l15 = lane & 15, l4 = lane >> 4;

    f32x4 acc[4][4];
    #pragma unroll
    for (int m = 0; m < 4; ++m)
        #pragma unroll
        for (int n = 0; n < 4; ++n) acc[m][n] = (f32x4){0.f, 0.f, 0.f, 0.f};

    for (int k0 = 0; k0 < K; k0 += BK) {
        #pragma unroll
        for (int i = 0; i < NLD; ++i) {
            int idx = tid + i * 256;
            int row = idx / CPR, c = idx % CPR;
            int kc = (BK == 32) ? (c ^ ((row >> 1) & 3)) : (c ^ (row & 7));
            GLOAD_LDS16(Ah + (ull)(brow + row) * lda + k0 + kc * 8, &lds[idx * 8]);
            GLOAD_LDS16(Bh + (ull)(bcol + row) * ldb + k0 + kc * 8, &lds[TSZ + idx * 8]);
            if constexpr (SPLITS >= 2)
                GLOAD_LDS16(Bl + (ull)(bcol + row) * ldb + k0 + kc * 8, &lds[2 * TSZ + idx * 8]);
            if constexpr (SPLITS == 3)
                GLOAD_LDS16(Al + (ull)(brow + row) * lda + k0 + kc * 8, &lds[3 * TSZ + idx * 8]);
        }
        __syncthreads();

        #pragma unroll
        for (int kk = 0; kk < BK / 32; ++kk) {
            short8 ah[4], bh[4], bl2[4], al2[4];
            #pragma unroll
            for (int m = 0; m < 4; ++m) {
                int rr = wr * 64 + m * 16 + l15;
                int sl = (BK == 32) ? (l4 ^ ((rr >> 1) & 3)) : ((kk * 4 + l4) ^ (rr & 7));
                int off = rr * BK + sl * 8;
                ah[m] = *(const short8*)&lds[off];
                if constexpr (SPLITS == 3) al2[m] = *(const short8*)&lds[3 * TSZ + off];
            }
            #pragma unroll
            for (int n = 0; n < 4; ++n) {
                int rr = wc * 64 + n * 16 + l15;
                int sl = (BK == 32) ? (l4 ^ ((rr >> 1) & 3)) : ((kk * 4 + l4) ^ (rr & 7));
                int off = rr * BK + sl * 8;
                bh[n] = *(const short8*)&lds[TSZ + off];
                if constexpr (SPLITS >= 2) bl2[n] = *(const short8*)&lds[2 * TSZ + off];
            }
            #pragma unroll
            for (int m = 0; m < 4; ++m)
                #pragma unroll
                for (int n = 0; n < 4; ++n) {
                    acc[m][n] = __builtin_amdgcn_mfma_f32_16x16x32_bf16(ah[m], bh[n], acc[m][n], 0, 0, 0);
                    if constexpr (SPLITS >= 2)
                        acc[m][n] = __builtin_amdgcn_mfma_f32_16x16x32_bf16(ah[m], bl2[n], acc[m][n], 0, 0, 0);
                    if constexpr (SPLITS == 3)
                        acc[m][n] = __builtin_amdgcn_mfma_f32_16x16x32_bf16(al2[m], bh[n], acc[m][n], 0, 0, 0);
                }
        }
        __syncthreads();
    }

    float* Cf = (float*)Cp + z * sCz;
    unsigned short* Ch = (unsigned short*)Cp + z * sCz;
    unsigned short* Cl = (unsigned short*)Clp + z * sCz;
    const unsigned short* rH = resH + z * sRz;
    const unsigned short* rL = resL + z * sRz;
    const int rowB = brow + wr * 64 + l4 * 4;
    const int colB = bcol + wc * 64 + l15;
    #pragma unroll
    for (int n = 0; n < 4; ++n) {
        int col = colB + n * 16;
        #pragma unroll
        for (int m = 0; m < 4; ++m) {
            #pragma unroll
            for (int r = 0; r < 4; ++r) {
                int row = rowB + m * 16 + r;
                ull ci = (ull)row * ldc + col;
                float v = acc[m][n][r] * alpha;
                if (bias) v += biasRow ? bias[row] : bias[col];
                if (resMode == 1)      v += bf2f(rH[ci]) + bf2f(rL[ci]);
                else if (resMode == 2) v *= bf2f(rH[ci]) + bf2f(rL[ci]);
                if constexpr (OUTM == 0)      Cf[ci] = v;
                else if constexpr (OUTM == 1) Ch[ci] = f2bf(v);
                else {
                    unsigned short h = f2bf(v);
                    Ch[ci] = h;
                    Cl[ci] = f2bf(v - bf2f(h));
                }
            }
        }
    }
}

// ---------------------------------------------------------------------------
// BK=64 staging/read helpers (flash-Kt-proven involution c^(row&7))
#define STAGE64(SRC, LD, DSTOFF)                                              \
    {                                                                         \
        int row = idx >> 3, c = idx & 7;                                      \
        int kc = c ^ (row & 7);                                               \
        GLOAD_LDS16(SRC + (ull)(row) * (LD) + k0 + kc * 8, &lds[(DSTOFF) + idx * 8]); \
    }

// ---------------------------------------------------------------------------
// Q/K projection for up to 2 batches (rounds 3-5). z = b*2 + j (j: 0=Q, 1=K).
// BK=64.
__global__ __launch_bounds__(256)
void gemm_qkproj(const unsigned short* a0, const unsigned short* a1,
                 const unsigned short* a2, const unsigned short* a3,
                 const unsigned short* __restrict__ W,
                 unsigned short* __restrict__ QK,
                 const float* __restrict__ bias)
{
    constexpr int TSZ = 128 * 64;
    __shared__ unsigned short lds[2 * TSZ];
    const int tid  = threadIdx.x;
    const int brow = blockIdx.y * 128;
    const int bcol = blockIdx.x * 128;
    const int z = blockIdx.z;
    const int j = z & 1;
    const int bb = z >> 1;
    const unsigned short* Ah = (z == 0) ? a0 : (z == 1) ? a1 : (z == 2) ? a2 : a3;
    const unsigned short* Bh = W + (ull)j * EMB * EMB;
    unsigned short* C = QK + (ull)bb * NTOK * 2048 + j * 1024;
    const float* bi = bias + j * 1024;

    const int lane = tid & 63;
    const int wv = tid >> 6, wr = wv >> 1, wc = wv & 1;
    const int l15 = lane & 15, l4 = lane >> 4;

    f32x4 acc[4][4];
    #pragma unroll
    for (int m = 0; m < 4; ++m)
        #pragma unroll
        for (int n = 0; n < 4; ++n) acc[m][n] = (f32x4){0.f, 0.f, 0.f, 0.f};

    for (int k0 = 0; k0 < EMB; k0 += 64) {
        #pragma unroll
        for (int i = 0; i < 4; ++i) {
            int idx = tid + i * 256;
            STAGE64(Ah + (ull)brow * EMB, EMB, 0);
        }
        #pragma unroll
        for (int i = 0; i < 4; ++i) {
            int idx = tid + i * 256;
            STAGE64(Bh + (ull)bcol * EMB, EMB, TSZ);
        }
        __syncthreads();
        #pragma unroll
        for (int kk = 0; kk < 2; ++kk) {
            short8 ah[4], bh[4];
            #pragma unroll
            for (int m = 0; m < 4; ++m) {
                int rr = wr * 64 + m * 16 + l15;
                int sl = (kk * 4 + l4) ^ (rr & 7);
                ah[m] = *(const short8*)&lds[rr * 64 + sl * 8];
            }
            #pragma unroll
            for (int n = 0; n < 4; ++n) {
                int rr = wc * 64 + n * 16 + l15;
                int sl = (kk * 4 + l4) ^ (rr & 7);
                bh[n] = *(const short8*)&lds[TSZ + rr * 64 + sl * 8];
            }
            #pragma unroll
            for (int m = 0; m < 4; ++m)
                #pragma unroll
                for (int n = 0; n < 4; ++n)
                    acc[m][n] = __builtin_amdgcn_mfma_f32_16x16x32_bf16(ah[m], bh[n], acc[m][n], 0, 0, 0);
        }
        __syncthreads();
    }

    const int rowB = brow + wr * 64 + l4 * 4;
    const int colB = bcol + wc * 64 + l15;
    #pragma unroll
    for (int n = 0; n < 4; ++n) {
        int col = colB + n * 16;
        float bv = bi[col];
        #pragma unroll
        for (int m = 0; m < 4; ++m)
            #pragma unroll
            for (int r = 0; r < 4; ++r) {
                int row = rowB + m * 16 + r;
                C[(ull)row * 2048 + col] = f2bf(acc[m][n][r] + bv);
            }
    }
}

// ---------------------------------------------------------------------------
// Merged-round Q/K projection: 3 mhas, z = m*2 + j. m==0 -> (w0,b0) [lg],
// else (w1,b1) [vt]. grid (8, 32, 6). BK=64.
__global__ __launch_bounds__(256)
void gemm_proj6(const unsigned short* a0, const unsigned short* a1,
                const unsigned short* a2, const unsigned short* a3,
                const unsigned short* a4, const unsigned short* a5,
                const unsigned short* __restrict__ w0, const unsigned short* __restrict__ w1,
                const float* __restrict__ b0, const float* __restrict__ b1,
                unsigned short* __restrict__ QK)
{
    constexpr int TSZ = 128 * 64;
    __shared__ unsigned short lds[2 * TSZ];
    const int tid  = threadIdx.x;
    const int brow = blockIdx.y * 128;
    const int bcol = blockIdx.x * 128;
    const int z = blockIdx.z;
    const int j = z & 1, m6 = z >> 1;
    const unsigned short* Ah = (z == 0) ? a0 : (z == 1) ? a1 : (z == 2) ? a2
                              : (z == 3) ? a3 : (z == 4) ? a4 : a5;
    const unsigned short* Bh = ((m6 == 0) ? w0 : w1) + (ull)j * EMB * EMB;
    unsigned short* C = QK + (ull)m6 * NTOK * 2048 + j * 1024;
    const float* bi = ((m6 == 0) ? b0 : b1) + j * 1024;

    const int lane = tid & 63;
    const int wv = tid >> 6, wr = wv >> 1, wc = wv & 1;
    const int l15 = lane & 15, l4 = lane >> 4;

    f32x4 acc[4][4];
    #pragma unroll
    for (int m = 0; m < 4; ++m)
        #pragma unroll
        for (int n = 0; n < 4; ++n) acc[m][n] = (f32x4){0.f, 0.f, 0.f, 0.f};

    for (int k0 = 0; k0 < EMB; k0 += 64) {
        #pragma unroll
        for (int i = 0; i < 4; ++i) {
            int idx = tid + i * 256;
            STAGE64(Ah + (ull)brow * EMB, EMB, 0);
        }
        #pragma unroll
        for (int i = 0; i < 4; ++i) {
            int idx = tid + i * 256;
            STAGE64(Bh + (ull)bcol * EMB, EMB, TSZ);
        }
        __syncthreads();
        #pragma unroll
        for (int kk = 0; kk < 2; ++kk) {
            short8 ah[4], bh[4];
            #pragma unroll
            for (int m = 0; m < 4; ++m) {
                int rr = wr * 64 + m * 16 + l15;
                int sl = (kk * 4 + l4) ^ (rr & 7);
                ah[m] = *(const short8*)&lds[rr * 64 + sl * 8];
            }
            #pragma unroll
            for (int n = 0; n < 4; ++n) {
                int rr = wc * 64 + n * 16 + l15;
                int sl = (kk * 4 + l4) ^ (rr & 7);
                bh[n] = *(const short8*)&lds[TSZ + rr * 64 + sl * 8];
            }
            #pragma unroll
            for (int m = 0; m < 4; ++m)
                #pragma unroll
                for (int n = 0; n < 4; ++n)
                    acc[m][n] = __builtin_amdgcn_mfma_f32_16x16x32_bf16(ah[m], bh[n], acc[m][n], 0, 0, 0);
        }
        __syncthreads();
    }

    const int rowB = brow + wr * 64 + l4 * 4;
    const int colB = bcol + wc * 64 + l15;
    #pragma unroll
    for (int n = 0; n < 4; ++n) {
        int col = colB + n * 16;
        float bv = bi[col];
        #pragma unroll
        for (int m = 0; m < 4; ++m)
            #pragma unroll
            for (int r = 0; r < 4; ++r) {
                int row = rowB + m * 16 + r;
                C[(ull)row * 2048 + col] = f2bf(acc[m][n][r] + bv);
            }
    }
}

// ---------------------------------------------------------------------------
// Merged-round V^T projection: 3 mhas, z = m. C[m][d][token] = Wv[d,:]·feat.
// grid (32, 8, 3). bias by row (d). BK=64.
__global__ __launch_bounds__(256)
void gemm_vt3(const unsigned short* f0, const unsigned short* f1,
              const unsigned short* f2,
              const unsigned short* __restrict__ w0, const unsigned short* __restrict__ w1,
              const float* __restrict__ b0, const float* __restrict__ b1,
              unsigned short* __restrict__ VT)
{
    constexpr int TSZ = 128 * 64;
    __shared__ unsigned short lds[2 * TSZ];
    const int tid  = threadIdx.x;
    const int brow = blockIdx.y * 128;          // d
    const int bcol = blockIdx.x * 128;          // token
    const int z = blockIdx.z;
    const unsigned short* Ah = ((z == 0) ? w0 : w1) + 2ull * EMB * EMB;
    const unsigned short* Bh = (z == 0) ? f0 : (z == 1) ? f1 : f2;
    const float* bi = ((z == 0) ? b0 : b1) + 2048;
    unsigned short* C = VT + (ull)z * 1024 * 4096;

    const int lane = tid & 63;
    const int wv = tid >> 6, wr = wv >> 1, wc = wv & 1;
    const int l15 = lane & 15, l4 = lane >> 4;

    f32x4 acc[4][4];
    #pragma unroll
    for (int m = 0; m < 4; ++m)
        #pragma unroll
        for (int n = 0; n < 4; ++n) acc[m][n] = (f32x4){0.f, 0.f, 0.f, 0.f};

    for (int k0 = 0; k0 < EMB; k0 += 64) {
        #pragma unroll
        for (int i = 0; i < 4; ++i) {
            int idx = tid + i * 256;
            STAGE64(Ah + (ull)brow * EMB, EMB, 0);
        }
        #pragma unroll
        for (int i = 0; i < 4; ++i) {
            int idx = tid + i * 256;
            STAGE64(Bh + (ull)bcol * EMB, EMB, TSZ);
        }
        __syncthreads();
        #pragma unroll
        for (int kk = 0; kk < 2; ++kk) {
            short8 ah[4], bh[4];
            #pragma unroll
            for (int m = 0; m < 4; ++m) {
                int rr = wr * 64 + m * 16 + l15;
                int sl = (kk * 4 + l4) ^ (rr & 7);
                ah[m] = *(const short8*)&lds[rr * 64 + sl * 8];
            }
            #pragma unroll
            for (int n = 0; n < 4; ++n) {
                int rr = wc * 64 + n * 16 + l15;
                int sl = (kk * 4 + l4) ^ (rr & 7);
                bh[n] = *(const short8*)&lds[TSZ + rr * 64 + sl * 8];
            }
            #pragma unroll
            for (int m = 0; m < 4; ++m)
                #pragma unroll
                for (int n = 0; n < 4; ++n)
                    acc[m][n] = __builtin_amdgcn_mfma_f32_16x16x32_bf16(ah[m], bh[n], acc[m][n], 0, 0, 0);
        }
        __syncthreads();
    }

    const int rowB = brow + wr * 64 + l4 * 4;
    const int colB = bcol + wc * 64 + l15;
    #pragma unroll
    for (int n = 0; n < 4; ++n) {
        int col = colB + n * 16;
        #pragma unroll
        for (int m = 0; m < 4; ++m)
            #pragma unroll
            for (int r = 0; r < 4; ++r) {
                int row = rowB + m * 16 + r;
                C[(ull)row * 4096 + col] = f2bf(acc[m][n][r] + bi[row]);
            }
    }
}

// ---------------------------------------------------------------------------
// Merged-round out-proj: 3 mhas. A = ATTh + z*TE (hi only) x weight pair.
// z==0 -> set0 (lg), else set1 (vt). res add: z0=r0, z1=r1, z2=r2. BK=64.
__global__ __launch_bounds__(256)
void gemm_out3(const unsigned short* __restrict__ ATTh,
               const unsigned short* __restrict__ w0h, const unsigned short* __restrict__ w0l,
               const unsigned short* __restrict__ w1h, const unsigned short* __restrict__ w1l,
               const float* __restrict__ b0, const float* __restrict__ b1,
               unsigned short* __restrict__ dsth, unsigned short* __restrict__ dstl,
               const unsigned short* r0h, const unsigned short* r0l,
               const unsigned short* r1h, const unsigned short* r1l,
               const unsigned short* r2h, const unsigned short* r2l)
{
    constexpr int TSZ = 128 * 64;
    __shared__ unsigned short lds[3 * TSZ];     // A | Bh | Bl (48 KB)
    const int tid  = threadIdx.x;
    const int brow = blockIdx.y * 128;
    const int bcol = blockIdx.x * 128;
    const int z = blockIdx.z;
    const ll TE = (ll)NTOK * EMB;
    const unsigned short* Ah = ATTh + z * TE;
    const unsigned short* Bh = (z == 0) ? w0h : w1h;
    const unsigned short* Bl = (z == 0) ? w0l : w1l;
    const float* bi = (z == 0) ? b0 : b1;
    unsigned short* Ch = dsth + z * 2 * TE;
    unsigned short* Cl = dstl + z * 2 * TE;
    const unsigned short* rH = (z == 0) ? r0h : (z == 1) ? r1h : r2h;
    const unsigned short* rL = (z == 0) ? r0l : (z == 1) ? r1l : r2l;

    const int lane = tid & 63;
    const int wv = tid >> 6, wr = wv >> 1, wc = wv & 1;
    const int l15 = lane & 15, l4 = lane >> 4;

    f32x4 acc[4][4];
    #pragma unroll
    for (int m = 0; m < 4; ++m)
        #pragma unroll
        for (int n = 0; n < 4; ++n) acc[m][n] = (f32x4){0.f, 0.f, 0.f, 0.f};

    for (int k0 = 0; k0 < EMB; k0 += 64) {
        #pragma unroll
        for (int i = 0; i < 4; ++i) {
            int idx = tid + i * 256;
            STAGE64(Ah + (ull)brow * EMB, EMB, 0);
        }
        #pragma unroll
        for (int i = 0; i < 4; ++i) {
            int idx = tid + i * 256;
            STAGE64(Bh + (ull)bcol * EMB, EMB, TSZ);
        }
        #pragma unroll
        for (int i = 0; i < 4; ++i) {
            int idx = tid + i * 256;
            STAGE64(Bl + (ull)bcol * EMB, EMB, 2 * TSZ);
        }
        __syncthreads();
        #pragma unroll
        for (int kk = 0; kk < 2; ++kk) {
            short8 ah[4], bh[4], bl2[4];
            #pragma unroll
            for (int m = 0; m < 4; ++m) {
                int rr = wr * 64 + m * 16 + l15;
                int sl = (kk * 4 + l4) ^ (rr & 7);
                ah[m] = *(const short8*)&lds[rr * 64 + sl * 8];
            }
            #pragma unroll
            for (int n = 0; n < 4; ++n) {
                int rr = wc * 64 + n * 16 + l15;
                int sl = (kk * 4 + l4) ^ (rr & 7);
                bh[n]  = *(const short8*)&lds[TSZ + rr * 64 + sl * 8];
                bl2[n] = *(const short8*)&lds[2 * TSZ + rr * 64 + sl * 8];
            }
            #pragma unroll
            for (int m = 0; m < 4; ++m)
                #pragma unroll
                for (int n = 0; n < 4; ++n) {
                    acc[m][n] = __builtin_amdgcn_mfma_f32_16x16x32_bf16(ah[m], bh[n], acc[m][n], 0, 0, 0);
                    acc[m][n] = __builtin_amdgcn_mfma_f32_16x16x32_bf16(ah[m], bl2[n], acc[m][n], 0, 0, 0);
                }
        }
        __syncthreads();
    }

    const int rowB = brow + wr * 64 + l4 * 4;
    const int colB = bcol + wc * 64 + l15;
    #pragma unroll
    for (int n = 0; n < 4; ++n) {
        int col = colB + n * 16;
        float bv = bi[col];
        #pragma unroll
        for (int m = 0; m < 4; ++m)
            #pragma unroll
            for (int r = 0; r < 4; ++r) {
                int row = rowB + m * 16 + r;
                ull ci = (ull)row * EMB + col;
                float v = acc[m][n][r] + bv + bf2f(rH[ci]) + bf2f(rL[ci]);
                unsigned short h = f2bf(v);
                Ch[ci] = h;
                Cl[ci] = f2bf(v - bf2f(h));
            }
    }
}

// ---------------------------------------------------------------------------
// Flash attention (v7 structure, LOCKED). 1D grid of 32*NZ blocks:
// zz = bid % NZ, qt = bid / NZ. NSPLIT=2: zz=sp*4+h (batch=1).
// NSPLIT=1: zz=b*4+h. QK [b][4096][2048]; VT [b][1024][4096].
template<int NSPLIT, int NZ>
__global__ __launch_bounds__(512)
void flash_attn(const unsigned short* __restrict__ QK,
                const unsigned short* __restrict__ VT,
                unsigned short* __restrict__ Opart, float* __restrict__ ml,
                unsigned short* __restrict__ attH)
{
    constexpr int KVB = 64;
    constexpr int NTILE = (NTOK / NSPLIT) / KVB;
    __shared__ unsigned short Kt[2][KVB * 256];
    __shared__ unsigned short Vt[2][256 * KVB];

    const int tid = threadIdx.x;
    const int w = tid >> 6, lane = tid & 63;
    const int l15 = lane & 15, l4 = lane >> 4;
    const int bid = blockIdx.x;
    const int zz = bid % NZ, qt = bid / NZ;
    const int h = zz & 3;
    int b, sp;
    if constexpr (NSPLIT == 2) { b = 0; sp = zz >> 2; }
    else                       { b = zz >> 2; sp = 0; }
    const int qrow = qt * 128 + w * 16 + l15;
    const int kv0 = sp * (NTOK / NSPLIT);
    const unsigned short* QKb = QK + (ull)b * NTOK * 2048;
    const unsigned short* VTb = VT + (ull)b * 1024 * 4096;

    short8 qreg[8];
    {
        const unsigned short* qp = QKb + (ull)qrow * 2048 + h * 256;
        #pragma unroll
        for (int c = 0; c < 8; ++c) {
            short8 x = *(const short8*)&qp[c * 32 + l4 * 8];
            #pragma unroll
            for (int j = 0; j < 8; ++j)
                x[j] = (short)f2bf(bf2f((unsigned short)x[j]) * 0.0625f);
            qreg[c] = x;
        }
    }

    f32x4 oacc[16];
    #pragma unroll
    for (int dn = 0; dn < 16; ++dn) oacc[dn] = (f32x4){0.f, 0.f, 0.f, 0.f};
    float m_r = -1e30f, l_r = 0.f;

    auto stage = [&](int t, int buf) {
        int base = kv0 + t * KVB;
        #pragma unroll
        for (int i = 0; i < 4; ++i) {
            int s = tid + i * 512;
            int r = s >> 5, c = s & 31;
            int c0 = c ^ (r & 7);
            GLOAD_LDS16(QKb + (ull)(base + r) * 2048 + 1024 + h * 256 + c0 * 8,
                        &Kt[buf][s * 8]);
        }
        #pragma unroll
        for (int i = 0; i < 4; ++i) {
            int s = tid + i * 512;
            int r = s >> 3, c = s & 7;
            int c0 = c ^ (r & 7);
            GLOAD_LDS16(VTb + (ull)(h * 256 + r) * 4096 + base + c0 * 8,
                        &Vt[buf][s * 8]);
        }
    };

    stage(0, 0);
    for (int t = 0; t < NTILE; ++t) {
        if (t + 1 < NTILE) {
            stage(t + 1, (t + 1) & 1);
            asm volatile("s_waitcnt vmcnt(8)");
        } else {
            asm volatile("s_waitcnt vmcnt(0)");
        }
        __builtin_amdgcn_s_barrier();

        const unsigned short* Kb = Kt[t & 1];
        const unsigned short* Vb = Vt[t & 1];

        f32x4 sacc[4];
        #pragma unroll
        for (int fk = 0; fk < 4; ++fk) sacc[fk] = (f32x4){0.f, 0.f, 0.f, 0.f};
        #pragma unroll
        for (int fk = 0; fk < 4; ++fk) {
            int r = fk * 16 + l15;
            int rx = r & 7;
            #pragma unroll
            for (int c = 0; c < 8; ++c) {
                int ch = (4 * c + l4) ^ rx;
                short8 kf = *(const short8*)&Kb[r * 256 + ch * 8];
                sacc[fk] = __builtin_amdgcn_mfma_f32_16x16x32_bf16(kf, qreg[c], sacc[fk], 0, 0, 0);
            }
        }

        float tm = sacc[0][0];
        #pragma unroll
        for (int fk = 0; fk < 4; ++fk)
            #pragma unroll
            for (int rr = 0; rr < 4; ++rr) tm = fmaxf(tm, sacc[fk][rr]);
        tm = fmaxf(tm, __shfl_xor(tm, 16));
        tm = fmaxf(tm, __shfl_xor(tm, 32));

        bool nomax = __all(tm <= m_r + 5.545f);
        if (!nomax) {
            float mnew = fmaxf(m_r, tm);
            float corr = __expf(m_r - mnew);
            float c4[4];
            #pragma unroll
            for (int r = 0; r < 4; ++r) c4[r] = __shfl(corr, l4 * 4 + r);
            #pragma unroll
            for (int dn = 0; dn < 16; ++dn)
                #pragma unroll
                for (int r = 0; r < 4; ++r) oacc[dn][r] *= c4[r];
            l_r *= corr;
            m_r = mnew;
        }

        float p[16]; float ls = 0.f;
        #pragma unroll
        for (int fk = 0; fk < 4; ++fk)
            #pragma unroll
            for (int rr = 0; rr < 4; ++rr) {
                float e = __expf(sacc[fk][rr] - m_r);
                p[fk * 4 + rr] = e; ls += e;
            }
        ls += __shfl_xor(ls, 16);
        ls += __shfl_xor(ls, 32);
        l_r += ls;

        unsigned int W[4][2];
        #pragma unroll
        for (int f = 0; f < 4; ++f)
            #pragma unroll
            for (int pp = 0; pp < 2; ++pp)
                W[f][pp] = (unsigned int)f2bf(p[f * 4 + 2 * pp]) |
                           ((unsigned int)f2bf(p[f * 4 + 2 * pp + 1]) << 16);

        const int sbase = l15 + ((l4 & 1) << 5);
        const bool hi = (l4 >> 1) & 1;
        #pragma unroll
        for (int kvc = 0; kvc < 2; ++kvc) {
            unsigned int a0 = (unsigned int)__shfl((int)W[2 * kvc][0], sbase);
            unsigned int a1 = (unsigned int)__shfl((int)W[2 * kvc][1], sbase);
            unsigned int a2 = (unsigned int)__shfl((int)W[2 * kvc][0], sbase + 16);
            unsigned int a3 = (unsigned int)__shfl((int)W[2 * kvc][1], sbase + 16);
            unsigned int b0 = (unsigned int)__shfl((int)W[2 * kvc + 1][0], sbase);
            unsigned int b1 = (unsigned int)__shfl((int)W[2 * kvc + 1][1], sbase);
            unsigned int b2 = (unsigned int)__shfl((int)W[2 * kvc + 1][0], sbase + 16);
            unsigned int b3 = (unsigned int)__shfl((int)W[2 * kvc + 1][1], sbase + 16);
            union { unsigned int u[4]; short8 s8; } pa;
            pa.u[0] = hi ? b0 : a0; pa.u[1] = hi ? b1 : a1;
            pa.u[2] = hi ? b2 : a2; pa.u[3] = hi ? b3 : a3;

            #pragma unroll
            for (int dn = 0; dn < 16; ++dn) {
                int row = dn * 16 + l15;
                int ch = (kvc * 4 + l4) ^ (row & 7);
                short8 vf = *(const short8*)&Vb[row * 64 + ch * 8];
                oacc[dn] = __builtin_amdgcn_mfma_f32_16x16x32_bf16(pa.s8, vf, oacc[dn], 0, 0, 0);
            }
        }
        __builtin_amdgcn_s_barrier();
    }

    float inv = 1.f / l_r;
    float i4[4];
    #pragma unroll
    for (int r = 0; r < 4; ++r) i4[r] = __shfl(inv, l4 * 4 + r);

    if constexpr (NSPLIT == 2) {
        unsigned short* Ob = Opart + (((ull)b * 2 + sp) * 4 + h) * NTOK * 256;
        #pragma unroll
        for (int dn = 0; dn < 16; ++dn) {
            int d = dn * 16 + l15;
            #pragma unroll
            for (int r = 0; r < 4; ++r) {
                int q = qt * 128 + w * 16 + l4 * 4 + r;
                Ob[(ull)q * 256 + d] = f2bf(oacc[dn][r] * i4[r]);
            }
        }
        if (l4 == 0) {
            float2* mlp = (float2*)ml + (((ull)b * 2 + sp) * 4 + h) * NTOK + qrow;
            *mlp = make_float2(m_r, l_r);
        }
    } else {
        unsigned short* Ob = attH + (ull)b * NTOK * EMB;
        #pragma unroll
        for (int dn = 0; dn < 16; ++dn) {
            int d = dn * 16 + l15;
            #pragma unroll
            for (int r = 0; r < 4; ++r) {
                int q = qt * 128 + w * 16 + l4 * 4 + r;
                Ob[(ull)q * EMB + h * 256 + d] = f2bf(oacc[dn][r] * i4[r]);
            }
        }
    }
}

// ---------------------------------------------------------------------------
// merge 2 KV-split partials (normalized bf16) -> att bf16 (hi only).
__global__ __launch_bounds__(256)
void flash_combine(const unsigned short* __restrict__ Opart, const float* __restrict__ ml,
                   unsigned short* __restrict__ attH)
{
    const int bx = blockIdx.x;
    const int b = bx >> 12, q = bx & 4095;
    const int t = threadIdx.x;
    const int h = t >> 6, d4 = (t & 63) * 4;

    float2 m0 = ((const float2*)ml)[(((ull)b * 2 + 0) * 4 + h) * NTOK + q];
    float2 m1 = ((const float2*)ml)[(((ull)b * 2 + 1) * 4 + h) * NTOK + q];
    float ms = fmaxf(m0.x, m1.x);
    float w0 = __expf(m0.x - ms) * m0.y;
    float w1 = __expf(m1.x - ms) * m1.y;
    float inv = 1.f / (w0 + w1);
    w0 *= inv; w1 *= inv;

    ushort4 o0 = *(const ushort4*)&Opart[((((ull)b * 2 + 0) * 4 + h) * NTOK + q) * 256 + d4];
    ushort4 o1 = *(const ushort4*)&Opart[((((ull)b * 2 + 1) * 4 + h) * NTOK + q) * 256 + d4];
    ushort4 ho;
    ho.x = f2bf(w0 * bf2f(o0.x) + w1 * bf2f(o1.x));
    ho.y = f2bf(w0 * bf2f(o0.y) + w1 * bf2f(o1.y));
    ho.z = f2bf(w0 * bf2f(o0.z) + w1 * bf2f(o1.z));
    ho.w = f2bf(w0 * bf2f(o0.w) + w1 * bf2f(o1.w));
    *(ushort4*)&attH[(ull)b * NTOK * EMB + (ull)q * EMB + h * 256 + d4] = ho;
}

// ---------------------------------------------------------------------------
template<bool F32IN>
__global__ __launch_bounds__(256)
void l2norm_rows(const float* __restrict__ inF, const unsigned short* __restrict__ inH,
                 const unsigned short* __restrict__ inL,
                 unsigned short* __restrict__ oH, unsigned short* __restrict__ oL)
{
    const ull row = blockIdx.x;
    const int t = threadIdx.x;
    const int lane = t & 63, wid = t >> 6;
    __shared__ float red[4];

    float v[4];
    if constexpr (F32IN) {
        float4 x = *(const float4*)&inF[row * EMB + t * 4];
        v[0] = x.x; v[1] = x.y; v[2] = x.z; v[3] = x.w;
    } else {
        ushort4 hh = *(const ushort4*)&inH[row * EMB + t * 4];
        ushort4 ll2 = *(const ushort4*)&inL[row * EMB + t * 4];
        v[0] = bf2f(hh.x) + bf2f(ll2.x); v[1] = bf2f(hh.y) + bf2f(ll2.y);
        v[2] = bf2f(hh.z) + bf2f(ll2.z); v[3] = bf2f(hh.w) + bf2f(ll2.w);
    }
    float ss = v[0] * v[0] + v[1] * v[1] + v[2] * v[2] + v[3] * v[3];
    #pragma unroll
    for (int o = 32; o > 0; o >>= 1) ss += __shfl_down(ss, o);
    if (lane == 0) red[wid] = ss;
    __syncthreads();
    ss = red[0] + red[1] + red[2] + red[3];

    float inv = 1.f / fmaxf(sqrtf(ss), 1e-8f);
    ushort4 ho, lo;
    float s0 = v[0] * inv, s1 = v[1] * inv, s2 = v[2] * inv, s3 = v[3] * inv;
    ho.x = f2bf(s0); lo.x = f2bf(s0 - bf2f(ho.x));
    ho.y = f2bf(s1); lo.y = f2bf(s1 - bf2f(ho.y));
    ho.z = f2bf(s2); lo.z = f2bf(s2 - bf2f(ho.z));
    ho.w = f2bf(s3); lo.w = f2bf(s3 - bf2f(ho.w));
    *(ushort4*)&oH[row * EMB + t * 4] = ho;
    *(ushort4*)&oL[row * EMB + t * 4] = lo;
}

__global__ __launch_bounds__(256)
void add_pos_pair(const float* __restrict__ in, const float* __restrict__ pos,
                  unsigned short* __restrict__ oH, unsigned short* __restrict__ oL)
{
    ull i = ((ull)blockIdx.x * 256 + threadIdx.x) * 4;
    float4 a = *(const float4*)&in[i];
    float4 p = *(const float4*)&pos[(int)(i & (EMB - 1))];
    float w[4] = { a.x + p.x, a.y + p.y, a.z + p.z, a.w + p.w };
    ushort4 ho, lo;
    ho.x = f2bf(w[0]); lo.x = f2bf(w[0] - bf2f(ho.x));
    ho.y = f2bf(w[1]); lo.y = f2bf(w[1] - bf2f(ho.y));
    ho.z = f2bf(w[2]); lo.z = f2bf(w[2] - bf2f(ho.z));
    ho.w = f2bf(w[3]); lo.w = f2bf(w[3] - bf2f(ho.w));
    *(ushort4*)&oH[i] = ho;
    *(ushort4*)&oL[i] = lo;
}

__global__ __launch_bounds__(256)
void split_pair(const float* __restrict__ in, unsigned short* __restrict__ oH,
                unsigned short* __restrict__ oL)
{
    ull i = ((ull)blockIdx.x * 256 + threadIdx.x) * 4;
    float4 a = *(const float4*)&in[i];
    float w[4] = { a.x, a.y, a.z, a.w };
    ushort4 ho, lo;
    ho.x = f2bf(w[0]); lo.x = f2bf(w[0] - bf2f(ho.x));
    ho.y = f2bf(w[1]); lo.y = f2bf(w[1] - bf2f(ho.y));
    ho.z = f2bf(w[2]); lo.z = f2bf(w[2] - bf2f(ho.z));
    ho.w = f2bf(w[3]); lo.w = f2bf(w[3] - bf2f(ho.w));
    *(ushort4*)&oH[i] = ho;
    *(ushort4*)&oL[i] = lo;
}

__global__ __launch_bounds__(256)
void cast_bf16(const float* __restrict__ in, unsigned short* __restrict__ out)
{
    ull i = ((ull)blockIdx.x * 256 + threadIdx.x) * 4;
    float4 a = *(const float4*)&in[i];
    ushort4 ho;
    ho.x = f2bf(a.x); ho.y = f2bf(a.y); ho.z = f2bf(a.z); ho.w = f2bf(a.w);
    *(ushort4*)&out[i] = ho;
}

// ---------------------------------------------------------------------------
namespace {

template<int S, int O, int BKv = 32>
inline void G(dim3 grid,
              const unsigned short* Ah, const unsigned short* Al, int lda, ll sAz,
              const unsigned short* Bh, const unsigned short* Bl, int ldb, ll sBz,
              void* Ch, void* Cl, int ldc, ll sCz,
              int K, float alpha, const float* bias, int biasRow,
              const unsigned short* rh, const unsigned short* rl, ll sRz, int rm,
              hipStream_t st)
{
    gemm_mfma<S, O, BKv><<<grid, dim3(256), 0, st>>>(Ah, Al, lda, sAz, Bh, Bl, ldb, sBz,
                                                     Ch, Cl, ldc, sCz, K, alpha, bias, biasRow,
                                                     rh, rl, sRz, rm);
}

struct Bufs {
    unsigned short *Ph[6], *Pl[6];
    unsigned short *ATTh, *QK, *VT, *Opart;
    unsigned short *Wih0, *Wih1, *Wo0h, *Wo0l, *Wo1h, *Wo1l;
    float *ml;
};

// rounds 3-5: batch mhas sharing set-0 weights (proven path)
void run_mha(int batch,
             const unsigned short* qh, ll sQ,
             const unsigned short* kh, ll sK,
             const float* in_w, const float* in_b,
             const float* out_w, const float* out_b,
             unsigned short* dsth, unsigned short* dstl,
             const unsigned short* resh, const unsigned short* resl, ll sR, int resMode,
             const Bufs& B, bool convW, hipStream_t s)
{
    const ull EE = (ull)EMB * EMB;
    const ll  TE = (ll)NTOK * EMB;
    const ll  VTBS = (ll)1024 * 4096;
    if (convW) {
        cast_bf16<<<3 * EE / 1024, 256, 0, s>>>(in_w, B.Wih0);
        split_pair<<<EE / 1024, 256, 0, s>>>(out_w, B.Wo0h, B.Wo0l);
    }
    gemm_qkproj<<<dim3(8, 32, 2 * batch), 256, 0, s>>>(
        qh, kh, qh + sQ, kh + sK, B.Wih0, B.QK, in_b);
    G<1, 1, 64>(dim3(32, 8, batch), B.Wih0 + 2 * EE, nullptr, EMB, 0, kh, nullptr, EMB, sK,
                B.VT, nullptr, 4096, VTBS, EMB, 1.f, in_b + 2 * EMB, 1, nullptr, nullptr, 0, 0, s);

    if (batch == 1) {
        flash_attn<2, 8><<<256, 512, 0, s>>>(B.QK, B.VT, B.Opart, B.ml, nullptr);
        flash_combine<<<NTOK, 256, 0, s>>>(B.Opart, B.ml, B.ATTh);
    } else {
        flash_attn<1, 8><<<256, 512, 0, s>>>(B.QK, B.VT, nullptr, nullptr, B.ATTh);
    }

    G<2, 2, 64>(dim3(8, 32, batch), B.ATTh, nullptr, EMB, TE, B.Wo0h, B.Wo0l, EMB, 0,
                dsth, dstl, EMB, 2 * TE, EMB, 1.f, out_b, 0, resh, resl, sR, resMode, s);
}

} // namespace

extern "C" void kernel_launch(void* const* d_in, const int* in_sizes, int n_in,
                              void* d_out, int out_size, void* d_ws, size_t ws_size,
                              hipStream_t stream) {
    const float* local_feat  = (const float*)d_in[0];
    const float* global_feat = (const float*)d_in[1];
    const float* text_feat   = (const float*)d_in[2];
    const float* pos_l       = (const float*)d_in[3];
    const float* pos_g       = (const float*)d_in[4];
    const float* fc_w        = (const float*)d_in[5];
    const float* fc_b        = (const float*)d_in[6];
    const float* lg_in_w     = (const float*)d_in[7];
    const float* lg_in_b     = (const float*)d_in[8];
    const float* lg_out_w    = (const float*)d_in[9];
    const float* lg_out_b    = (const float*)d_in[10];
    const float* vt_in_w     = (const float*)d_in[11];
    const float* vt_in_b     = (const float*)d_in[12];
    const float* vt_out_w    = (const float*)d_in[13];
    const float* vt_out_b    = (const float*)d_in[14];
    const float* ml_in_w     = (const float*)d_in[15];
    const float* ml_in_b     = (const float*)d_in[16];
    const float* ml_out_w    = (const float*)d_in[17];
    const float* ml_out_b    = (const float*)d_in[18];
    float* out = (float*)d_out;

    const ull TE = (ull)NTOK * EMB;
    const ull EE = (ull)EMB * EMB;
    unsigned short* w = (unsigned short*)d_ws;
    Bufs B;
    for (int i = 0; i < 6; ++i) { B.Ph[i] = w + (2 * i) * TE; B.Pl[i] = w + (2 * i + 1) * TE; }
    B.ATTh  = w + 12 * TE;              // 3 TE
    B.QK    = w + 15 * TE;              // 6 TE (merged); rounds 3-5 use <=4 TE
    B.Opart = B.QK + 2 * TE;            // rounds 4-5 only (QK batch-1 region free)
    B.VT    = w + 21 * TE;              // 3 TE
    B.ml    = (float*)(w + 24 * TE);    // 256 KB = 131072 ushorts
    B.Wih0  = w + 24 * TE + 131072;     // 3 EE
    B.Wih1  = B.Wih0 + 3 * EE;          // 3 EE
    B.Wo0h  = B.Wih1 + 3 * EE;
    B.Wo0l  = B.Wo0h + EE;
    B.Wo1h  = B.Wo0l + EE;
    B.Wo1l  = B.Wo1h + EE;

    add_pos_pair<<<TE / 1024, 256, 0, stream>>>(local_feat, pos_l, B.Ph[0], B.Pl[0]);
    add_pos_pair<<<TE / 1024, 256, 0, stream>>>(global_feat, pos_g, B.Ph[1], B.Pl[1]);

    // tf = text @ fc_w^T + fc_b -> P2 pair
    split_pair<<<TE / 1024, 256, 0, stream>>>(text_feat, B.QK, B.QK + TE);
    split_pair<<<EE / 1024, 256, 0, stream>>>(fc_w, B.Wo0h, B.Wo0l);
    G<3, 2>(dim3(EMB / 128, NTOK / 128), B.QK, B.QK + TE, EMB, 0, B.Wo0h, B.Wo0l, EMB, 0,
            B.Ph[2], B.Pl[2], EMB, 0, EMB, 1.f, fc_b, 0, nullptr, nullptr, 0, 0, stream);

    // ---- merged round 1+2: three independent mhas ----
    // m0: local_global = mha(lf, gf; lg) + lf   -> P3
    // m1: text_local   = mha(tf, lf; vt) + lf   -> P4
    // m2: text_global  = mha(tf, gf; vt) + tf   -> P5
    cast_bf16<<<3 * EE / 1024, 256, 0, stream>>>(lg_in_w, B.Wih0);
    cast_bf16<<<3 * EE / 1024, 256, 0, stream>>>(vt_in_w, B.Wih1);
    split_pair<<<EE / 1024, 256, 0, stream>>>(lg_out_w, B.Wo0h, B.Wo0l);
    split_pair<<<EE / 1024, 256, 0, stream>>>(vt_out_w, B.Wo1h, B.Wo1l);
    gemm_proj6<<<dim3(8, 32, 6), 256, 0, stream>>>(
        B.Ph[0], B.Ph[1], B.Ph[2], B.Ph[0], B.Ph[2], B.Ph[1],
        B.Wih0, B.Wih1, lg_in_b, vt_in_b, B.QK);
    gemm_vt3<<<dim3(32, 8, 3), 256, 0, stream>>>(
        B.Ph[1], B.Ph[0], B.Ph[1], B.Wih0, B.Wih1, lg_in_b, vt_in_b, B.VT);
    // mha0: NSPLIT=2 full-chip; Opart aliases dead P3/P4 dest region (2 TE)
    flash_attn<2, 8><<<256, 512, 0, stream>>>(B.QK, B.VT, B.Ph[3], B.ml, nullptr);
    // mhas 1,2: NSPLIT=1 full-chip, b in {0,1} over QK batches 1,2 -> ATTh+TE
    flash_attn<1, 8><<<256, 512, 0, stream>>>(B.QK + 2 * TE, B.VT + TE,
                                              nullptr, nullptr, B.ATTh + TE);
    flash_combine<<<NTOK, 256, 0, stream>>>(B.Ph[3], B.ml, B.ATTh);
    gemm_out3<<<dim3(8, 32, 3), 256, 0, stream>>>(
        B.ATTh, B.Wo0h, B.Wo0l, B.Wo1h, B.Wo1l, lg_out_b, vt_out_b,
        B.Ph[3], B.Pl[3],
        B.Ph[0], B.Pl[0], B.Ph[0], B.Pl[0], B.Ph[2], B.Pl[2]);

    const ll T2 = (ll)2 * TE, T4 = (ll)4 * TE;
    // round 3 (batch): gt_gl = mha(P3, P5; ml) -> P0 ; gl_lt = mha(P4, P3; ml) -> P1
    run_mha(2, B.Ph[3], T2, B.Ph[5], -T4, ml_in_w, ml_in_b, ml_out_w, ml_out_b,
            B.Ph[0], B.Pl[0], nullptr, nullptr, 0, 0, B, true, stream);
    // round 4: full = mha(gl_lt=P1, gt_gl=P0; ml)            -> P3
    run_mha(1, B.Ph[1], 0, B.Ph[0], 0, ml_in_w, ml_in_b, ml_out_w, ml_out_b,
            B.Ph[3], B.Pl[3], nullptr, nullptr, 0, 0, B, false, stream);
    // round 5: fusion = mha(tf=P2, full=P3; ml) * tf         -> P4
    run_mha(1, B.Ph[2], 0, B.Ph[3], 0, ml_in_w, ml_in_b, ml_out_w, ml_out_b,
            B.Ph[4], B.Pl[4], B.Ph[2], B.Pl[2], 0, 2, B, false, stream);

    l2norm_rows<false><<<NTOK, 256, 0, stream>>>(nullptr, B.Ph[4], B.Pl[4], B.Ph[4], B.Pl[4]);
    l2norm_rows<true ><<<NTOK, 256, 0, stream>>>(local_feat, nullptr, nullptr, B.Ph[5], B.Pl[5]);

    G<3, 0>(dim3(QTY / 128, QTY / 128, 8),
            B.Ph[4], B.Pl[4], EMB, (ll)QTY * EMB,
            B.Ph[5], B.Pl[5], EMB, (ll)QTY * EMB,
            out, nullptr, QTY, (ll)QTY * QTY,
            EMB, 1.f, nullptr, 0, nullptr, nullptr, 0, 0, stream);
}

// Round 18
// 1492.075 us; speedup vs baseline: 1.3944x; 1.0143x over previous
//
#include <hip/hip_runtime.h>
#include <hip/hip_bf16.h>

// FilterModule: 7x MHA fusion pipeline, bf16 MFMA + flash attention v17.
// v17 = v16 + BK=64 for the SPLITS=3 GEMMs (fc, logits: grid-limited to
// 1 block/CU so 64KB LDS is free) + launch-count trim (merged weight-convert
// and l2norm dispatches). Flash LOCKED (LDS-BW floor); shapes locked at v15.

typedef __attribute__((ext_vector_type(8))) short short8;
typedef __attribute__((ext_vector_type(4))) float f32x4;
typedef unsigned long long ull;
typedef long long ll;

namespace {
constexpr int NTOK = 4096;
constexpr int EMB  = 1024;
constexpr int QTY  = 512;
}

__device__ __forceinline__ float bf2f(unsigned short u) {
    union { float f; unsigned int i; } x; x.i = ((unsigned int)u) << 16; return x.f;
}
__device__ __forceinline__ unsigned short f2bf(float f) {
    union { float f; unsigned int i; } x; x.f = f;
    unsigned int r = x.i + 0x7fffu + ((x.i >> 16) & 1u);
    return (unsigned short)(r >> 16);
}

#define GLOAD_LDS16(g, l) __builtin_amdgcn_global_load_lds( \
    (const __attribute__((address_space(1))) void*)(g),     \
    (__attribute__((address_space(3))) void*)(l), 16, 0, 0)

// ---------------------------------------------------------------------------
// Generic MFMA GEMM (B^T layout), 128x128 tile, templated BK (32 or 64).
template<int SPLITS, int OUTM, int BK>
__global__ __launch_bounds__(256)
void gemm_mfma(const unsigned short* __restrict__ Ah, const unsigned short* __restrict__ Al,
               int lda, ll sAz,
               const unsigned short* __restrict__ Bh, const unsigned short* __restrict__ Bl,
               int ldb, ll sBz,
               void* __restrict__ Cp, void* __restrict__ Clp,
               int ldc, ll sCz,
               int K, float alpha, const float* __restrict__ bias, int biasRow,
               const unsigned short* __restrict__ resH, const unsigned short* __restrict__ resL,
               ll sRz, int resMode)
{
    constexpr int NTILES = (SPLITS == 3 ? 4 : (SPLITS == 2 ? 3 : 2));
    constexpr int CPR = BK / 8;               // 16B chunks per row
    constexpr int TSZ = 128 * BK;
    constexpr int NLD = 128 * CPR / 256;      // stage iters per tile
    __shared__ unsigned short lds[NTILES * TSZ];
    const int tid  = threadIdx.x;
    const int brow = blockIdx.y * 128;
    const int bcol = blockIdx.x * 128;
    const ll   z   = blockIdx.z;
    Ah += z * sAz; Bh += z * sBz;
    if constexpr (SPLITS == 3) Al += z * sAz;
    if constexpr (SPLITS >= 2) Bl += z * sBz;

    const int lane = tid & 63;
    const int wv = tid >> 6, wr = wv >> 1, wc = wv & 1;
    const int l15 = lane & 15, l4 = lane >> 4;

    f32x4 acc[4][4];
    #pragma unroll
    for (int m = 0; m < 4; ++m)
        #pragma unroll
        for (int n = 0; n < 4; ++n) acc[m][n] = (f32x4){0.f, 0.f, 0.f, 0.f};

    for (int k0 = 0; k0 < K; k0 += BK) {
        #pragma unroll
        for (int i = 0; i < NLD; ++i) {
            int idx = tid + i * 256;
            int row = idx / CPR, c = idx % CPR;
            int kc = (BK == 32) ? (c ^ ((row >> 1) & 3)) : (c ^ (row & 7));
            GLOAD_LDS16(Ah + (ull)(brow + row) * lda + k0 + kc * 8, &lds[idx * 8]);
            GLOAD_LDS16(Bh + (ull)(bcol + row) * ldb + k0 + kc * 8, &lds[TSZ + idx * 8]);
            if constexpr (SPLITS >= 2)
                GLOAD_LDS16(Bl + (ull)(bcol + row) * ldb + k0 + kc * 8, &lds[2 * TSZ + idx * 8]);
            if constexpr (SPLITS == 3)
                GLOAD_LDS16(Al + (ull)(brow + row) * lda + k0 + kc * 8, &lds[3 * TSZ + idx * 8]);
        }
        __syncthreads();

        #pragma unroll
        for (int kk = 0; kk < BK / 32; ++kk) {
            short8 ah[4], bh[4], bl2[4], al2[4];
            #pragma unroll
            for (int m = 0; m < 4; ++m) {
                int rr = wr * 64 + m * 16 + l15;
                int sl = (BK == 32) ? (l4 ^ ((rr >> 1) & 3)) : ((kk * 4 + l4) ^ (rr & 7));
                int off = rr * BK + sl * 8;
                ah[m] = *(const short8*)&lds[off];
                if constexpr (SPLITS == 3) al2[m] = *(const short8*)&lds[3 * TSZ + off];
            }
            #pragma unroll
            for (int n = 0; n < 4; ++n) {
                int rr = wc * 64 + n * 16 + l15;
                int sl = (BK == 32) ? (l4 ^ ((rr >> 1) & 3)) : ((kk * 4 + l4) ^ (rr & 7));
                int off = rr * BK + sl * 8;
                bh[n] = *(const short8*)&lds[TSZ + off];
                if constexpr (SPLITS >= 2) bl2[n] = *(const short8*)&lds[2 * TSZ + off];
            }
            #pragma unroll
            for (int m = 0; m < 4; ++m)
                #pragma unroll
                for (int n = 0; n < 4; ++n) {
                    acc[m][n] = __builtin_amdgcn_mfma_f32_16x16x32_bf16(ah[m], bh[n], acc[m][n], 0, 0, 0);
                    if constexpr (SPLITS >= 2)
                        acc[m][n] = __builtin_amdgcn_mfma_f32_16x16x32_bf16(ah[m], bl2[n], acc[m][n], 0, 0, 0);
                    if constexpr (SPLITS == 3)
                        acc[m][n] = __builtin_amdgcn_mfma_f32_16x16x32_bf16(al2[m], bh[n], acc[m][n], 0, 0, 0);
                }
        }
        __syncthreads();
    }

    float* Cf = (float*)Cp + z * sCz;
    unsigned short* Ch = (unsigned short*)Cp + z * sCz;
    unsigned short* Cl = (unsigned short*)Clp + z * sCz;
    const unsigned short* rH = resH + z * sRz;
    const unsigned short* rL = resL + z * sRz;
    const int rowB = brow + wr * 64 + l4 * 4;
    const int colB = bcol + wc * 64 + l15;
    #pragma unroll
    for (int n = 0; n < 4; ++n) {
        int col = colB + n * 16;
        #pragma unroll
        for (int m = 0; m < 4; ++m) {
            #pragma unroll
            for (int r = 0; r < 4; ++r) {
                int row = rowB + m * 16 + r;
                ull ci = (ull)row * ldc + col;
                float v = acc[m][n][r] * alpha;
                if (bias) v += biasRow ? bias[row] : bias[col];
                if (resMode == 1)      v += bf2f(rH[ci]) + bf2f(rL[ci]);
                else if (resMode == 2) v *= bf2f(rH[ci]) + bf2f(rL[ci]);
                if constexpr (OUTM == 0)      Cf[ci] = v;
                else if constexpr (OUTM == 1) Ch[ci] = f2bf(v);
                else {
                    unsigned short h = f2bf(v);
                    Ch[ci] = h;
                    Cl[ci] = f2bf(v - bf2f(h));
                }
            }
        }
    }
}

// ---------------------------------------------------------------------------
// BK=64 staging helper (flash-Kt-proven involution c^(row&7))
#define STAGE64(SRC, LD, DSTOFF)                                              \
    {                                                                         \
        int row = idx >> 3, c = idx & 7;                                      \
        int kc = c ^ (row & 7);                                               \
        GLOAD_LDS16(SRC + (ull)(row) * (LD) + k0 + kc * 8, &lds[(DSTOFF) + idx * 8]); \
    }

// ---------------------------------------------------------------------------
// Q/K projection for up to 2 batches (rounds 3-5). z = b*2 + j. BK=64.
__global__ __launch_bounds__(256)
void gemm_qkproj(const unsigned short* a0, const unsigned short* a1,
                 const unsigned short* a2, const unsigned short* a3,
                 const unsigned short* __restrict__ W,
                 unsigned short* __restrict__ QK,
                 const float* __restrict__ bias)
{
    constexpr int TSZ = 128 * 64;
    __shared__ unsigned short lds[2 * TSZ];
    const int tid  = threadIdx.x;
    const int brow = blockIdx.y * 128;
    const int bcol = blockIdx.x * 128;
    const int z = blockIdx.z;
    const int j = z & 1;
    const int bb = z >> 1;
    const unsigned short* Ah = (z == 0) ? a0 : (z == 1) ? a1 : (z == 2) ? a2 : a3;
    const unsigned short* Bh = W + (ull)j * EMB * EMB;
    unsigned short* C = QK + (ull)bb * NTOK * 2048 + j * 1024;
    const float* bi = bias + j * 1024;

    const int lane = tid & 63;
    const int wv = tid >> 6, wr = wv >> 1, wc = wv & 1;
    const int l15 = lane & 15, l4 = lane >> 4;

    f32x4 acc[4][4];
    #pragma unroll
    for (int m = 0; m < 4; ++m)
        #pragma unroll
        for (int n = 0; n < 4; ++n) acc[m][n] = (f32x4){0.f, 0.f, 0.f, 0.f};

    for (int k0 = 0; k0 < EMB; k0 += 64) {
        #pragma unroll
        for (int i = 0; i < 4; ++i) {
            int idx = tid + i * 256;
            STAGE64(Ah + (ull)brow * EMB, EMB, 0);
        }
        #pragma unroll
        for (int i = 0; i < 4; ++i) {
            int idx = tid + i * 256;
            STAGE64(Bh + (ull)bcol * EMB, EMB, TSZ);
        }
        __syncthreads();
        #pragma unroll
        for (int kk = 0; kk < 2; ++kk) {
            short8 ah[4], bh[4];
            #pragma unroll
            for (int m = 0; m < 4; ++m) {
                int rr = wr * 64 + m * 16 + l15;
                int sl = (kk * 4 + l4) ^ (rr & 7);
                ah[m] = *(const short8*)&lds[rr * 64 + sl * 8];
            }
            #pragma unroll
            for (int n = 0; n < 4; ++n) {
                int rr = wc * 64 + n * 16 + l15;
                int sl = (kk * 4 + l4) ^ (rr & 7);
                bh[n] = *(const short8*)&lds[TSZ + rr * 64 + sl * 8];
            }
            #pragma unroll
            for (int m = 0; m < 4; ++m)
                #pragma unroll
                for (int n = 0; n < 4; ++n)
                    acc[m][n] = __builtin_amdgcn_mfma_f32_16x16x32_bf16(ah[m], bh[n], acc[m][n], 0, 0, 0);
        }
        __syncthreads();
    }

    const int rowB = brow + wr * 64 + l4 * 4;
    const int colB = bcol + wc * 64 + l15;
    #pragma unroll
    for (int n = 0; n < 4; ++n) {
        int col = colB + n * 16;
        float bv = bi[col];
        #pragma unroll
        for (int m = 0; m < 4; ++m)
            #pragma unroll
            for (int r = 0; r < 4; ++r) {
                int row = rowB + m * 16 + r;
                C[(ull)row * 2048 + col] = f2bf(acc[m][n][r] + bv);
            }
    }
}

// ---------------------------------------------------------------------------
// Merged-round Q/K projection: 3 mhas, z = m*2 + j. BK=64. grid (8,32,6).
__global__ __launch_bounds__(256)
void gemm_proj6(const unsigned short* a0, const unsigned short* a1,
                const unsigned short* a2, const unsigned short* a3,
                const unsigned short* a4, const unsigned short* a5,
                const unsigned short* __restrict__ w0, const unsigned short* __restrict__ w1,
                const float* __restrict__ b0, const float* __restrict__ b1,
                unsigned short* __restrict__ QK)
{
    constexpr int TSZ = 128 * 64;
    __shared__ unsigned short lds[2 * TSZ];
    const int tid  = threadIdx.x;
    const int brow = blockIdx.y * 128;
    const int bcol = blockIdx.x * 128;
    const int z = blockIdx.z;
    const int j = z & 1, m6 = z >> 1;
    const unsigned short* Ah = (z == 0) ? a0 : (z == 1) ? a1 : (z == 2) ? a2
                              : (z == 3) ? a3 : (z == 4) ? a4 : a5;
    const unsigned short* Bh = ((m6 == 0) ? w0 : w1) + (ull)j * EMB * EMB;
    unsigned short* C = QK + (ull)m6 * NTOK * 2048 + j * 1024;
    const float* bi = ((m6 == 0) ? b0 : b1) + j * 1024;

    const int lane = tid & 63;
    const int wv = tid >> 6, wr = wv >> 1, wc = wv & 1;
    const int l15 = lane & 15, l4 = lane >> 4;

    f32x4 acc[4][4];
    #pragma unroll
    for (int m = 0; m < 4; ++m)
        #pragma unroll
        for (int n = 0; n < 4; ++n) acc[m][n] = (f32x4){0.f, 0.f, 0.f, 0.f};

    for (int k0 = 0; k0 < EMB; k0 += 64) {
        #pragma unroll
        for (int i = 0; i < 4; ++i) {
            int idx = tid + i * 256;
            STAGE64(Ah + (ull)brow * EMB, EMB, 0);
        }
        #pragma unroll
        for (int i = 0; i < 4; ++i) {
            int idx = tid + i * 256;
            STAGE64(Bh + (ull)bcol * EMB, EMB, TSZ);
        }
        __syncthreads();
        #pragma unroll
        for (int kk = 0; kk < 2; ++kk) {
            short8 ah[4], bh[4];
            #pragma unroll
            for (int m = 0; m < 4; ++m) {
                int rr = wr * 64 + m * 16 + l15;
                int sl = (kk * 4 + l4) ^ (rr & 7);
                ah[m] = *(const short8*)&lds[rr * 64 + sl * 8];
            }
            #pragma unroll
            for (int n = 0; n < 4; ++n) {
                int rr = wc * 64 + n * 16 + l15;
                int sl = (kk * 4 + l4) ^ (rr & 7);
                bh[n] = *(const short8*)&lds[TSZ + rr * 64 + sl * 8];
            }
            #pragma unroll
            for (int m = 0; m < 4; ++m)
                #pragma unroll
                for (int n = 0; n < 4; ++n)
                    acc[m][n] = __builtin_amdgcn_mfma_f32_16x16x32_bf16(ah[m], bh[n], acc[m][n], 0, 0, 0);
        }
        __syncthreads();
    }

    const int rowB = brow + wr * 64 + l4 * 4;
    const int colB = bcol + wc * 64 + l15;
    #pragma unroll
    for (int n = 0; n < 4; ++n) {
        int col = colB + n * 16;
        float bv = bi[col];
        #pragma unroll
        for (int m = 0; m < 4; ++m)
            #pragma unroll
            for (int r = 0; r < 4; ++r) {
                int row = rowB + m * 16 + r;
                C[(ull)row * 2048 + col] = f2bf(acc[m][n][r] + bv);
            }
    }
}

// ---------------------------------------------------------------------------
// Merged-round V^T projection: 3 mhas, z = m. BK=64. grid (32,8,3).
__global__ __launch_bounds__(256)
void gemm_vt3(const unsigned short* f0, const unsigned short* f1,
              const unsigned short* f2,
              const unsigned short* __restrict__ w0, const unsigned short* __restrict__ w1,
              const float* __restrict__ b0, const float* __restrict__ b1,
              unsigned short* __restrict__ VT)
{
    constexpr int TSZ = 128 * 64;
    __shared__ unsigned short lds[2 * TSZ];
    const int tid  = threadIdx.x;
    const int brow = blockIdx.y * 128;          // d
    const int bcol = blockIdx.x * 128;          // token
    const int z = blockIdx.z;
    const unsigned short* Ah = ((z == 0) ? w0 : w1) + 2ull * EMB * EMB;
    const unsigned short* Bh = (z == 0) ? f0 : (z == 1) ? f1 : f2;
    const float* bi = ((z == 0) ? b0 : b1) + 2048;
    unsigned short* C = VT + (ull)z * 1024 * 4096;

    const int lane = tid & 63;
    const int wv = tid >> 6, wr = wv >> 1, wc = wv & 1;
    const int l15 = lane & 15, l4 = lane >> 4;

    f32x4 acc[4][4];
    #pragma unroll
    for (int m = 0; m < 4; ++m)
        #pragma unroll
        for (int n = 0; n < 4; ++n) acc[m][n] = (f32x4){0.f, 0.f, 0.f, 0.f};

    for (int k0 = 0; k0 < EMB; k0 += 64) {
        #pragma unroll
        for (int i = 0; i < 4; ++i) {
            int idx = tid + i * 256;
            STAGE64(Ah + (ull)brow * EMB, EMB, 0);
        }
        #pragma unroll
        for (int i = 0; i < 4; ++i) {
            int idx = tid + i * 256;
            STAGE64(Bh + (ull)bcol * EMB, EMB, TSZ);
        }
        __syncthreads();
        #pragma unroll
        for (int kk = 0; kk < 2; ++kk) {
            short8 ah[4], bh[4];
            #pragma unroll
            for (int m = 0; m < 4; ++m) {
                int rr = wr * 64 + m * 16 + l15;
                int sl = (kk * 4 + l4) ^ (rr & 7);
                ah[m] = *(const short8*)&lds[rr * 64 + sl * 8];
            }
            #pragma unroll
            for (int n = 0; n < 4; ++n) {
                int rr = wc * 64 + n * 16 + l15;
                int sl = (kk * 4 + l4) ^ (rr & 7);
                bh[n] = *(const short8*)&lds[TSZ + rr * 64 + sl * 8];
            }
            #pragma unroll
            for (int m = 0; m < 4; ++m)
                #pragma unroll
                for (int n = 0; n < 4; ++n)
                    acc[m][n] = __builtin_amdgcn_mfma_f32_16x16x32_bf16(ah[m], bh[n], acc[m][n], 0, 0, 0);
        }
        __syncthreads();
    }

    const int rowB = brow + wr * 64 + l4 * 4;
    const int colB = bcol + wc * 64 + l15;
    #pragma unroll
    for (int n = 0; n < 4; ++n) {
        int col = colB + n * 16;
        #pragma unroll
        for (int m = 0; m < 4; ++m)
            #pragma unroll
            for (int r = 0; r < 4; ++r) {
                int row = rowB + m * 16 + r;
                C[(ull)row * 4096 + col] = f2bf(acc[m][n][r] + bi[row]);
            }
    }
}

// ---------------------------------------------------------------------------
// Merged-round out-proj: 3 mhas. BK=64. grid (8,32,3).
__global__ __launch_bounds__(256)
void gemm_out3(const unsigned short* __restrict__ ATTh,
               const unsigned short* __restrict__ w0h, const unsigned short* __restrict__ w0l,
               const unsigned short* __restrict__ w1h, const unsigned short* __restrict__ w1l,
               const float* __restrict__ b0, const float* __restrict__ b1,
               unsigned short* __restrict__ dsth, unsigned short* __restrict__ dstl,
               const unsigned short* r0h, const unsigned short* r0l,
               const unsigned short* r1h, const unsigned short* r1l,
               const unsigned short* r2h, const unsigned short* r2l)
{
    constexpr int TSZ = 128 * 64;
    __shared__ unsigned short lds[3 * TSZ];     // A | Bh | Bl (48 KB)
    const int tid  = threadIdx.x;
    const int brow = blockIdx.y * 128;
    const int bcol = blockIdx.x * 128;
    const int z = blockIdx.z;
    const ll TE = (ll)NTOK * EMB;
    const unsigned short* Ah = ATTh + z * TE;
    const unsigned short* Bh = (z == 0) ? w0h : w1h;
    const unsigned short* Bl = (z == 0) ? w0l : w1l;
    const float* bi = (z == 0) ? b0 : b1;
    unsigned short* Ch = dsth + z * 2 * TE;
    unsigned short* Cl = dstl + z * 2 * TE;
    const unsigned short* rH = (z == 0) ? r0h : (z == 1) ? r1h : r2h;
    const unsigned short* rL = (z == 0) ? r0l : (z == 1) ? r1l : r2l;

    const int lane = tid & 63;
    const int wv = tid >> 6, wr = wv >> 1, wc = wv & 1;
    const int l15 = lane & 15, l4 = lane >> 4;

    f32x4 acc[4][4];
    #pragma unroll
    for (int m = 0; m < 4; ++m)
        #pragma unroll
        for (int n = 0; n < 4; ++n) acc[m][n] = (f32x4){0.f, 0.f, 0.f, 0.f};

    for (int k0 = 0; k0 < EMB; k0 += 64) {
        #pragma unroll
        for (int i = 0; i < 4; ++i) {
            int idx = tid + i * 256;
            STAGE64(Ah + (ull)brow * EMB, EMB, 0);
        }
        #pragma unroll
        for (int i = 0; i < 4; ++i) {
            int idx = tid + i * 256;
            STAGE64(Bh + (ull)bcol * EMB, EMB, TSZ);
        }
        #pragma unroll
        for (int i = 0; i < 4; ++i) {
            int idx = tid + i * 256;
            STAGE64(Bl + (ull)bcol * EMB, EMB, 2 * TSZ);
        }
        __syncthreads();
        #pragma unroll
        for (int kk = 0; kk < 2; ++kk) {
            short8 ah[4], bh[4], bl2[4];
            #pragma unroll
            for (int m = 0; m < 4; ++m) {
                int rr = wr * 64 + m * 16 + l15;
                int sl = (kk * 4 + l4) ^ (rr & 7);
                ah[m] = *(const short8*)&lds[rr * 64 + sl * 8];
            }
            #pragma unroll
            for (int n = 0; n < 4; ++n) {
                int rr = wc * 64 + n * 16 + l15;
                int sl = (kk * 4 + l4) ^ (rr & 7);
                bh[n]  = *(const short8*)&lds[TSZ + rr * 64 + sl * 8];
                bl2[n] = *(const short8*)&lds[2 * TSZ + rr * 64 + sl * 8];
            }
            #pragma unroll
            for (int m = 0; m < 4; ++m)
                #pragma unroll
                for (int n = 0; n < 4; ++n) {
                    acc[m][n] = __builtin_amdgcn_mfma_f32_16x16x32_bf16(ah[m], bh[n], acc[m][n], 0, 0, 0);
                    acc[m][n] = __builtin_amdgcn_mfma_f32_16x16x32_bf16(ah[m], bl2[n], acc[m][n], 0, 0, 0);
                }
        }
        __syncthreads();
    }

    const int rowB = brow + wr * 64 + l4 * 4;
    const int colB = bcol + wc * 64 + l15;
    #pragma unroll
    for (int n = 0; n < 4; ++n) {
        int col = colB + n * 16;
        float bv = bi[col];
        #pragma unroll
        for (int m = 0; m < 4; ++m)
            #pragma unroll
            for (int r = 0; r < 4; ++r) {
                int row = rowB + m * 16 + r;
                ull ci = (ull)row * EMB + col;
                float v = acc[m][n][r] + bv + bf2f(rH[ci]) + bf2f(rL[ci]);
                unsigned short h = f2bf(v);
                Ch[ci] = h;
                Cl[ci] = f2bf(v - bf2f(h));
            }
    }
}

// ---------------------------------------------------------------------------
// Flash attention (v7 structure, LOCKED). 1D grid of 32*NZ blocks:
// zz = bid % NZ, qt = bid / NZ. NSPLIT=2: zz=sp*4+h (batch=1).
// NSPLIT=1: zz=b*4+h. QK [b][4096][2048]; VT [b][1024][4096].
template<int NSPLIT, int NZ>
__global__ __launch_bounds__(512)
void flash_attn(const unsigned short* __restrict__ QK,
                const unsigned short* __restrict__ VT,
                unsigned short* __restrict__ Opart, float* __restrict__ ml,
                unsigned short* __restrict__ attH)
{
    constexpr int KVB = 64;
    constexpr int NTILE = (NTOK / NSPLIT) / KVB;
    __shared__ unsigned short Kt[2][KVB * 256];
    __shared__ unsigned short Vt[2][256 * KVB];

    const int tid = threadIdx.x;
    const int w = tid >> 6, lane = tid & 63;
    const int l15 = lane & 15, l4 = lane >> 4;
    const int bid = blockIdx.x;
    const int zz = bid % NZ, qt = bid / NZ;
    const int h = zz & 3;
    int b, sp;
    if constexpr (NSPLIT == 2) { b = 0; sp = zz >> 2; }
    else                       { b = zz >> 2; sp = 0; }
    const int qrow = qt * 128 + w * 16 + l15;
    const int kv0 = sp * (NTOK / NSPLIT);
    const unsigned short* QKb = QK + (ull)b * NTOK * 2048;
    const unsigned short* VTb = VT + (ull)b * 1024 * 4096;

    short8 qreg[8];
    {
        const unsigned short* qp = QKb + (ull)qrow * 2048 + h * 256;
        #pragma unroll
        for (int c = 0; c < 8; ++c) {
            short8 x = *(const short8*)&qp[c * 32 + l4 * 8];
            #pragma unroll
            for (int j = 0; j < 8; ++j)
                x[j] = (short)f2bf(bf2f((unsigned short)x[j]) * 0.0625f);
            qreg[c] = x;
        }
    }

    f32x4 oacc[16];
    #pragma unroll
    for (int dn = 0; dn < 16; ++dn) oacc[dn] = (f32x4){0.f, 0.f, 0.f, 0.f};
    float m_r = -1e30f, l_r = 0.f;

    auto stage = [&](int t, int buf) {
        int base = kv0 + t * KVB;
        #pragma unroll
        for (int i = 0; i < 4; ++i) {
            int s = tid + i * 512;
            int r = s >> 5, c = s & 31;
            int c0 = c ^ (r & 7);
            GLOAD_LDS16(QKb + (ull)(base + r) * 2048 + 1024 + h * 256 + c0 * 8,
                        &Kt[buf][s * 8]);
        }
        #pragma unroll
        for (int i = 0; i < 4; ++i) {
            int s = tid + i * 512;
            int r = s >> 3, c = s & 7;
            int c0 = c ^ (r & 7);
            GLOAD_LDS16(VTb + (ull)(h * 256 + r) * 4096 + base + c0 * 8,
                        &Vt[buf][s * 8]);
        }
    };

    stage(0, 0);
    for (int t = 0; t < NTILE; ++t) {
        if (t + 1 < NTILE) {
            stage(t + 1, (t + 1) & 1);
            asm volatile("s_waitcnt vmcnt(8)");
        } else {
            asm volatile("s_waitcnt vmcnt(0)");
        }
        __builtin_amdgcn_s_barrier();

        const unsigned short* Kb = Kt[t & 1];
        const unsigned short* Vb = Vt[t & 1];

        f32x4 sacc[4];
        #pragma unroll
        for (int fk = 0; fk < 4; ++fk) sacc[fk] = (f32x4){0.f, 0.f, 0.f, 0.f};
        #pragma unroll
        for (int fk = 0; fk < 4; ++fk) {
            int r = fk * 16 + l15;
            int rx = r & 7;
            #pragma unroll
            for (int c = 0; c < 8; ++c) {
                int ch = (4 * c + l4) ^ rx;
                short8 kf = *(const short8*)&Kb[r * 256 + ch * 8];
                sacc[fk] = __builtin_amdgcn_mfma_f32_16x16x32_bf16(kf, qreg[c], sacc[fk], 0, 0, 0);
            }
        }

        float tm = sacc[0][0];
        #pragma unroll
        for (int fk = 0; fk < 4; ++fk)
            #pragma unroll
            for (int rr = 0; rr < 4; ++rr) tm = fmaxf(tm, sacc[fk][rr]);
        tm = fmaxf(tm, __shfl_xor(tm, 16));
        tm = fmaxf(tm, __shfl_xor(tm, 32));

        bool nomax = __all(tm <= m_r + 5.545f);
        if (!nomax) {
            float mnew = fmaxf(m_r, tm);
            float corr = __expf(m_r - mnew);
            float c4[4];
            #pragma unroll
            for (int r = 0; r < 4; ++r) c4[r] = __shfl(corr, l4 * 4 + r);
            #pragma unroll
            for (int dn = 0; dn < 16; ++dn)
                #pragma unroll
                for (int r = 0; r < 4; ++r) oacc[dn][r] *= c4[r];
            l_r *= corr;
            m_r = mnew;
        }

        float p[16]; float ls = 0.f;
        #pragma unroll
        for (int fk = 0; fk < 4; ++fk)
            #pragma unroll
            for (int rr = 0; rr < 4; ++rr) {
                float e = __expf(sacc[fk][rr] - m_r);
                p[fk * 4 + rr] = e; ls += e;
            }
        ls += __shfl_xor(ls, 16);
        ls += __shfl_xor(ls, 32);
        l_r += ls;

        unsigned int W[4][2];
        #pragma unroll
        for (int f = 0; f < 4; ++f)
            #pragma unroll
            for (int pp = 0; pp < 2; ++pp)
                W[f][pp] = (unsigned int)f2bf(p[f * 4 + 2 * pp]) |
                           ((unsigned int)f2bf(p[f * 4 + 2 * pp + 1]) << 16);

        const int sbase = l15 + ((l4 & 1) << 5);
        const bool hi = (l4 >> 1) & 1;
        #pragma unroll
        for (int kvc = 0; kvc < 2; ++kvc) {
            unsigned int a0 = (unsigned int)__shfl((int)W[2 * kvc][0], sbase);
            unsigned int a1 = (unsigned int)__shfl((int)W[2 * kvc][1], sbase);
            unsigned int a2 = (unsigned int)__shfl((int)W[2 * kvc][0], sbase + 16);
            unsigned int a3 = (unsigned int)__shfl((int)W[2 * kvc][1], sbase + 16);
            unsigned int b0 = (unsigned int)__shfl((int)W[2 * kvc + 1][0], sbase);
            unsigned int b1 = (unsigned int)__shfl((int)W[2 * kvc + 1][1], sbase);
            unsigned int b2 = (unsigned int)__shfl((int)W[2 * kvc + 1][0], sbase + 16);
            unsigned int b3 = (unsigned int)__shfl((int)W[2 * kvc + 1][1], sbase + 16);
            union { unsigned int u[4]; short8 s8; } pa;
            pa.u[0] = hi ? b0 : a0; pa.u[1] = hi ? b1 : a1;
            pa.u[2] = hi ? b2 : a2; pa.u[3] = hi ? b3 : a3;

            #pragma unroll
            for (int dn = 0; dn < 16; ++dn) {
                int row = dn * 16 + l15;
                int ch = (kvc * 4 + l4) ^ (row & 7);
                short8 vf = *(const short8*)&Vb[row * 64 + ch * 8];
                oacc[dn] = __builtin_amdgcn_mfma_f32_16x16x32_bf16(pa.s8, vf, oacc[dn], 0, 0, 0);
            }
        }
        __builtin_amdgcn_s_barrier();
    }

    float inv = 1.f / l_r;
    float i4[4];
    #pragma unroll
    for (int r = 0; r < 4; ++r) i4[r] = __shfl(inv, l4 * 4 + r);

    if constexpr (NSPLIT == 2) {
        unsigned short* Ob = Opart + (((ull)b * 2 + sp) * 4 + h) * NTOK * 256;
        #pragma unroll
        for (int dn = 0; dn < 16; ++dn) {
            int d = dn * 16 + l15;
            #pragma unroll
            for (int r = 0; r < 4; ++r) {
                int q = qt * 128 + w * 16 + l4 * 4 + r;
                Ob[(ull)q * 256 + d] = f2bf(oacc[dn][r] * i4[r]);
            }
        }
        if (l4 == 0) {
            float2* mlp = (float2*)ml + (((ull)b * 2 + sp) * 4 + h) * NTOK + qrow;
            *mlp = make_float2(m_r, l_r);
        }
    } else {
        unsigned short* Ob = attH + (ull)b * NTOK * EMB;
        #pragma unroll
        for (int dn = 0; dn < 16; ++dn) {
            int d = dn * 16 + l15;
            #pragma unroll
            for (int r = 0; r < 4; ++r) {
                int q = qt * 128 + w * 16 + l4 * 4 + r;
                Ob[(ull)q * EMB + h * 256 + d] = f2bf(oacc[dn][r] * i4[r]);
            }
        }
    }
}

// ---------------------------------------------------------------------------
// merge 2 KV-split partials (normalized bf16) -> att bf16 (hi only).
__global__ __launch_bounds__(256)
void flash_combine(const unsigned short* __restrict__ Opart, const float* __restrict__ ml,
                   unsigned short* __restrict__ attH)
{
    const int bx = blockIdx.x;
    const int b = bx >> 12, q = bx & 4095;
    const int t = threadIdx.x;
    const int h = t >> 6, d4 = (t & 63) * 4;

    float2 m0 = ((const float2*)ml)[(((ull)b * 2 + 0) * 4 + h) * NTOK + q];
    float2 m1 = ((const float2*)ml)[(((ull)b * 2 + 1) * 4 + h) * NTOK + q];
    float ms = fmaxf(m0.x, m1.x);
    float w0 = __expf(m0.x - ms) * m0.y;
    float w1 = __expf(m1.x - ms) * m1.y;
    float inv = 1.f / (w0 + w1);
    w0 *= inv; w1 *= inv;

    ushort4 o0 = *(const ushort4*)&Opart[((((ull)b * 2 + 0) * 4 + h) * NTOK + q) * 256 + d4];
    ushort4 o1 = *(const ushort4*)&Opart[((((ull)b * 2 + 1) * 4 + h) * NTOK + q) * 256 + d4];
    ushort4 ho;
    ho.x = f2bf(w0 * bf2f(o0.x) + w1 * bf2f(o1.x));
    ho.y = f2bf(w0 * bf2f(o0.y) + w1 * bf2f(o1.y));
    ho.z = f2bf(w0 * bf2f(o0.z) + w1 * bf2f(o1.z));
    ho.w = f2bf(w0 * bf2f(o0.w) + w1 * bf2f(o1.w));
    *(ushort4*)&attH[(ull)b * NTOK * EMB + (ull)q * EMB + h * 256 + d4] = ho;
}

// ---------------------------------------------------------------------------
// merged l2norm: bid<4096 -> pair in/out (fusion, in-place);
// else f32 in (local_feat) -> pair out. One dispatch of 8192 blocks.
__global__ __launch_bounds__(256)
void l2norm2(const unsigned short* __restrict__ pH, const unsigned short* __restrict__ pL,
             unsigned short* __restrict__ oH1, unsigned short* __restrict__ oL1,
             const float* __restrict__ inF,
             unsigned short* __restrict__ oH2, unsigned short* __restrict__ oL2)
{
    const int bid = blockIdx.x;
    const bool pairIn = bid < NTOK;
    const ull row = pairIn ? bid : (bid - NTOK);
    const int t = threadIdx.x;
    const int lane = t & 63, wid = t >> 6;
    __shared__ float red[4];

    float v[4];
    if (pairIn) {
        ushort4 hh = *(const ushort4*)&pH[row * EMB + t * 4];
        ushort4 ll2 = *(const ushort4*)&pL[row * EMB + t * 4];
        v[0] = bf2f(hh.x) + bf2f(ll2.x); v[1] = bf2f(hh.y) + bf2f(ll2.y);
        v[2] = bf2f(hh.z) + bf2f(ll2.z); v[3] = bf2f(hh.w) + bf2f(ll2.w);
    } else {
        float4 x = *(const float4*)&inF[row * EMB + t * 4];
        v[0] = x.x; v[1] = x.y; v[2] = x.z; v[3] = x.w;
    }
    float ss = v[0] * v[0] + v[1] * v[1] + v[2] * v[2] + v[3] * v[3];
    #pragma unroll
    for (int o = 32; o > 0; o >>= 1) ss += __shfl_down(ss, o);
    if (lane == 0) red[wid] = ss;
    __syncthreads();
    ss = red[0] + red[1] + red[2] + red[3];

    float inv = 1.f / fmaxf(sqrtf(ss), 1e-8f);
    unsigned short* oH = pairIn ? oH1 : oH2;
    unsigned short* oL = pairIn ? oL1 : oL2;
    ushort4 ho, lo;
    float s0 = v[0] * inv, s1 = v[1] * inv, s2 = v[2] * inv, s3 = v[3] * inv;
    ho.x = f2bf(s0); lo.x = f2bf(s0 - bf2f(ho.x));
    ho.y = f2bf(s1); lo.y = f2bf(s1 - bf2f(ho.y));
    ho.z = f2bf(s2); lo.z = f2bf(s2 - bf2f(ho.z));
    ho.w = f2bf(s3); lo.w = f2bf(s3 - bf2f(ho.w));
    *(ushort4*)&oH[row * EMB + t * 4] = ho;
    *(ushort4*)&oL[row * EMB + t * 4] = lo;
}

__global__ __launch_bounds__(256)
void add_pos_pair(const float* __restrict__ in, const float* __restrict__ pos,
                  unsigned short* __restrict__ oH, unsigned short* __restrict__ oL)
{
    ull i = ((ull)blockIdx.x * 256 + threadIdx.x) * 4;
    float4 a = *(const float4*)&in[i];
    float4 p = *(const float4*)&pos[(int)(i & (EMB - 1))];
    float w[4] = { a.x + p.x, a.y + p.y, a.z + p.z, a.w + p.w };
    ushort4 ho, lo;
    ho.x = f2bf(w[0]); lo.x = f2bf(w[0] - bf2f(ho.x));
    ho.y = f2bf(w[1]); lo.y = f2bf(w[1] - bf2f(ho.y));
    ho.z = f2bf(w[2]); lo.z = f2bf(w[2] - bf2f(ho.z));
    ho.w = f2bf(w[3]); lo.w = f2bf(w[3] - bf2f(ho.w));
    *(ushort4*)&oH[i] = ho;
    *(ushort4*)&oL[i] = lo;
}

__global__ __launch_bounds__(256)
void split_pair(const float* __restrict__ in, unsigned short* __restrict__ oH,
                unsigned short* __restrict__ oL)
{
    ull i = ((ull)blockIdx.x * 256 + threadIdx.x) * 4;
    float4 a = *(const float4*)&in[i];
    float w[4] = { a.x, a.y, a.z, a.w };
    ushort4 ho, lo;
    ho.x = f2bf(w[0]); lo.x = f2bf(w[0] - bf2f(ho.x));
    ho.y = f2bf(w[1]); lo.y = f2bf(w[1] - bf2f(ho.y));
    ho.z = f2bf(w[2]); lo.z = f2bf(w[2] - bf2f(ho.z));
    ho.w = f2bf(w[3]); lo.w = f2bf(w[3] - bf2f(ho.w));
    *(ushort4*)&oH[i] = ho;
    *(ushort4*)&oL[i] = lo;
}

// merged split_pair for two weight matrices (out-proj pairs)
__global__ __launch_bounds__(256)
void split2_pair(const float* __restrict__ s0, unsigned short* __restrict__ d0h,
                 unsigned short* __restrict__ d0l,
                 const float* __restrict__ s1, unsigned short* __restrict__ d1h,
                 unsigned short* __restrict__ d1l, int n0)
{
    int b = blockIdx.x;
    const float* s; unsigned short* dh; unsigned short* dl; ull base;
    if (b < n0) { s = s0; dh = d0h; dl = d0l; base = b; }
    else        { s = s1; dh = d1h; dl = d1l; base = b - n0; }
    ull i = (base * 256 + threadIdx.x) * 4;
    float4 a = *(const float4*)&s[i];
    float w[4] = { a.x, a.y, a.z, a.w };
    ushort4 ho, lo;
    ho.x = f2bf(w[0]); lo.x = f2bf(w[0] - bf2f(ho.x));
    ho.y = f2bf(w[1]); lo.y = f2bf(w[1] - bf2f(ho.y));
    ho.z = f2bf(w[2]); lo.z = f2bf(w[2] - bf2f(ho.z));
    ho.w = f2bf(w[3]); lo.w = f2bf(w[3] - bf2f(ho.w));
    *(ushort4*)&dh[i] = ho;
    *(ushort4*)&dl[i] = lo;
}

__global__ __launch_bounds__(256)
void cast_bf16(const float* __restrict__ in, unsigned short* __restrict__ out)
{
    ull i = ((ull)blockIdx.x * 256 + threadIdx.x) * 4;
    float4 a = *(const float4*)&in[i];
    ushort4 ho;
    ho.x = f2bf(a.x); ho.y = f2bf(a.y); ho.z = f2bf(a.z); ho.w = f2bf(a.w);
    *(ushort4*)&out[i] = ho;
}

// merged cast for two in-proj weight tensors
__global__ __launch_bounds__(256)
void cast2_bf16(const float* __restrict__ s0, unsigned short* __restrict__ d0,
                const float* __restrict__ s1, unsigned short* __restrict__ d1, int n0)
{
    int b = blockIdx.x;
    const float* s; unsigned short* d; ull base;
    if (b < n0) { s = s0; d = d0; base = b; }
    else        { s = s1; d = d1; base = b - n0; }
    ull i = (base * 256 + threadIdx.x) * 4;
    float4 a = *(const float4*)&s[i];
    ushort4 ho;
    ho.x = f2bf(a.x); ho.y = f2bf(a.y); ho.z = f2bf(a.z); ho.w = f2bf(a.w);
    *(ushort4*)&d[i] = ho;
}

// ---------------------------------------------------------------------------
namespace {

template<int S, int O, int BKv = 32>
inline void G(dim3 grid,
              const unsigned short* Ah, const unsigned short* Al, int lda, ll sAz,
              const unsigned short* Bh, const unsigned short* Bl, int ldb, ll sBz,
              void* Ch, void* Cl, int ldc, ll sCz,
              int K, float alpha, const float* bias, int biasRow,
              const unsigned short* rh, const unsigned short* rl, ll sRz, int rm,
              hipStream_t st)
{
    gemm_mfma<S, O, BKv><<<grid, dim3(256), 0, st>>>(Ah, Al, lda, sAz, Bh, Bl, ldb, sBz,
                                                     Ch, Cl, ldc, sCz, K, alpha, bias, biasRow,
                                                     rh, rl, sRz, rm);
}

struct Bufs {
    unsigned short *Ph[6], *Pl[6];
    unsigned short *ATTh, *QK, *VT, *Opart;
    unsigned short *Wih0, *Wih1, *Wo0h, *Wo0l, *Wo1h, *Wo1l;
    float *ml;
};

// rounds 3-5: batch mhas sharing set-0 weights (proven path)
void run_mha(int batch,
             const unsigned short* qh, ll sQ,
             const unsigned short* kh, ll sK,
             const float* in_w, const float* in_b,
             const float* out_w, const float* out_b,
             unsigned short* dsth, unsigned short* dstl,
             const unsigned short* resh, const unsigned short* resl, ll sR, int resMode,
             const Bufs& B, bool convW, hipStream_t s)
{
    const ull EE = (ull)EMB * EMB;
    const ll  TE = (ll)NTOK * EMB;
    const ll  VTBS = (ll)1024 * 4096;
    if (convW) {
        cast_bf16<<<3 * EE / 1024, 256, 0, s>>>(in_w, B.Wih0);
        split_pair<<<EE / 1024, 256, 0, s>>>(out_w, B.Wo0h, B.Wo0l);
    }
    gemm_qkproj<<<dim3(8, 32, 2 * batch), 256, 0, s>>>(
        qh, kh, qh + sQ, kh + sK, B.Wih0, B.QK, in_b);
    G<1, 1, 64>(dim3(32, 8, batch), B.Wih0 + 2 * EE, nullptr, EMB, 0, kh, nullptr, EMB, sK,
                B.VT, nullptr, 4096, VTBS, EMB, 1.f, in_b + 2 * EMB, 1, nullptr, nullptr, 0, 0, s);

    if (batch == 1) {
        flash_attn<2, 8><<<256, 512, 0, s>>>(B.QK, B.VT, B.Opart, B.ml, nullptr);
        flash_combine<<<NTOK, 256, 0, s>>>(B.Opart, B.ml, B.ATTh);
    } else {
        flash_attn<1, 8><<<256, 512, 0, s>>>(B.QK, B.VT, nullptr, nullptr, B.ATTh);
    }

    G<2, 2, 64>(dim3(8, 32, batch), B.ATTh, nullptr, EMB, TE, B.Wo0h, B.Wo0l, EMB, 0,
                dsth, dstl, EMB, 2 * TE, EMB, 1.f, out_b, 0, resh, resl, sR, resMode, s);
}

} // namespace

extern "C" void kernel_launch(void* const* d_in, const int* in_sizes, int n_in,
                              void* d_out, int out_size, void* d_ws, size_t ws_size,
                              hipStream_t stream) {
    const float* local_feat  = (const float*)d_in[0];
    const float* global_feat = (const float*)d_in[1];
    const float* text_feat   = (const float*)d_in[2];
    const float* pos_l       = (const float*)d_in[3];
    const float* pos_g       = (const float*)d_in[4];
    const float* fc_w        = (const float*)d_in[5];
    const float* fc_b        = (const float*)d_in[6];
    const float* lg_in_w     = (const float*)d_in[7];
    const float* lg_in_b     = (const float*)d_in[8];
    const float* lg_out_w    = (const float*)d_in[9];
    const float* lg_out_b    = (const float*)d_in[10];
    const float* vt_in_w     = (const float*)d_in[11];
    const float* vt_in_b     = (const float*)d_in[12];
    const float* vt_out_w    = (const float*)d_in[13];
    const float* vt_out_b    = (const float*)d_in[14];
    const float* ml_in_w     = (const float*)d_in[15];
    const float* ml_in_b     = (const float*)d_in[16];
    const float* ml_out_w    = (const float*)d_in[17];
    const float* ml_out_b    = (const float*)d_in[18];
    float* out = (float*)d_out;

    const ull TE = (ull)NTOK * EMB;
    const ull EE = (ull)EMB * EMB;
    unsigned short* w = (unsigned short*)d_ws;
    Bufs B;
    for (int i = 0; i < 6; ++i) { B.Ph[i] = w + (2 * i) * TE; B.Pl[i] = w + (2 * i + 1) * TE; }
    B.ATTh  = w + 12 * TE;              // 3 TE
    B.QK    = w + 15 * TE;              // 6 TE (merged); rounds 3-5 use <=4 TE
    B.Opart = B.QK + 2 * TE;            // rounds 4-5 only (QK batch-1 region free)
    B.VT    = w + 21 * TE;              // 3 TE
    B.ml    = (float*)(w + 24 * TE);    // 256 KB = 131072 ushorts
    B.Wih0  = w + 24 * TE + 131072;     // 3 EE
    B.Wih1  = B.Wih0 + 3 * EE;          // 3 EE
    B.Wo0h  = B.Wih1 + 3 * EE;
    B.Wo0l  = B.Wo0h + EE;
    B.Wo1h  = B.Wo0l + EE;
    B.Wo1l  = B.Wo1h + EE;

    add_pos_pair<<<TE / 1024, 256, 0, stream>>>(local_feat, pos_l, B.Ph[0], B.Pl[0]);
    add_pos_pair<<<TE / 1024, 256, 0, stream>>>(global_feat, pos_g, B.Ph[1], B.Pl[1]);

    // tf = text @ fc_w^T + fc_b -> P2 pair (BK=64 SPLITS=3: grid-limited, safe)
    split_pair<<<TE / 1024, 256, 0, stream>>>(text_feat, B.QK, B.QK + TE);
    split_pair<<<EE / 1024, 256, 0, stream>>>(fc_w, B.Wo0h, B.Wo0l);
    G<3, 2, 64>(dim3(EMB / 128, NTOK / 128), B.QK, B.QK + TE, EMB, 0, B.Wo0h, B.Wo0l, EMB, 0,
                B.Ph[2], B.Pl[2], EMB, 0, EMB, 1.f, fc_b, 0, nullptr, nullptr, 0, 0, stream);

    // ---- merged round 1+2: three independent mhas ----
    // m0: local_global = mha(lf, gf; lg) + lf   -> P3
    // m1: text_local   = mha(tf, lf; vt) + lf   -> P4
    // m2: text_global  = mha(tf, gf; vt) + tf   -> P5
    cast2_bf16<<<6 * EE / 1024, 256, 0, stream>>>(lg_in_w, B.Wih0, vt_in_w, B.Wih1,
                                                  (int)(3 * EE / 1024));
    split2_pair<<<2 * EE / 1024, 256, 0, stream>>>(lg_out_w, B.Wo0h, B.Wo0l,
                                                   vt_out_w, B.Wo1h, B.Wo1l,
                                                   (int)(EE / 1024));
    gemm_proj6<<<dim3(8, 32, 6), 256, 0, stream>>>(
        B.Ph[0], B.Ph[1], B.Ph[2], B.Ph[0], B.Ph[2], B.Ph[1],
        B.Wih0, B.Wih1, lg_in_b, vt_in_b, B.QK);
    gemm_vt3<<<dim3(32, 8, 3), 256, 0, stream>>>(
        B.Ph[1], B.Ph[0], B.Ph[1], B.Wih0, B.Wih1, lg_in_b, vt_in_b, B.VT);
    // mha0: NSPLIT=2 full-chip; Opart aliases dead P3/P4 dest region (2 TE)
    flash_attn<2, 8><<<256, 512, 0, stream>>>(B.QK, B.VT, B.Ph[3], B.ml, nullptr);
    // mhas 1,2: NSPLIT=1 full-chip, b in {0,1} over QK batches 1,2 -> ATTh+TE
    flash_attn<1, 8><<<256, 512, 0, stream>>>(B.QK + 2 * TE, B.VT + TE,
                                              nullptr, nullptr, B.ATTh + TE);
    flash_combine<<<NTOK, 256, 0, stream>>>(B.Ph[3], B.ml, B.ATTh);
    gemm_out3<<<dim3(8, 32, 3), 256, 0, stream>>>(
        B.ATTh, B.Wo0h, B.Wo0l, B.Wo1h, B.Wo1l, lg_out_b, vt_out_b,
        B.Ph[3], B.Pl[3],
        B.Ph[0], B.Pl[0], B.Ph[0], B.Pl[0], B.Ph[2], B.Pl[2]);

    const ll T2 = (ll)2 * TE, T4 = (ll)4 * TE;
    // round 3 (batch): gt_gl = mha(P3, P5; ml) -> P0 ; gl_lt = mha(P4, P3; ml) -> P1
    run_mha(2, B.Ph[3], T2, B.Ph[5], -T4, ml_in_w, ml_in_b, ml_out_w, ml_out_b,
            B.Ph[0], B.Pl[0], nullptr, nullptr, 0, 0, B, true, stream);
    // round 4: full = mha(gl_lt=P1, gt_gl=P0; ml)            -> P3
    run_mha(1, B.Ph[1], 0, B.Ph[0], 0, ml_in_w, ml_in_b, ml_out_w, ml_out_b,
            B.Ph[3], B.Pl[3], nullptr, nullptr, 0, 0, B, false, stream);
    // round 5: fusion = mha(tf=P2, full=P3; ml) * tf         -> P4
    run_mha(1, B.Ph[2], 0, B.Ph[3], 0, ml_in_w, ml_in_b, ml_out_w, ml_out_b,
            B.Ph[4], B.Pl[4], B.Ph[2], B.Pl[2], 0, 2, B, false, stream);

    // ff = l2norm(fusion) in-place on P4 pair; lb = l2norm(local_feat) -> P5
    l2norm2<<<2 * NTOK, 256, 0, stream>>>(B.Ph[4], B.Pl[4], B.Ph[4], B.Pl[4],
                                          local_feat, B.Ph[5], B.Pl[5]);

    // logits (BK=64 SPLITS=3: 128 blocks, grid-limited)
    G<3, 0, 64>(dim3(QTY / 128, QTY / 128, 8),
                B.Ph[4], B.Pl[4], EMB, (ll)QTY * EMB,
                B.Ph[5], B.Pl[5], EMB, (ll)QTY * EMB,
                out, nullptr, QTY, (ll)QTY * QTY,
                EMB, 1.f, nullptr, 0, nullptr, nullptr, 0, 0, stream);
}